// Round 9
// baseline (503.154 us; speedup 1.0000x reference)
//
#include <hip/hip_runtime.h>

#define N_NODES 4096
#define C_DIM   128
#define L_LAYERS 4
#define E_EDGES 131072
#define H_HEADS 4
#define D_HEAD  32
#define NC      (N_NODES * C_DIM)
#define NCu     (N_NODES * C_DIM)

typedef short bf16x8 __attribute__((ext_vector_type(8)));
typedef short bf16x4 __attribute__((ext_vector_type(4)));
typedef float f32x4  __attribute__((ext_vector_type(4)));

__device__ __forceinline__ unsigned short f2bf(float f) {
    unsigned int u = __float_as_uint(f);
    u += 0x7fffu + ((u >> 16) & 1u);
    return (unsigned short)(u >> 16);
}

__device__ __forceinline__ float bf_lo(unsigned int u) { return __uint_as_float(u << 16); }
__device__ __forceinline__ float bf_hi(unsigned int u) { return __uint_as_float(u & 0xffff0000u); }

__device__ __forceinline__ bf16x8 pack8(const float* v) {
    bf16x8 o;
#pragma unroll
    for (int i = 0; i < 8; ++i) o[i] = (short)f2bf(v[i]);
    return o;
}

// ---------------------------------------------------------------------------
// CSR build (once per launch)
// ---------------------------------------------------------------------------
__global__ __launch_bounds__(256) void hist_kernel(const int* __restrict__ ei,
                                                   int* __restrict__ deg) {
    int e = blockIdx.x * 256 + threadIdx.x;
    atomicAdd(&deg[ei[E_EDGES + e]], 1);
}

__global__ __launch_bounds__(256) void scan_kernel(const int* __restrict__ deg,
                                                   int* __restrict__ rowstart,
                                                   int* __restrict__ cursor) {
    __shared__ int ts[256];
    const int tid = threadIdx.x;
    int loc[16];
    int s = 0;
#pragma unroll
    for (int i = 0; i < 16; ++i) { loc[i] = s; s += deg[tid * 16 + i]; }
    ts[tid] = s;
    __syncthreads();
    for (int off = 1; off < 256; off <<= 1) {
        int t = (tid >= off) ? ts[tid - off] : 0;
        __syncthreads();
        if (tid >= off) ts[tid] += t;
        __syncthreads();
    }
    int off0 = ts[tid] - s;
#pragma unroll
    for (int i = 0; i < 16; ++i) {
        int v = off0 + loc[i];
        rowstart[tid * 16 + i] = v;
        cursor[tid * 16 + i] = v;
    }
    if (tid == 255) rowstart[4096] = off0 + s;
}

__global__ __launch_bounds__(256) void fill_kernel(const int* __restrict__ ei,
                                                   int* __restrict__ cursor,
                                                   int* __restrict__ csr_src) {
    int e = blockIdx.x * 256 + threadIdx.x;
    int d = ei[E_EDGES + e];
    int s = ei[e];
    int p = atomicAdd(&cursor[d], 1);
    csr_src[p] = s;
}

// ---------------------------------------------------------------------------
// weight pre-convert fp32 -> bf16
// ---------------------------------------------------------------------------
__global__ __launch_bounds__(256) void wcvt(const float* __restrict__ s0, const float* __restrict__ s1,
                                            const float* __restrict__ s2, const float* __restrict__ s3,
                                            const float* __restrict__ s4, const float* __restrict__ s5,
                                            unsigned short* __restrict__ wbf) {
    int i0 = (blockIdx.x * 256 + threadIdx.x) * 8;
    const float* src; int base;
    if      (i0 < 65536)  { src = s0; base = 0; }
    else if (i0 < 131072) { src = s1; base = 65536; }
    else if (i0 < 327680) { src = s2; base = 131072; }
    else if (i0 < 393216) { src = s3; base = 327680; }
    else if (i0 < 524288) { src = s4; base = 393216; }
    else                  { src = s5; base = 524288; }
    const float* p = src + (i0 - base);
    float t[8];
#pragma unroll
    for (int i = 0; i < 8; ++i) t[i] = p[i];
    *(bf16x8*)(wbf + i0) = pack8(t);
}

__global__ __launch_bounds__(256) void x2bf(const float* __restrict__ x,
                                            unsigned short* __restrict__ xb) {
    int i0 = (blockIdx.x * 256 + threadIdx.x) * 8;
    float t[8];
#pragma unroll
    for (int i = 0; i < 8; ++i) t[i] = x[i0 + i];
    *(bf16x8*)(xb + i0) = pack8(t);
}

// ---------------------------------------------------------------------------
// GIN aggregation from bf16 x; block 0 also zeroes the BN stats buffer
// (stream-ordered before all stats-producing GEMMs of this layer).
// ---------------------------------------------------------------------------
__global__ __launch_bounds__(256) void gather_agg(const unsigned short* __restrict__ xb,
                                                  const int* __restrict__ rowstart,
                                                  const int* __restrict__ csr_src,
                                                  unsigned int* __restrict__ hsum,
                                                  float* __restrict__ ssz) {
    if (blockIdx.x == 0) {
        ssz[threadIdx.x] = 0.f;
        ssz[256 + threadIdx.x] = 0.f;
        ssz[512 + threadIdx.x] = 0.f;
    }
    const int node = blockIdx.x * 4 + (threadIdx.x >> 6);
    const int lane = threadIdx.x & 63;
    const unsigned int* xu = (const unsigned int*)xb;
    const int beg = rowstart[node], end = rowstart[node + 1];
    unsigned int su = xu[(size_t)node * 64 + lane];
    float ax = bf_lo(su), ay = bf_hi(su);
    float bx = 0.f, by = 0.f;
    int e = beg;
    for (; e + 4 <= end; e += 4) {
        int s0 = csr_src[e], s1 = csr_src[e + 1], s2 = csr_src[e + 2], s3 = csr_src[e + 3];
        unsigned int u0 = xu[(size_t)s0 * 64 + lane];
        unsigned int u1 = xu[(size_t)s1 * 64 + lane];
        unsigned int u2 = xu[(size_t)s2 * 64 + lane];
        unsigned int u3 = xu[(size_t)s3 * 64 + lane];
        ax += bf_lo(u0) + bf_lo(u1); ay += bf_hi(u0) + bf_hi(u1);
        bx += bf_lo(u2) + bf_lo(u3); by += bf_hi(u2) + bf_hi(u3);
    }
    for (; e < end; ++e) {
        unsigned int u0 = xu[(size_t)csr_src[e] * 64 + lane];
        ax += bf_lo(u0); ay += bf_hi(u0);
    }
    float ox = ax + bx, oy = ay + by;
    hsum[(size_t)node * 64 + lane] = (unsigned int)f2bf(ox) | ((unsigned int)f2bf(oy) << 16);
}

// ---------------------------------------------------------------------------
// bf16 MFMA GEMM, LDS-free, 16x16 tile per wave. grid (J/64, N/16).
// Optional stats: accumulate per-channel sum / sumsq of the final output v
// into stats[col] / stats[C_DIM+col] (for fused BatchNorm).
// ---------------------------------------------------------------------------
template <int K>
__global__ __launch_bounds__(256, 8) void gemm_bf(const unsigned short* __restrict__ Abf,
                                                  const unsigned short* __restrict__ Wbf,
                                                  const float* __restrict__ bias,
                                                  const float* __restrict__ resid,
                                                  float* __restrict__ outf,
                                                  unsigned short* __restrict__ outb,
                                                  float* __restrict__ stats,
                                                  const int J, const int relu) {
    const int tid = threadIdx.x;
    const int wv = tid >> 6;
    const int lane = tid & 63, lg = lane >> 4, ll = lane & 15;
    const int rowbase = blockIdx.y * 16;
    const int colbase = blockIdx.x * 64 + wv * 16;

    const unsigned short* Ap = Abf + (size_t)(rowbase + ll) * K + lg * 8;
    const unsigned short* Wp = Wbf + (size_t)(colbase + ll) * K + lg * 8;

    f32x4 acc = {0.f, 0.f, 0.f, 0.f};
#pragma unroll
    for (int k = 0; k < K; k += 32) {
        bf16x8 a = *(const bf16x8*)(Ap + k);
        bf16x8 b = *(const bf16x8*)(Wp + k);
        acc = __builtin_amdgcn_mfma_f32_16x16x32_bf16(a, b, acc, 0, 0, 0);
    }

    const int col = colbase + ll;
    const float bi = bias[col];
    float sv = 0.f, sv2 = 0.f;
#pragma unroll
    for (int r = 0; r < 4; ++r) {
        const int row = rowbase + lg * 4 + r;
        float v = acc[r] + bi;
        if (resid) v += resid[(size_t)row * J + col];
        if (relu) v = fmaxf(v, 0.f);
        if (outf) outf[(size_t)row * J + col] = v;
        if (outb) outb[(size_t)row * J + col] = f2bf(v);
        sv += v; sv2 += v * v;
    }
    if (stats) {
        sv  += __shfl_xor(sv, 16, 64);  sv  += __shfl_xor(sv, 32, 64);
        sv2 += __shfl_xor(sv2, 16, 64); sv2 += __shfl_xor(sv2, 32, 64);
        if (lg == 0) {
            atomicAdd(&stats[col], sv);
            atomicAdd(&stats[C_DIM + col], sv2);
        }
    }
}

// ---------------------------------------------------------------------------
// QKV GEMM with layout epilogue: Qb [H][N][32] (pre-scaled), Kb [H][N][32],
// VT [H][32][N].  grid (6, 256).
// ---------------------------------------------------------------------------
__global__ __launch_bounds__(256, 8) void gemm_qkv_bf(const unsigned short* __restrict__ Abf,
                                                      const unsigned short* __restrict__ Wbf,
                                                      const float* __restrict__ bias,
                                                      unsigned short* __restrict__ Qb,
                                                      unsigned short* __restrict__ Kb,
                                                      unsigned short* __restrict__ VT) {
    const int tid = threadIdx.x;
    const int wv = tid >> 6;
    const int lane = tid & 63, lg = lane >> 4, ll = lane & 15;
    const int rowbase = blockIdx.y * 16;
    const int colbase = blockIdx.x * 64 + wv * 16;

    const unsigned short* Ap = Abf + (size_t)(rowbase + ll) * 128 + lg * 8;
    const unsigned short* Wp = Wbf + (size_t)(colbase + ll) * 128 + lg * 8;

    f32x4 acc = {0.f, 0.f, 0.f, 0.f};
#pragma unroll
    for (int k = 0; k < 128; k += 32) {
        bf16x8 a = *(const bf16x8*)(Ap + k);
        bf16x8 b = *(const bf16x8*)(Wp + k);
        acc = __builtin_amdgcn_mfma_f32_16x16x32_bf16(a, b, acc, 0, 0, 0);
    }

    const float qsc = 0.25506973f;  // (1/sqrt(32)) * log2(e)
    const int col = colbase + ll;
    const float bi = bias[col];
#pragma unroll
    for (int r = 0; r < 4; ++r) {
        const int row = rowbase + lg * 4 + r;
        float v = acc[r] + bi;
        if (col < 128) {
            int hh = col >> 5, d = col & 31;
            Qb[((size_t)hh * N_NODES + row) * D_HEAD + d] = f2bf(v * qsc);
        } else if (col < 256) {
            int c2 = col - 128, hh = c2 >> 5, d = c2 & 31;
            Kb[((size_t)hh * N_NODES + row) * D_HEAD + d] = f2bf(v);
        } else {
            int c2 = col - 256, hh = c2 >> 5, d = c2 & 31;
            VT[((size_t)hh * D_HEAD + d) * N_NODES + row] = f2bf(v);
        }
    }
}

// ---------------------------------------------------------------------------
// Flash attention v7: 16-way key split over 2 blocks per (q-tile, head).
// grid (N/32, H, 2), 512 thr = 8 waves; wave (s,wv) owns keys
// (s*8+wv)*256 .. +256 (2 tiles of 128). Swapped-operand QK^T (P in-lane,
// zero flash-loop LDS). Block writes UNNORMALIZED O partial (fp32) + L
// partial; attn_finalize merges the 2 splits and packs bf16.
// ---------------------------------------------------------------------------
__global__ __launch_bounds__(512, 4) void attn_kernel(const unsigned short* __restrict__ Qb,
                                                      const unsigned short* __restrict__ Kb,
                                                      const unsigned short* __restrict__ VT,
                                                      float* __restrict__ Op0,
                                                      float* __restrict__ Op1,
                                                      float* __restrict__ Lp) {
    __shared__ float Ouns[8][32][33];   // 33792 B
    __shared__ float Llp[8][32];        //  1024 B

    const int h   = blockIdx.y;
    const int q0  = blockIdx.x * 32;
    const int sp  = blockIdx.z;
    const int tid = threadIdx.x;
    const int wv  = tid >> 6;
    const int lane = tid & 63;
    const int lg  = lane >> 4;
    const int ll  = lane & 15;

    const unsigned short* Qh = Qb + ((size_t)h * N_NODES + q0) * D_HEAD;
    const unsigned short* Kh = Kb + (size_t)h * N_NODES * D_HEAD;
    const unsigned short* Vh = VT + (size_t)h * D_HEAD * N_NODES;

    bf16x8 qf0 = *(const bf16x8*)(Qh + ll * D_HEAD + lg * 8);
    bf16x8 qf1 = *(const bf16x8*)(Qh + (16 + ll) * D_HEAD + lg * 8);

    f32x4 o00 = {0.f,0.f,0.f,0.f}, o01 = {0.f,0.f,0.f,0.f};
    f32x4 o10 = {0.f,0.f,0.f,0.f}, o11 = {0.f,0.f,0.f,0.f};
    float l0 = 0.f, l1 = 0.f;

    const int k0 = (sp * 8 + wv) * (N_NODES / 16);
    const unsigned short* Vrow_lo = Vh + (size_t)ll * N_NODES;
    const unsigned short* Vrow_hi = Vh + (size_t)(16 + ll) * N_NODES;

#pragma unroll
    for (int t = 0; t < 2; ++t) {
        const int kt = k0 + t * 128;

        // QK^T (A=K, B=Q) + exp2 + in-lane bf16 pack
        bf16x8 pa0[4], pa1[4];
#pragma unroll
        for (int kc = 0; kc < 8; ++kc) {
            bf16x8 kf = *(const bf16x8*)(Kh + (size_t)(kt + kc * 16 + ll) * D_HEAD + lg * 8);
            f32x4 z = {0.f, 0.f, 0.f, 0.f};
            f32x4 d0 = __builtin_amdgcn_mfma_f32_16x16x32_bf16(kf, qf0, z, 0, 0, 0);
            f32x4 d1 = __builtin_amdgcn_mfma_f32_16x16x32_bf16(kf, qf1, z, 0, 0, 0);
#pragma unroll
            for (int r = 0; r < 4; ++r) {
                float p0 = exp2f(d0[r]); l0 += p0;
                float p1 = exp2f(d1[r]); l1 += p1;
                pa0[kc >> 1][(kc & 1) * 4 + r] = (short)f2bf(p0);
                pa1[kc >> 1][(kc & 1) * 4 + r] = (short)f2bf(p1);
            }
        }

        // PV: V read with the matching per-lane key permutation
#pragma unroll
        for (int j = 0; j < 4; ++j) {
            const int kb = kt + 32 * j + lg * 4;
            bf16x4 alo0 = *(const bf16x4*)(Vrow_lo + kb);
            bf16x4 alo1 = *(const bf16x4*)(Vrow_lo + kb + 16);
            bf16x4 ahi0 = *(const bf16x4*)(Vrow_hi + kb);
            bf16x4 ahi1 = *(const bf16x4*)(Vrow_hi + kb + 16);
            bf16x8 vlo = __builtin_shufflevector(alo0, alo1, 0, 1, 2, 3, 4, 5, 6, 7);
            bf16x8 vhi = __builtin_shufflevector(ahi0, ahi1, 0, 1, 2, 3, 4, 5, 6, 7);
            o00 = __builtin_amdgcn_mfma_f32_16x16x32_bf16(pa0[j], vlo, o00, 0, 0, 0);
            o01 = __builtin_amdgcn_mfma_f32_16x16x32_bf16(pa0[j], vhi, o01, 0, 0, 0);
            o10 = __builtin_amdgcn_mfma_f32_16x16x32_bf16(pa1[j], vlo, o10, 0, 0, 0);
            o11 = __builtin_amdgcn_mfma_f32_16x16x32_bf16(pa1[j], vhi, o11, 0, 0, 0);
        }
    }

    // lane-local denominators: sum the 4 lg-groups holding same q
    l0 += __shfl_xor(l0, 16, 64); l0 += __shfl_xor(l0, 32, 64);
    l1 += __shfl_xor(l1, 16, 64); l1 += __shfl_xor(l1, 32, 64);

#pragma unroll
    for (int r = 0; r < 4; ++r) {
        Ouns[wv][lg * 4 + r][ll]           = o00[r];
        Ouns[wv][lg * 4 + r][16 + ll]      = o01[r];
        Ouns[wv][16 + lg * 4 + r][ll]      = o10[r];
        Ouns[wv][16 + lg * 4 + r][16 + ll] = o11[r];
    }
    if (lg == 0) {
        Llp[wv][ll]      = l0;
        Llp[wv][16 + ll] = l1;
    }
    __syncthreads();

    // merge 8 in-block partials; write unnormalized split-partial
    {
        float* Op = sp ? Op1 : Op0;
        const int row = tid >> 4, col = tid & 15;
        float L = 0.f, oa = 0.f, obv = 0.f;
#pragma unroll
        for (int w = 0; w < 8; ++w) {
            L   += Llp[w][row];
            oa  += Ouns[w][row][col];
            obv += Ouns[w][row][16 + col];
        }
        Op[(size_t)(q0 + row) * C_DIM + h * D_HEAD + col]      = oa;
        Op[(size_t)(q0 + row) * C_DIM + h * D_HEAD + 16 + col] = obv;
        if (col == 0)
            Lp[((size_t)sp * H_HEADS + h) * N_NODES + q0 + row] = L;
    }
}

// merge the 2 key-split partials: ob = (O0+O1)/(L0+L1), bf16. grid 512x256.
__global__ __launch_bounds__(256) void attn_finalize(const float* __restrict__ Op0,
                                                     const float* __restrict__ Op1,
                                                     const float* __restrict__ Lp,
                                                     unsigned short* __restrict__ ob) {
    int idx = blockIdx.x * 256 + threadIdx.x;   // N*C/4
    int row = idx >> 5;
    int c0 = (idx & 31) * 4;
    int h = c0 >> 5;
    float L = Lp[(size_t)h * N_NODES + row] +
              Lp[((size_t)H_HEADS + h) * N_NODES + row];
    float inv = 1.f / L;
    float4 a = *(const float4*)(Op0 + (size_t)row * C_DIM + c0);
    float4 b = *(const float4*)(Op1 + (size_t)row * C_DIM + c0);
    ushort4 u;
    u.x = f2bf((a.x + b.x) * inv);
    u.y = f2bf((a.y + b.y) * inv);
    u.z = f2bf((a.z + b.z) * inv);
    u.w = f2bf((a.w + b.w) * inv);
    *(ushort4*)(ob + (size_t)row * C_DIM + c0) = u;
}

// ---------------------------------------------------------------------------
// h = bn1(g1)+bn2(a2) with BN scales computed inline from raw sums
// ---------------------------------------------------------------------------
__global__ __launch_bounds__(256) void combine2(const float* __restrict__ p1,
                                                const float* __restrict__ p2,
                                                const float* __restrict__ st1,
                                                const float* __restrict__ st2,
                                                const float* __restrict__ g1v,
                                                const float* __restrict__ b1v,
                                                const float* __restrict__ g2v,
                                                const float* __restrict__ b2v,
                                                float* __restrict__ out,
                                                unsigned short* __restrict__ outb) {
    int idx = blockIdx.x * 256 + threadIdx.x;
    int c4 = (idx & 31) * 4;
    const float inv_n = 1.f / N_NODES;
    float sc1[4], sh1[4], sc2[4], sh2[4];
#pragma unroll
    for (int c = 0; c < 4; ++c) {
        int ch = c4 + c;
        float m1 = st1[ch] * inv_n;
        float v1 = st1[C_DIM + ch] * inv_n - m1 * m1;
        float r1 = rsqrtf(v1 + 1e-5f);
        sc1[c] = g1v[ch] * r1; sh1[c] = b1v[ch] - m1 * sc1[c];
        float m2 = st2[ch] * inv_n;
        float v2 = st2[C_DIM + ch] * inv_n - m2 * m2;
        float r2 = rsqrtf(v2 + 1e-5f);
        sc2[c] = g2v[ch] * r2; sh2[c] = b2v[ch] - m2 * sc2[c];
    }
    float4 v1 = ((const float4*)p1)[idx];
    float4 v2 = ((const float4*)p2)[idx];
    float4 o;
    o.x = v1.x * sc1[0] + sh1[0] + v2.x * sc2[0] + sh2[0];
    o.y = v1.y * sc1[1] + sh1[1] + v2.y * sc2[1] + sh2[1];
    o.z = v1.z * sc1[2] + sh1[2] + v2.z * sc2[2] + sh2[2];
    o.w = v1.w * sc1[3] + sh1[3] + v2.w * sc2[3] + sh2[3];
    ((float4*)out)[idx] = o;
    ushort4 ub;
    ub.x = f2bf(o.x); ub.y = f2bf(o.y); ub.z = f2bf(o.z); ub.w = f2bf(o.w);
    *(ushort4*)(outb + (size_t)idx * 4) = ub;
}

// x = bn3(m3), scales inline from raw sums
__global__ __launch_bounds__(256) void bn_apply(const float* __restrict__ p,
                                                const float* __restrict__ st,
                                                const float* __restrict__ gv,
                                                const float* __restrict__ bv,
                                                float* __restrict__ out,
                                                unsigned short* __restrict__ outb) {
    int idx = blockIdx.x * 256 + threadIdx.x;
    int c4 = (idx & 31) * 4;
    const float inv_n = 1.f / N_NODES;
    float sc[4], sh[4];
#pragma unroll
    for (int c = 0; c < 4; ++c) {
        int ch = c4 + c;
        float m = st[ch] * inv_n;
        float vv = st[C_DIM + ch] * inv_n - m * m;
        float r = rsqrtf(vv + 1e-5f);
        sc[c] = gv[ch] * r; sh[c] = bv[ch] - m * sc[c];
    }
    float4 v = ((const float4*)p)[idx];
    float4 o;
    o.x = v.x * sc[0] + sh[0];
    o.y = v.y * sc[1] + sh[1];
    o.z = v.z * sc[2] + sh[2];
    o.w = v.w * sc[3] + sh[3];
    ((float4*)out)[idx] = o;
    ushort4 ub;
    ub.x = f2bf(o.x); ub.y = f2bf(o.y); ub.z = f2bf(o.z); ub.w = f2bf(o.w);
    *(ushort4*)(outb + (size_t)idx * 4) = ub;
}

// ---------------------------------------------------------------------------
// Fused head MLP
// ---------------------------------------------------------------------------
__global__ __launch_bounds__(256) void head_fused(const float* __restrict__ x,
                                                  const float* __restrict__ w1,
                                                  const float* __restrict__ b1,
                                                  const float* __restrict__ w2,
                                                  const float* __restrict__ b2,
                                                  const float* __restrict__ w3,
                                                  const float* __restrict__ b3,
                                                  float* __restrict__ out) {
    __shared__ __align__(16) float xs[8][128];
    __shared__ __align__(16) float hs[8][64];
    const int tid = threadIdx.x;
    const int n = tid >> 5;
    const int g = tid & 31;
    const int node0 = blockIdx.x * 8;

    {
        int r = tid >> 5, q = tid & 31;
        *(float4*)(&xs[r][q * 4]) = *(const float4*)(x + (size_t)(node0 + r) * 128 + q * 4);
    }
    __syncthreads();

    {
        float acc0 = b1[g], acc1 = b1[g + 32];
        const float* wa = w1 + (size_t)g * 128;
        const float* wb = w1 + (size_t)(g + 32) * 128;
#pragma unroll 8
        for (int k = 0; k < 128; k += 4) {
            float4 xv = *(const float4*)(&xs[n][k]);
            float4 va = *(const float4*)(wa + k);
            float4 vb = *(const float4*)(wb + k);
            acc0 += xv.x * va.x + xv.y * va.y + xv.z * va.z + xv.w * va.w;
            acc1 += xv.x * vb.x + xv.y * vb.y + xv.z * vb.z + xv.w * vb.w;
        }
        hs[n][g]      = fmaxf(acc0, 0.f);
        hs[n][g + 32] = fmaxf(acc1, 0.f);
    }
    __syncthreads();

    {
        float acc = b2[g];
        const float* wr = w2 + (size_t)g * 64;
#pragma unroll 8
        for (int k = 0; k < 64; k += 4) {
            float4 hv = *(const float4*)(&hs[n][k]);
            float4 wv = *(const float4*)(wr + k);
            acc += hv.x * wv.x + hv.y * wv.y + hv.z * wv.z + hv.w * wv.w;
        }
        float t = fmaxf(acc, 0.f) * w3[g];
#pragma unroll
        for (int off = 1; off < 32; off <<= 1) t += __shfl_xor(t, off, 64);
        if (g == 0) out[node0 + n] = t + b3[0];
    }
}

// ---------------------------------------------------------------------------
extern "C" void kernel_launch(void* const* d_in, const int* in_sizes, int n_in,
                              void* d_out, int out_size, void* d_ws, size_t ws_size,
                              hipStream_t stream) {
    (void)in_sizes; (void)n_in; (void)out_size; (void)ws_size;
    const float* x_in   = (const float*)d_in[0];
    const int*   ei     = (const int*)d_in[1];
    const float* gin_w1 = (const float*)d_in[2];
    const float* gin_b1 = (const float*)d_in[3];
    const float* gin_w2 = (const float*)d_in[4];
    const float* gin_b2 = (const float*)d_in[5];
    const float* ain_w  = (const float*)d_in[6];
    const float* ain_b  = (const float*)d_in[7];
    const float* aout_w = (const float*)d_in[8];
    const float* aout_b = (const float*)d_in[9];
    const float* n1_g   = (const float*)d_in[10];
    const float* n1_b   = (const float*)d_in[11];
    const float* n2_g   = (const float*)d_in[12];
    const float* n2_b   = (const float*)d_in[13];
    const float* n3_g   = (const float*)d_in[14];
    const float* n3_b   = (const float*)d_in[15];
    const float* mlp_w1 = (const float*)d_in[16];
    const float* mlp_b1 = (const float*)d_in[17];
    const float* mlp_w2 = (const float*)d_in[18];
    const float* mlp_b2 = (const float*)d_in[19];
    const float* h_w1   = (const float*)d_in[20];
    const float* h_b1   = (const float*)d_in[21];
    const float* h_w2   = (const float*)d_in[22];
    const float* h_b2   = (const float*)d_in[23];
    const float* h_w3   = (const float*)d_in[24];
    const float* h_b3   = (const float*)d_in[25];

    float* f = (float*)d_ws;
    float* g1   = f;                   // c0 (m3 aliases later)
    float* m3   = f;
    float* a2   = f + 1 * (size_t)NC;  // c1 (O_part0 aliases during attn)
    float* hbuf = f + 2 * (size_t)NC;  // c2 (O_part1 aliases during attn)
    float* Op0  = a2;
    float* Op1  = hbuf;
    float* xA   = f + 3 * (size_t)NC;
    float* xB   = f + 4 * (size_t)NC;
    unsigned short* R1  = (unsigned short*)(f + 5 * (size_t)NC);  // 3 NCu
    unsigned short* hsum_bf = R1;
    unsigned short* t1_bf   = R1 + (size_t)NCu;
    unsigned short* Qb      = R1;
    unsigned short* Kb      = R1 + (size_t)NCu;
    unsigned short* VT      = R1 + 2 * (size_t)NCu;
    unsigned short* t2_bf   = R1;
    unsigned short* R2      = R1 + 3 * (size_t)NCu;
    unsigned short* ao_bf   = R2;
    unsigned short* hbuf_bf = R2;
    unsigned short* xbf     = R2 + (size_t)NCu;
    unsigned short* wbf     = xbf + (size_t)NCu;
    float* ss    = (float*)(wbf + 655360);      // 768 raw sums (3 BNs)
    int* ibase    = (int*)(ss + 768);
    int* deg      = ibase;
    int* rowstart = ibase + 4096;
    int* cursor   = ibase + 4096 + 4098;
    int* csr_src  = ibase + 4096 + 4098 + 4096;
    float* lpart  = (float*)(csr_src + E_EDGES); // 2*H*N = 32768 floats

    const int OG1 = 0, OG2 = 65536, OAI = 131072, OAO = 327680, OM1 = 393216, OM2 = 524288;

    hipMemsetAsync(deg, 0, 4096 * sizeof(int), stream);
    hist_kernel<<<E_EDGES / 256, 256, 0, stream>>>(ei, deg);
    scan_kernel<<<1, 256, 0, stream>>>(deg, rowstart, cursor);
    fill_kernel<<<E_EDGES / 256, 256, 0, stream>>>(ei, cursor, csr_src);
    wcvt<<<320, 256, 0, stream>>>(gin_w1, gin_w2, ain_w, aout_w, mlp_w1, mlp_w2, wbf);
    x2bf<<<NC / 2048, 256, 0, stream>>>(x_in, xbf);

    for (int i = 0; i < L_LAYERS; ++i) {
        const float* xin = (i == 0) ? x_in : ((i & 1) ? xA : xB);
        float* xout = (i & 1) ? xB : xA;
        const float* gb1 = gin_b1 + (size_t)i * C_DIM;
        const float* gb2 = gin_b2 + (size_t)i * C_DIM;
        const float* aib = ain_b + (size_t)i * 3 * C_DIM;
        const float* aob = aout_b + (size_t)i * C_DIM;
        const float* mb1 = mlp_b1 + (size_t)i * 2 * C_DIM;
        const float* mb2 = mlp_b2 + (size_t)i * C_DIM;

        // GIN branch (gather also zeroes ss for this layer's fused BN stats)
        gather_agg<<<N_NODES / 4, 256, 0, stream>>>(xbf, rowstart, csr_src,
                                                    (unsigned int*)hsum_bf, ss);
        gemm_bf<128><<<dim3(2, 256), 256, 0, stream>>>(hsum_bf, wbf + OG1 + (size_t)i * 16384,
                                                       gb1, nullptr, nullptr, t1_bf, nullptr, 128, 1);
        gemm_bf<128><<<dim3(2, 256), 256, 0, stream>>>(t1_bf, wbf + OG2 + (size_t)i * 16384,
                                                       gb2, xin, g1, nullptr, ss, 128, 0);
        // attention branch
        gemm_qkv_bf<<<dim3(6, 256), 256, 0, stream>>>(xbf, wbf + OAI + (size_t)i * 49152,
                                                      aib, Qb, Kb, VT);
        attn_kernel<<<dim3(N_NODES / 32, H_HEADS, 2), 512, 0, stream>>>(Qb, Kb, VT,
                                                                        Op0, Op1, lpart);
        attn_finalize<<<NC / 1024, 256, 0, stream>>>(Op0, Op1, lpart, ao_bf);
        gemm_bf<128><<<dim3(2, 256), 256, 0, stream>>>(ao_bf, wbf + OAO + (size_t)i * 16384,
                                                       aob, xin, a2, nullptr, ss + 256, 128, 0);
        // combine (BN scales inline from fused stats)
        combine2<<<512, 256, 0, stream>>>(g1, a2, ss, ss + 256,
                                          n1_g + (size_t)i * C_DIM, n1_b + (size_t)i * C_DIM,
                                          n2_g + (size_t)i * C_DIM, n2_b + (size_t)i * C_DIM,
                                          hbuf, hbuf_bf);
        // MLP
        gemm_bf<128><<<dim3(4, 256), 256, 0, stream>>>(hbuf_bf, wbf + OM1 + (size_t)i * 32768,
                                                       mb1, nullptr, nullptr, t2_bf, nullptr, 256, 1);
        gemm_bf<256><<<dim3(2, 256), 256, 0, stream>>>(t2_bf, wbf + OM2 + (size_t)i * 32768,
                                                       mb2, hbuf, m3, nullptr, ss + 512, 128, 0);
        bn_apply<<<512, 256, 0, stream>>>(m3, ss + 512,
                                          n3_g + (size_t)i * C_DIM, n3_b + (size_t)i * C_DIM,
                                          xout, xbf);
    }

    const float* xf = xB;  // after layer 3
    head_fused<<<N_NODES / 8, 256, 0, stream>>>(xf, h_w1, h_b1, h_w2, h_b2, h_w3, h_b3,
                                                (float*)d_out);
}

// Round 11
// 472.860 us; speedup vs baseline: 1.0641x; 1.0641x over previous
//
#include <hip/hip_runtime.h>

#define N_NODES 4096
#define C_DIM   128
#define L_LAYERS 4
#define E_EDGES 131072
#define H_HEADS 4
#define D_HEAD  32
#define NC      (N_NODES * C_DIM)
#define NCu     (N_NODES * C_DIM)
#define P_STRIDE 136

typedef short bf16x8 __attribute__((ext_vector_type(8)));
typedef float f32x4  __attribute__((ext_vector_type(4)));

__device__ __forceinline__ unsigned short f2bf(float f) {
    unsigned int u = __float_as_uint(f);
    u += 0x7fffu + ((u >> 16) & 1u);
    return (unsigned short)(u >> 16);
}

__device__ __forceinline__ float bf_lo(unsigned int u) { return __uint_as_float(u << 16); }
__device__ __forceinline__ float bf_hi(unsigned int u) { return __uint_as_float(u & 0xffff0000u); }

__device__ __forceinline__ bf16x8 pack8(const float* v) {
    bf16x8 o;
#pragma unroll
    for (int i = 0; i < 8; ++i) o[i] = (short)f2bf(v[i]);
    return o;
}

// ---------------------------------------------------------------------------
// CSR build (once per launch)
// ---------------------------------------------------------------------------
__global__ __launch_bounds__(256) void hist_kernel(const int* __restrict__ ei,
                                                   int* __restrict__ deg) {
    int e = blockIdx.x * 256 + threadIdx.x;
    atomicAdd(&deg[ei[E_EDGES + e]], 1);
}

__global__ __launch_bounds__(256) void scan_kernel(const int* __restrict__ deg,
                                                   int* __restrict__ rowstart,
                                                   int* __restrict__ cursor) {
    __shared__ int ts[256];
    const int tid = threadIdx.x;
    int loc[16];
    int s = 0;
#pragma unroll
    for (int i = 0; i < 16; ++i) { loc[i] = s; s += deg[tid * 16 + i]; }
    ts[tid] = s;
    __syncthreads();
    for (int off = 1; off < 256; off <<= 1) {
        int t = (tid >= off) ? ts[tid - off] : 0;
        __syncthreads();
        if (tid >= off) ts[tid] += t;
        __syncthreads();
    }
    int off0 = ts[tid] - s;
#pragma unroll
    for (int i = 0; i < 16; ++i) {
        int v = off0 + loc[i];
        rowstart[tid * 16 + i] = v;
        cursor[tid * 16 + i] = v;
    }
    if (tid == 255) rowstart[4096] = off0 + s;
}

__global__ __launch_bounds__(256) void fill_kernel(const int* __restrict__ ei,
                                                   int* __restrict__ cursor,
                                                   int* __restrict__ csr_src) {
    int e = blockIdx.x * 256 + threadIdx.x;
    int d = ei[E_EDGES + e];
    int s = ei[e];
    int p = atomicAdd(&cursor[d], 1);
    csr_src[p] = s;
}

// ---------------------------------------------------------------------------
// weight pre-convert fp32 -> bf16
// ---------------------------------------------------------------------------
__global__ __launch_bounds__(256) void wcvt(const float* __restrict__ s0, const float* __restrict__ s1,
                                            const float* __restrict__ s2, const float* __restrict__ s3,
                                            const float* __restrict__ s4, const float* __restrict__ s5,
                                            unsigned short* __restrict__ wbf) {
    int i0 = (blockIdx.x * 256 + threadIdx.x) * 8;
    const float* src; int base;
    if      (i0 < 65536)  { src = s0; base = 0; }
    else if (i0 < 131072) { src = s1; base = 65536; }
    else if (i0 < 327680) { src = s2; base = 131072; }
    else if (i0 < 393216) { src = s3; base = 327680; }
    else if (i0 < 524288) { src = s4; base = 393216; }
    else                  { src = s5; base = 524288; }
    const float* p = src + (i0 - base);
    float t[8];
#pragma unroll
    for (int i = 0; i < 8; ++i) t[i] = p[i];
    *(bf16x8*)(wbf + i0) = pack8(t);
}

__global__ __launch_bounds__(256) void x2bf(const float* __restrict__ x,
                                            unsigned short* __restrict__ xb) {
    int i0 = (blockIdx.x * 256 + threadIdx.x) * 8;
    float t[8];
#pragma unroll
    for (int i = 0; i < 8; ++i) t[i] = x[i0 + i];
    *(bf16x8*)(xb + i0) = pack8(t);
}

// ---------------------------------------------------------------------------
// GIN aggregation from bf16 x: hsum[n] = x[n] + sum_{j in N(n)} x[j] (bf16 out)
// lane owns 2 channels = one packed uint per row.
// ---------------------------------------------------------------------------
__global__ __launch_bounds__(256) void gather_agg(const unsigned short* __restrict__ xb,
                                                  const int* __restrict__ rowstart,
                                                  const int* __restrict__ csr_src,
                                                  unsigned int* __restrict__ hsum) {
    const int node = blockIdx.x * 4 + (threadIdx.x >> 6);
    const int lane = threadIdx.x & 63;
    const unsigned int* xu = (const unsigned int*)xb;   // [N][64] packed bf16x2
    const int beg = rowstart[node], end = rowstart[node + 1];
    unsigned int su = xu[(size_t)node * 64 + lane];
    float ax = bf_lo(su), ay = bf_hi(su);
    float bx = 0.f, by = 0.f;
    int e = beg;
    for (; e + 4 <= end; e += 4) {
        int s0 = csr_src[e], s1 = csr_src[e + 1], s2 = csr_src[e + 2], s3 = csr_src[e + 3];
        unsigned int u0 = xu[(size_t)s0 * 64 + lane];
        unsigned int u1 = xu[(size_t)s1 * 64 + lane];
        unsigned int u2 = xu[(size_t)s2 * 64 + lane];
        unsigned int u3 = xu[(size_t)s3 * 64 + lane];
        ax += bf_lo(u0) + bf_lo(u1); ay += bf_hi(u0) + bf_hi(u1);
        bx += bf_lo(u2) + bf_lo(u3); by += bf_hi(u2) + bf_hi(u3);
    }
    for (; e < end; ++e) {
        unsigned int u0 = xu[(size_t)csr_src[e] * 64 + lane];
        ax += bf_lo(u0); ay += bf_hi(u0);
    }
    float ox = ax + bx, oy = ay + by;
    hsum[(size_t)node * 64 + lane] = (unsigned int)f2bf(ox) | ((unsigned int)f2bf(oy) << 16);
}

// ---------------------------------------------------------------------------
// bf16 MFMA GEMM, LDS-free, 16x16 tile per wave.
// grid (J/64, N/16), 256 thr = 4 waves.
// ---------------------------------------------------------------------------
template <int K>
__global__ __launch_bounds__(256, 8) void gemm_bf(const unsigned short* __restrict__ Abf,
                                                  const unsigned short* __restrict__ Wbf,
                                                  const float* __restrict__ bias,
                                                  const float* __restrict__ resid,
                                                  float* __restrict__ outf,
                                                  unsigned short* __restrict__ outb,
                                                  const int J, const int relu) {
    const int tid = threadIdx.x;
    const int wv = tid >> 6;
    const int lane = tid & 63, lg = lane >> 4, ll = lane & 15;
    const int rowbase = blockIdx.y * 16;
    const int colbase = blockIdx.x * 64 + wv * 16;

    const unsigned short* Ap = Abf + (size_t)(rowbase + ll) * K + lg * 8;
    const unsigned short* Wp = Wbf + (size_t)(colbase + ll) * K + lg * 8;

    f32x4 acc = {0.f, 0.f, 0.f, 0.f};
#pragma unroll
    for (int k = 0; k < K; k += 32) {
        bf16x8 a = *(const bf16x8*)(Ap + k);
        bf16x8 b = *(const bf16x8*)(Wp + k);
        acc = __builtin_amdgcn_mfma_f32_16x16x32_bf16(a, b, acc, 0, 0, 0);
    }

    const int col = colbase + ll;
    const float bi = bias[col];
#pragma unroll
    for (int r = 0; r < 4; ++r) {
        const int row = rowbase + lg * 4 + r;
        float v = acc[r] + bi;
        if (resid) v += resid[(size_t)row * J + col];
        if (relu) v = fmaxf(v, 0.f);
        if (outf) outf[(size_t)row * J + col] = v;
        if (outb) outb[(size_t)row * J + col] = f2bf(v);
    }
}

// ---------------------------------------------------------------------------
// QKV GEMM with layout epilogue: Qb [H][N][32] (pre-scaled), Kb [H][N][32],
// VT [H][32][N].  grid (6, 256).
// ---------------------------------------------------------------------------
__global__ __launch_bounds__(256, 8) void gemm_qkv_bf(const unsigned short* __restrict__ Abf,
                                                      const unsigned short* __restrict__ Wbf,
                                                      const float* __restrict__ bias,
                                                      unsigned short* __restrict__ Qb,
                                                      unsigned short* __restrict__ Kb,
                                                      unsigned short* __restrict__ VT) {
    const int tid = threadIdx.x;
    const int wv = tid >> 6;
    const int lane = tid & 63, lg = lane >> 4, ll = lane & 15;
    const int rowbase = blockIdx.y * 16;
    const int colbase = blockIdx.x * 64 + wv * 16;

    const unsigned short* Ap = Abf + (size_t)(rowbase + ll) * 128 + lg * 8;
    const unsigned short* Wp = Wbf + (size_t)(colbase + ll) * 128 + lg * 8;

    f32x4 acc = {0.f, 0.f, 0.f, 0.f};
#pragma unroll
    for (int k = 0; k < 128; k += 32) {
        bf16x8 a = *(const bf16x8*)(Ap + k);
        bf16x8 b = *(const bf16x8*)(Wp + k);
        acc = __builtin_amdgcn_mfma_f32_16x16x32_bf16(a, b, acc, 0, 0, 0);
    }

    const float qsc = 0.25506973f;  // (1/sqrt(32)) * log2(e)
    const int col = colbase + ll;
    const float bi = bias[col];
#pragma unroll
    for (int r = 0; r < 4; ++r) {
        const int row = rowbase + lg * 4 + r;
        float v = acc[r] + bi;
        if (col < 128) {
            int hh = col >> 5, d = col & 31;
            Qb[((size_t)hh * N_NODES + row) * D_HEAD + d] = f2bf(v * qsc);
        } else if (col < 256) {
            int c2 = col - 128, hh = c2 >> 5, d = c2 & 31;
            Kb[((size_t)hh * N_NODES + row) * D_HEAD + d] = f2bf(v);
        } else {
            int c2 = col - 256, hh = c2 >> 5, d = c2 & 31;
            VT[((size_t)hh * D_HEAD + d) * N_NODES + row] = f2bf(v);
        }
    }
}

// ---------------------------------------------------------------------------
// Flash attention v4: grid (N/32, H), 512 thr = 8 waves.
// Block = 32 q-rows. Each wave: 2 q-fragments x 512-key range (8-way split);
// K-frag loaded once feeds 2 QK MFMAs, V-frag feeds 2 PV MFMAs.
// No max-subtraction (scores bounded). P in wave-private LDS (stride 136).
// Merge arrays OVERLAY Pl (barrier-separated).
// ---------------------------------------------------------------------------
__global__ __launch_bounds__(512, 4) void attn_kernel(const unsigned short* __restrict__ Qb,
                                                      const unsigned short* __restrict__ Kb,
                                                      const unsigned short* __restrict__ VT,
                                                      unsigned short* __restrict__ ob) {
    __shared__ __align__(16) unsigned short Pl[8 * 32 * P_STRIDE];
    float (*Ouns)[32][33] = (float (*)[32][33])(void*)Pl;
    float (*Llp)[32] = (float (*)[32])(void*)(Pl + 8 * 32 * 33 * 2);

    const int h   = blockIdx.y;
    const int q0  = blockIdx.x * 32;
    const int tid = threadIdx.x;
    const int wv  = tid >> 6;
    const int lane = tid & 63;
    const int lg  = lane >> 4;
    const int ll  = lane & 15;

    const unsigned short* Qh = Qb + ((size_t)h * N_NODES + q0) * D_HEAD;
    const unsigned short* Kh = Kb + (size_t)h * N_NODES * D_HEAD;
    const unsigned short* Vh = VT + (size_t)h * D_HEAD * N_NODES;

    bf16x8 qf0 = *(const bf16x8*)(Qh + ll * D_HEAD + lg * 8);
    bf16x8 qf1 = *(const bf16x8*)(Qh + (16 + ll) * D_HEAD + lg * 8);

    f32x4 oacc00 = {0.f,0.f,0.f,0.f}, oacc01 = {0.f,0.f,0.f,0.f};
    f32x4 oacc10 = {0.f,0.f,0.f,0.f}, oacc11 = {0.f,0.f,0.f,0.f};
    float l0[4] = {0.f,0.f,0.f,0.f}, l1[4] = {0.f,0.f,0.f,0.f};

    unsigned short* Pw = Pl + wv * (32 * P_STRIDE);
    const int k0 = wv * (N_NODES / 8);

    for (int t = 0; t < (N_NODES / 8) / 128; ++t) {
        const int kt = k0 + t * 128;

        float s0[8][4], s1[8][4];
#pragma unroll
        for (int kc = 0; kc < 8; ++kc) {
            bf16x8 kf = *(const bf16x8*)(Kh + (size_t)(kt + kc * 16 + ll) * D_HEAD + lg * 8);
            f32x4 z = {0.f, 0.f, 0.f, 0.f};
            f32x4 d0 = __builtin_amdgcn_mfma_f32_16x16x32_bf16(qf0, kf, z, 0, 0, 0);
            f32x4 d1 = __builtin_amdgcn_mfma_f32_16x16x32_bf16(qf1, kf, z, 0, 0, 0);
#pragma unroll
            for (int r = 0; r < 4; ++r) { s0[kc][r] = d0[r]; s1[kc][r] = d1[r]; }
        }

#pragma unroll
        for (int r = 0; r < 4; ++r) {
            float a = 0.f, b = 0.f;
#pragma unroll
            for (int kc = 0; kc < 8; ++kc) {
                float p0 = exp2f(s0[kc][r]); s0[kc][r] = p0; a += p0;
                float p1 = exp2f(s1[kc][r]); s1[kc][r] = p1; b += p1;
            }
#pragma unroll
            for (int off = 1; off < 16; off <<= 1) {
                a += __shfl_xor(a, off, 64);
                b += __shfl_xor(b, off, 64);
            }
            l0[r] += a;
            l1[r] += b;
        }

#pragma unroll
        for (int kc = 0; kc < 8; ++kc)
#pragma unroll
            for (int r = 0; r < 4; ++r) {
                Pw[(lg * 4 + r) * P_STRIDE + kc * 16 + ll]      = f2bf(s0[kc][r]);
                Pw[(16 + lg * 4 + r) * P_STRIDE + kc * 16 + ll] = f2bf(s1[kc][r]);
            }
        asm volatile("" ::: "memory");

#pragma unroll
        for (int kc2 = 0; kc2 < 4; ++kc2) {
            bf16x8 va = *(const bf16x8*)(Vh + (size_t)ll * N_NODES + kt + kc2 * 32 + lg * 8);
            bf16x8 vb = *(const bf16x8*)(Vh + (size_t)(16 + ll) * N_NODES + kt + kc2 * 32 + lg * 8);
            bf16x8 pf0 = *(const bf16x8*)(Pw + ll * P_STRIDE + kc2 * 32 + lg * 8);
            bf16x8 pf1 = *(const bf16x8*)(Pw + (16 + ll) * P_STRIDE + kc2 * 32 + lg * 8);
            oacc00 = __builtin_amdgcn_mfma_f32_16x16x32_bf16(pf0, va, oacc00, 0, 0, 0);
            oacc01 = __builtin_amdgcn_mfma_f32_16x16x32_bf16(pf0, vb, oacc01, 0, 0, 0);
            oacc10 = __builtin_amdgcn_mfma_f32_16x16x32_bf16(pf1, va, oacc10, 0, 0, 0);
            oacc11 = __builtin_amdgcn_mfma_f32_16x16x32_bf16(pf1, vb, oacc11, 0, 0, 0);
        }
    }

    __syncthreads();

#pragma unroll
    for (int r = 0; r < 4; ++r) {
        Ouns[wv][lg * 4 + r][ll]           = oacc00[r];
        Ouns[wv][lg * 4 + r][16 + ll]      = oacc01[r];
        Ouns[wv][16 + lg * 4 + r][ll]      = oacc10[r];
        Ouns[wv][16 + lg * 4 + r][16 + ll] = oacc11[r];
    }
    if (ll == 0) {
#pragma unroll
        for (int r = 0; r < 4; ++r) {
            Llp[wv][lg * 4 + r]      = l0[r];
            Llp[wv][16 + lg * 4 + r] = l1[r];
        }
    }
    __syncthreads();

    {
        const int row = tid >> 4, col = tid & 15;
        float L = 0.f, oa = 0.f, obv = 0.f;
#pragma unroll
        for (int w = 0; w < 8; ++w) {
            L   += Llp[w][row];
            oa  += Ouns[w][row][col];
            obv += Ouns[w][row][16 + col];
        }
        float inv = 1.f / L;
        ob[(size_t)(q0 + row) * C_DIM + h * D_HEAD + col]      = f2bf(oa * inv);
        ob[(size_t)(q0 + row) * C_DIM + h * D_HEAD + 16 + col] = f2bf(obv * inv);
    }
}

// ---------------------------------------------------------------------------
// fused double BatchNorm stats
// ---------------------------------------------------------------------------
__global__ __launch_bounds__(256) void bn_stats2(const float* __restrict__ in1,
                                                 const float* __restrict__ g1v,
                                                 const float* __restrict__ b1v,
                                                 float* __restrict__ ss1,
                                                 const float* __restrict__ in2,
                                                 const float* __restrict__ g2v,
                                                 const float* __restrict__ b2v,
                                                 float* __restrict__ ss2) {
    const int which = blockIdx.x >> 5;
    const int c4 = blockIdx.x & 31;
    const float* in = which ? in2 : in1;
    const float* g  = which ? g2v : g1v;
    const float* b  = which ? b2v : b1v;
    float* ss       = which ? ss2 : ss1;
    const int tid = threadIdx.x;
    float s[4] = {0.f,0.f,0.f,0.f}, s2[4] = {0.f,0.f,0.f,0.f};
    for (int r = tid; r < N_NODES; r += 256) {
        float4 v = *(const float4*)(in + (size_t)r * C_DIM + c4 * 4);
        s[0] += v.x; s2[0] += v.x * v.x;
        s[1] += v.y; s2[1] += v.y * v.y;
        s[2] += v.z; s2[2] += v.z * v.z;
        s[3] += v.w; s2[3] += v.w * v.w;
    }
#pragma unroll
    for (int off = 1; off < 64; off <<= 1) {
#pragma unroll
        for (int c = 0; c < 4; ++c) {
            s[c]  += __shfl_xor(s[c],  off, 64);
            s2[c] += __shfl_xor(s2[c], off, 64);
        }
    }
    __shared__ float red[4][8];
    int w = tid >> 6;
    if ((tid & 63) == 0) {
#pragma unroll
        for (int c = 0; c < 4; ++c) { red[w][c] = s[c]; red[w][4 + c] = s2[c]; }
    }
    __syncthreads();
    if (tid == 0) {
#pragma unroll
        for (int c = 0; c < 4; ++c) {
            float fs = red[0][c] + red[1][c] + red[2][c] + red[3][c];
            float fs2 = red[0][4 + c] + red[1][4 + c] + red[2][4 + c] + red[3][4 + c];
            int ch = c4 * 4 + c;
            float mean = fs / N_NODES;
            float var = fs2 / N_NODES - mean * mean;
            float rstd = rsqrtf(var + 1e-5f);
            float scale = g[ch] * rstd;
            ss[ch] = scale;
            ss[C_DIM + ch] = b[ch] - mean * scale;
        }
    }
}

__global__ __launch_bounds__(256) void bn_stats(const float* __restrict__ in,
                                                const float* __restrict__ g,
                                                const float* __restrict__ b,
                                                float* __restrict__ ss) {
    const int c4 = blockIdx.x;
    const int tid = threadIdx.x;
    float s[4] = {0.f,0.f,0.f,0.f}, s2[4] = {0.f,0.f,0.f,0.f};
    for (int r = tid; r < N_NODES; r += 256) {
        float4 v = *(const float4*)(in + (size_t)r * C_DIM + c4 * 4);
        s[0] += v.x; s2[0] += v.x * v.x;
        s[1] += v.y; s2[1] += v.y * v.y;
        s[2] += v.z; s2[2] += v.z * v.z;
        s[3] += v.w; s2[3] += v.w * v.w;
    }
#pragma unroll
    for (int off = 1; off < 64; off <<= 1) {
#pragma unroll
        for (int c = 0; c < 4; ++c) {
            s[c]  += __shfl_xor(s[c],  off, 64);
            s2[c] += __shfl_xor(s2[c], off, 64);
        }
    }
    __shared__ float red[4][8];
    int w = tid >> 6;
    if ((tid & 63) == 0) {
#pragma unroll
        for (int c = 0; c < 4; ++c) { red[w][c] = s[c]; red[w][4 + c] = s2[c]; }
    }
    __syncthreads();
    if (tid == 0) {
#pragma unroll
        for (int c = 0; c < 4; ++c) {
            float fs = red[0][c] + red[1][c] + red[2][c] + red[3][c];
            float fs2 = red[0][4 + c] + red[1][4 + c] + red[2][4 + c] + red[3][4 + c];
            int ch = c4 * 4 + c;
            float mean = fs / N_NODES;
            float var = fs2 / N_NODES - mean * mean;
            float rstd = rsqrtf(var + 1e-5f);
            float scale = g[ch] * rstd;
            ss[ch] = scale;
            ss[C_DIM + ch] = b[ch] - mean * scale;
        }
    }
}

__global__ __launch_bounds__(256) void combine2(const float* __restrict__ p1,
                                                const float* __restrict__ p2,
                                                const float* __restrict__ ss1,
                                                const float* __restrict__ ss2,
                                                float* __restrict__ out,
                                                unsigned short* __restrict__ outb) {
    int idx = blockIdx.x * 256 + threadIdx.x;
    int c4 = (idx & 31) * 4;
    float4 v1 = ((const float4*)p1)[idx];
    float4 v2 = ((const float4*)p2)[idx];
    float4 sc1 = *(const float4*)(ss1 + c4), sh1 = *(const float4*)(ss1 + C_DIM + c4);
    float4 sc2 = *(const float4*)(ss2 + c4), sh2 = *(const float4*)(ss2 + C_DIM + c4);
    float4 o;
    o.x = v1.x * sc1.x + sh1.x + v2.x * sc2.x + sh2.x;
    o.y = v1.y * sc1.y + sh1.y + v2.y * sc2.y + sh2.y;
    o.z = v1.z * sc1.z + sh1.z + v2.z * sc2.z + sh2.z;
    o.w = v1.w * sc1.w + sh1.w + v2.w * sc2.w + sh2.w;
    ((float4*)out)[idx] = o;
    ushort4 ub;
    ub.x = f2bf(o.x); ub.y = f2bf(o.y); ub.z = f2bf(o.z); ub.w = f2bf(o.w);
    *(ushort4*)(outb + (size_t)idx * 4) = ub;
}

__global__ __launch_bounds__(256) void bn_apply(const float* __restrict__ p,
                                                const float* __restrict__ ss,
                                                float* __restrict__ out,
                                                unsigned short* __restrict__ outb) {
    int idx = blockIdx.x * 256 + threadIdx.x;
    int c4 = (idx & 31) * 4;
    float4 v = ((const float4*)p)[idx];
    float4 sc = *(const float4*)(ss + c4), sh = *(const float4*)(ss + C_DIM + c4);
    float4 o;
    o.x = v.x * sc.x + sh.x;
    o.y = v.y * sc.y + sh.y;
    o.z = v.z * sc.z + sh.z;
    o.w = v.w * sc.w + sh.w;
    ((float4*)out)[idx] = o;
    ushort4 ub;
    ub.x = f2bf(o.x); ub.y = f2bf(o.y); ub.z = f2bf(o.z); ub.w = f2bf(o.w);
    *(ushort4*)(outb + (size_t)idx * 4) = ub;
}

// ---------------------------------------------------------------------------
// Fused head MLP: x[4096][128] -> relu(W1) -> relu(W2) -> W3 -> out[4096]
// grid 512, 256 thr; block = 8 nodes, 32 threads/node. All fp32.
// ---------------------------------------------------------------------------
__global__ __launch_bounds__(256) void head_fused(const float* __restrict__ x,
                                                  const float* __restrict__ w1,
                                                  const float* __restrict__ b1,
                                                  const float* __restrict__ w2,
                                                  const float* __restrict__ b2,
                                                  const float* __restrict__ w3,
                                                  const float* __restrict__ b3,
                                                  float* __restrict__ out) {
    __shared__ __align__(16) float xs[8][128];
    __shared__ __align__(16) float hs[8][64];
    const int tid = threadIdx.x;
    const int n = tid >> 5;
    const int g = tid & 31;
    const int node0 = blockIdx.x * 8;

    {
        int r = tid >> 5, q = tid & 31;
        *(float4*)(&xs[r][q * 4]) = *(const float4*)(x + (size_t)(node0 + r) * 128 + q * 4);
    }
    __syncthreads();

    {
        float acc0 = b1[g], acc1 = b1[g + 32];
        const float* wa = w1 + (size_t)g * 128;
        const float* wb = w1 + (size_t)(g + 32) * 128;
#pragma unroll 8
        for (int k = 0; k < 128; k += 4) {
            float4 xv = *(const float4*)(&xs[n][k]);
            float4 va = *(const float4*)(wa + k);
            float4 vb = *(const float4*)(wb + k);
            acc0 += xv.x * va.x + xv.y * va.y + xv.z * va.z + xv.w * va.w;
            acc1 += xv.x * vb.x + xv.y * vb.y + xv.z * vb.z + xv.w * vb.w;
        }
        hs[n][g]      = fmaxf(acc0, 0.f);
        hs[n][g + 32] = fmaxf(acc1, 0.f);
    }
    __syncthreads();

    {
        float acc = b2[g];
        const float* wr = w2 + (size_t)g * 64;
#pragma unroll 8
        for (int k = 0; k < 64; k += 4) {
            float4 hv = *(const float4*)(&hs[n][k]);
            float4 wv = *(const float4*)(wr + k);
            acc += hv.x * wv.x + hv.y * wv.y + hv.z * wv.z + hv.w * wv.w;
        }
        float t = fmaxf(acc, 0.f) * w3[g];
#pragma unroll
        for (int off = 1; off < 32; off <<= 1) t += __shfl_xor(t, off, 64);
        if (g == 0) out[node0 + n] = t + b3[0];
    }
}

// ---------------------------------------------------------------------------
extern "C" void kernel_launch(void* const* d_in, const int* in_sizes, int n_in,
                              void* d_out, int out_size, void* d_ws, size_t ws_size,
                              hipStream_t stream) {
    (void)in_sizes; (void)n_in; (void)out_size; (void)ws_size;
    const float* x_in   = (const float*)d_in[0];
    const int*   ei     = (const int*)d_in[1];
    const float* gin_w1 = (const float*)d_in[2];
    const float* gin_b1 = (const float*)d_in[3];
    const float* gin_w2 = (const float*)d_in[4];
    const float* gin_b2 = (const float*)d_in[5];
    const float* ain_w  = (const float*)d_in[6];
    const float* ain_b  = (const float*)d_in[7];
    const float* aout_w = (const float*)d_in[8];
    const float* aout_b = (const float*)d_in[9];
    const float* n1_g   = (const float*)d_in[10];
    const float* n1_b   = (const float*)d_in[11];
    const float* n2_g   = (const float*)d_in[12];
    const float* n2_b   = (const float*)d_in[13];
    const float* n3_g   = (const float*)d_in[14];
    const float* n3_b   = (const float*)d_in[15];
    const float* mlp_w1 = (const float*)d_in[16];
    const float* mlp_b1 = (const float*)d_in[17];
    const float* mlp_w2 = (const float*)d_in[18];
    const float* mlp_b2 = (const float*)d_in[19];
    const float* h_w1   = (const float*)d_in[20];
    const float* h_b1   = (const float*)d_in[21];
    const float* h_w2   = (const float*)d_in[22];
    const float* h_b2   = (const float*)d_in[23];
    const float* h_w3   = (const float*)d_in[24];
    const float* h_b3   = (const float*)d_in[25];

    float* f = (float*)d_ws;
    float* g1   = f;                 // c0; m3 aliases (g1 dead after combine2)
    float* m3   = f;
    float* a2   = f + 1 * (size_t)NC;
    float* hbuf = f + 2 * (size_t)NC;
    float* xA   = f + 3 * (size_t)NC;
    float* xB   = f + 4 * (size_t)NC;
    unsigned short* R1  = (unsigned short*)(f + 5 * (size_t)NC);  // 3 NCu
    unsigned short* hsum_bf = R1;
    unsigned short* t1_bf   = R1 + (size_t)NCu;
    unsigned short* Qb      = R1;
    unsigned short* Kb      = R1 + (size_t)NCu;
    unsigned short* VT      = R1 + 2 * (size_t)NCu;
    unsigned short* t2_bf   = R1;
    unsigned short* R2      = R1 + 3 * (size_t)NCu;
    unsigned short* ao_bf   = R2;
    unsigned short* hbuf_bf = R2;
    unsigned short* xbf     = R2 + (size_t)NCu;
    unsigned short* wbf     = xbf + (size_t)NCu;
    float* ss    = (float*)(wbf + 655360);
    int* ibase    = (int*)(ss + 768);
    int* deg      = ibase;
    int* rowstart = ibase + 4096;
    int* cursor   = ibase + 4096 + 4098;
    int* csr_src  = ibase + 4096 + 4098 + 4096;

    const int OG1 = 0, OG2 = 65536, OAI = 131072, OAO = 327680, OM1 = 393216, OM2 = 524288;

    hipMemsetAsync(deg, 0, 4096 * sizeof(int), stream);
    hist_kernel<<<E_EDGES / 256, 256, 0, stream>>>(ei, deg);
    scan_kernel<<<1, 256, 0, stream>>>(deg, rowstart, cursor);
    fill_kernel<<<E_EDGES / 256, 256, 0, stream>>>(ei, cursor, csr_src);
    wcvt<<<320, 256, 0, stream>>>(gin_w1, gin_w2, ain_w, aout_w, mlp_w1, mlp_w2, wbf);
    x2bf<<<NC / 2048, 256, 0, stream>>>(x_in, xbf);

    for (int i = 0; i < L_LAYERS; ++i) {
        const float* xin = (i == 0) ? x_in : ((i & 1) ? xA : xB);
        float* xout = (i & 1) ? xB : xA;
        const float* gb1 = gin_b1 + (size_t)i * C_DIM;
        const float* gb2 = gin_b2 + (size_t)i * C_DIM;
        const float* aib = ain_b + (size_t)i * 3 * C_DIM;
        const float* aob = aout_b + (size_t)i * C_DIM;
        const float* mb1 = mlp_b1 + (size_t)i * 2 * C_DIM;
        const float* mb2 = mlp_b2 + (size_t)i * C_DIM;

        // GIN branch (gathers bf16 x)
        gather_agg<<<N_NODES / 4, 256, 0, stream>>>(xbf, rowstart, csr_src, (unsigned int*)hsum_bf);
        gemm_bf<128><<<dim3(2, 256), 256, 0, stream>>>(hsum_bf, wbf + OG1 + (size_t)i * 16384,
                                                       gb1, nullptr, nullptr, t1_bf, 128, 1);
        gemm_bf<128><<<dim3(2, 256), 256, 0, stream>>>(t1_bf, wbf + OG2 + (size_t)i * 16384,
                                                       gb2, xin, g1, nullptr, 128, 0);
        // attention branch
        gemm_qkv_bf<<<dim3(6, 256), 256, 0, stream>>>(xbf, wbf + OAI + (size_t)i * 49152,
                                                      aib, Qb, Kb, VT);
        attn_kernel<<<dim3(N_NODES / 32, H_HEADS), 512, 0, stream>>>(Qb, Kb, VT, ao_bf);
        gemm_bf<128><<<dim3(2, 256), 256, 0, stream>>>(ao_bf, wbf + OAO + (size_t)i * 16384,
                                                       aob, xin, a2, nullptr, 128, 0);
        // norms + combine
        bn_stats2<<<64, 256, 0, stream>>>(g1, n1_g + (size_t)i * C_DIM, n1_b + (size_t)i * C_DIM, ss,
                                          a2, n2_g + (size_t)i * C_DIM, n2_b + (size_t)i * C_DIM, ss + 256);
        combine2<<<512, 256, 0, stream>>>(g1, a2, ss, ss + 256, hbuf, hbuf_bf);
        // MLP
        gemm_bf<128><<<dim3(4, 256), 256, 0, stream>>>(hbuf_bf, wbf + OM1 + (size_t)i * 32768,
                                                       mb1, nullptr, nullptr, t2_bf, 256, 1);
        gemm_bf<256><<<dim3(2, 256), 256, 0, stream>>>(t2_bf, wbf + OM2 + (size_t)i * 32768,
                                                       mb2, hbuf, m3, nullptr, 128, 0);
        bn_stats<<<32, 256, 0, stream>>>(m3, n3_g + (size_t)i * C_DIM, n3_b + (size_t)i * C_DIM, ss + 512);
        bn_apply<<<512, 256, 0, stream>>>(m3, ss + 512, xout, xbf);
    }

    const float* xf = xB;  // after layer 3
    head_fused<<<N_NODES / 8, 256, 0, stream>>>(xf, h_w1, h_b1, h_w2, h_b2, h_w3, h_b3,
                                                (float*)d_out);
}

// Round 12
// 468.696 us; speedup vs baseline: 1.0735x; 1.0089x over previous
//
#include <hip/hip_runtime.h>

#define N_NODES 4096
#define C_DIM   128
#define L_LAYERS 4
#define E_EDGES 131072
#define H_HEADS 4
#define D_HEAD  32
#define NC      (N_NODES * C_DIM)
#define NCu     (N_NODES * C_DIM)
#define P_STRIDE 136

typedef short bf16x8 __attribute__((ext_vector_type(8)));
typedef float f32x4  __attribute__((ext_vector_type(4)));

__device__ __forceinline__ unsigned short f2bf(float f) {
    unsigned int u = __float_as_uint(f);
    u += 0x7fffu + ((u >> 16) & 1u);
    return (unsigned short)(u >> 16);
}

__device__ __forceinline__ float bf_lo(unsigned int u) { return __uint_as_float(u << 16); }
__device__ __forceinline__ float bf_hi(unsigned int u) { return __uint_as_float(u & 0xffff0000u); }

__device__ __forceinline__ bf16x8 pack8(const float* v) {
    bf16x8 o;
#pragma unroll
    for (int i = 0; i < 8; ++i) o[i] = (short)f2bf(v[i]);
    return o;
}

// ---------------------------------------------------------------------------
// CSR build (once per launch)
// ---------------------------------------------------------------------------
__global__ __launch_bounds__(256) void hist_kernel(const int* __restrict__ ei,
                                                   int* __restrict__ deg) {
    int e = blockIdx.x * 256 + threadIdx.x;
    atomicAdd(&deg[ei[E_EDGES + e]], 1);
}

__global__ __launch_bounds__(256) void scan_kernel(const int* __restrict__ deg,
                                                   int* __restrict__ rowstart,
                                                   int* __restrict__ cursor) {
    __shared__ int ts[256];
    const int tid = threadIdx.x;
    int loc[16];
    int s = 0;
#pragma unroll
    for (int i = 0; i < 16; ++i) { loc[i] = s; s += deg[tid * 16 + i]; }
    ts[tid] = s;
    __syncthreads();
    for (int off = 1; off < 256; off <<= 1) {
        int t = (tid >= off) ? ts[tid - off] : 0;
        __syncthreads();
        if (tid >= off) ts[tid] += t;
        __syncthreads();
    }
    int off0 = ts[tid] - s;
#pragma unroll
    for (int i = 0; i < 16; ++i) {
        int v = off0 + loc[i];
        rowstart[tid * 16 + i] = v;
        cursor[tid * 16 + i] = v;
    }
    if (tid == 255) rowstart[4096] = off0 + s;
}

__global__ __launch_bounds__(256) void fill_kernel(const int* __restrict__ ei,
                                                   int* __restrict__ cursor,
                                                   int* __restrict__ csr_src) {
    int e = blockIdx.x * 256 + threadIdx.x;
    int d = ei[E_EDGES + e];
    int s = ei[e];
    int p = atomicAdd(&cursor[d], 1);
    csr_src[p] = s;
}

// ---------------------------------------------------------------------------
// weight pre-convert fp32 -> bf16
// ---------------------------------------------------------------------------
__global__ __launch_bounds__(256) void wcvt(const float* __restrict__ s0, const float* __restrict__ s1,
                                            const float* __restrict__ s2, const float* __restrict__ s3,
                                            const float* __restrict__ s4, const float* __restrict__ s5,
                                            unsigned short* __restrict__ wbf) {
    int i0 = (blockIdx.x * 256 + threadIdx.x) * 8;
    const float* src; int base;
    if      (i0 < 65536)  { src = s0; base = 0; }
    else if (i0 < 131072) { src = s1; base = 65536; }
    else if (i0 < 327680) { src = s2; base = 131072; }
    else if (i0 < 393216) { src = s3; base = 327680; }
    else if (i0 < 524288) { src = s4; base = 393216; }
    else                  { src = s5; base = 524288; }
    const float* p = src + (i0 - base);
    float t[8];
#pragma unroll
    for (int i = 0; i < 8; ++i) t[i] = p[i];
    *(bf16x8*)(wbf + i0) = pack8(t);
}

__global__ __launch_bounds__(256) void x2bf(const float* __restrict__ x,
                                            unsigned short* __restrict__ xb) {
    int i0 = (blockIdx.x * 256 + threadIdx.x) * 8;
    float t[8];
#pragma unroll
    for (int i = 0; i < 8; ++i) t[i] = x[i0 + i];
    *(bf16x8*)(xb + i0) = pack8(t);
}

// ---------------------------------------------------------------------------
// GIN aggregation from bf16 x; block 0 also zeroes the BN stats buffer
// (stream-ordered before this layer's stats-producing GEMMs).
// ---------------------------------------------------------------------------
__global__ __launch_bounds__(256) void gather_agg(const unsigned short* __restrict__ xb,
                                                  const int* __restrict__ rowstart,
                                                  const int* __restrict__ csr_src,
                                                  unsigned int* __restrict__ hsum,
                                                  float* __restrict__ ssz) {
    if (blockIdx.x == 0) {
        ssz[threadIdx.x] = 0.f;
        ssz[256 + threadIdx.x] = 0.f;
        ssz[512 + threadIdx.x] = 0.f;
    }
    const int node = blockIdx.x * 4 + (threadIdx.x >> 6);
    const int lane = threadIdx.x & 63;
    const unsigned int* xu = (const unsigned int*)xb;   // [N][64] packed bf16x2
    const int beg = rowstart[node], end = rowstart[node + 1];
    unsigned int su = xu[(size_t)node * 64 + lane];
    float ax = bf_lo(su), ay = bf_hi(su);
    float bx = 0.f, by = 0.f;
    int e = beg;
    for (; e + 4 <= end; e += 4) {
        int s0 = csr_src[e], s1 = csr_src[e + 1], s2 = csr_src[e + 2], s3 = csr_src[e + 3];
        unsigned int u0 = xu[(size_t)s0 * 64 + lane];
        unsigned int u1 = xu[(size_t)s1 * 64 + lane];
        unsigned int u2 = xu[(size_t)s2 * 64 + lane];
        unsigned int u3 = xu[(size_t)s3 * 64 + lane];
        ax += bf_lo(u0) + bf_lo(u1); ay += bf_hi(u0) + bf_hi(u1);
        bx += bf_lo(u2) + bf_lo(u3); by += bf_hi(u2) + bf_hi(u3);
    }
    for (; e < end; ++e) {
        unsigned int u0 = xu[(size_t)csr_src[e] * 64 + lane];
        ax += bf_lo(u0); ay += bf_hi(u0);
    }
    float ox = ax + bx, oy = ay + by;
    hsum[(size_t)node * 64 + lane] = (unsigned int)f2bf(ox) | ((unsigned int)f2bf(oy) << 16);
}

// ---------------------------------------------------------------------------
// bf16 MFMA GEMM, LDS-free, 16x16 tile per wave. grid (J/64, N/16).
// Optional fused BatchNorm stats: per-channel sum/sumsq of final output v
// into stats[col] / stats[C_DIM+col] (2 wave-reduced atomics per col).
// ---------------------------------------------------------------------------
template <int K>
__global__ __launch_bounds__(256, 8) void gemm_bf(const unsigned short* __restrict__ Abf,
                                                  const unsigned short* __restrict__ Wbf,
                                                  const float* __restrict__ bias,
                                                  const float* __restrict__ resid,
                                                  float* __restrict__ outf,
                                                  unsigned short* __restrict__ outb,
                                                  float* __restrict__ stats,
                                                  const int J, const int relu) {
    const int tid = threadIdx.x;
    const int wv = tid >> 6;
    const int lane = tid & 63, lg = lane >> 4, ll = lane & 15;
    const int rowbase = blockIdx.y * 16;
    const int colbase = blockIdx.x * 64 + wv * 16;

    const unsigned short* Ap = Abf + (size_t)(rowbase + ll) * K + lg * 8;
    const unsigned short* Wp = Wbf + (size_t)(colbase + ll) * K + lg * 8;

    f32x4 acc = {0.f, 0.f, 0.f, 0.f};
#pragma unroll
    for (int k = 0; k < K; k += 32) {
        bf16x8 a = *(const bf16x8*)(Ap + k);
        bf16x8 b = *(const bf16x8*)(Wp + k);
        acc = __builtin_amdgcn_mfma_f32_16x16x32_bf16(a, b, acc, 0, 0, 0);
    }

    const int col = colbase + ll;
    const float bi = bias[col];
    float sv = 0.f, sv2 = 0.f;
#pragma unroll
    for (int r = 0; r < 4; ++r) {
        const int row = rowbase + lg * 4 + r;
        float v = acc[r] + bi;
        if (resid) v += resid[(size_t)row * J + col];
        if (relu) v = fmaxf(v, 0.f);
        if (outf) outf[(size_t)row * J + col] = v;
        if (outb) outb[(size_t)row * J + col] = f2bf(v);
        sv += v; sv2 += v * v;
    }
    if (stats) {
        sv  += __shfl_xor(sv, 16, 64);  sv  += __shfl_xor(sv, 32, 64);
        sv2 += __shfl_xor(sv2, 16, 64); sv2 += __shfl_xor(sv2, 32, 64);
        if (lg == 0) {
            atomicAdd(&stats[col], sv);
            atomicAdd(&stats[C_DIM + col], sv2);
        }
    }
}

// ---------------------------------------------------------------------------
// QKV GEMM with layout epilogue: Qb [H][N][32] (pre-scaled), Kb [H][N][32],
// VT [H][32][N].  grid (6, 256).
// ---------------------------------------------------------------------------
__global__ __launch_bounds__(256, 8) void gemm_qkv_bf(const unsigned short* __restrict__ Abf,
                                                      const unsigned short* __restrict__ Wbf,
                                                      const float* __restrict__ bias,
                                                      unsigned short* __restrict__ Qb,
                                                      unsigned short* __restrict__ Kb,
                                                      unsigned short* __restrict__ VT) {
    const int tid = threadIdx.x;
    const int wv = tid >> 6;
    const int lane = tid & 63, lg = lane >> 4, ll = lane & 15;
    const int rowbase = blockIdx.y * 16;
    const int colbase = blockIdx.x * 64 + wv * 16;

    const unsigned short* Ap = Abf + (size_t)(rowbase + ll) * 128 + lg * 8;
    const unsigned short* Wp = Wbf + (size_t)(colbase + ll) * 128 + lg * 8;

    f32x4 acc = {0.f, 0.f, 0.f, 0.f};
#pragma unroll
    for (int k = 0; k < 128; k += 32) {
        bf16x8 a = *(const bf16x8*)(Ap + k);
        bf16x8 b = *(const bf16x8*)(Wp + k);
        acc = __builtin_amdgcn_mfma_f32_16x16x32_bf16(a, b, acc, 0, 0, 0);
    }

    const float qsc = 0.25506973f;  // (1/sqrt(32)) * log2(e)
    const int col = colbase + ll;
    const float bi = bias[col];
#pragma unroll
    for (int r = 0; r < 4; ++r) {
        const int row = rowbase + lg * 4 + r;
        float v = acc[r] + bi;
        if (col < 128) {
            int hh = col >> 5, d = col & 31;
            Qb[((size_t)hh * N_NODES + row) * D_HEAD + d] = f2bf(v * qsc);
        } else if (col < 256) {
            int c2 = col - 128, hh = c2 >> 5, d = c2 & 31;
            Kb[((size_t)hh * N_NODES + row) * D_HEAD + d] = f2bf(v);
        } else {
            int c2 = col - 256, hh = c2 >> 5, d = c2 & 31;
            VT[((size_t)hh * D_HEAD + d) * N_NODES + row] = f2bf(v);
        }
    }
}

// ---------------------------------------------------------------------------
// Flash attention v4 (R7/R11 verified): grid (N/32, H), 512 thr = 8 waves.
// Block = 32 q-rows; wave = 2 q-fragments x 512-key range (8-way split).
// No max-subtraction (scores bounded). P in wave-private LDS (stride 136).
// Merge arrays OVERLAY Pl (barrier-separated).
// ---------------------------------------------------------------------------
__global__ __launch_bounds__(512, 4) void attn_kernel(const unsigned short* __restrict__ Qb,
                                                      const unsigned short* __restrict__ Kb,
                                                      const unsigned short* __restrict__ VT,
                                                      unsigned short* __restrict__ ob) {
    __shared__ __align__(16) unsigned short Pl[8 * 32 * P_STRIDE];
    float (*Ouns)[32][33] = (float (*)[32][33])(void*)Pl;
    float (*Llp)[32] = (float (*)[32])(void*)(Pl + 8 * 32 * 33 * 2);

    const int h   = blockIdx.y;
    const int q0  = blockIdx.x * 32;
    const int tid = threadIdx.x;
    const int wv  = tid >> 6;
    const int lane = tid & 63;
    const int lg  = lane >> 4;
    const int ll  = lane & 15;

    const unsigned short* Qh = Qb + ((size_t)h * N_NODES + q0) * D_HEAD;
    const unsigned short* Kh = Kb + (size_t)h * N_NODES * D_HEAD;
    const unsigned short* Vh = VT + (size_t)h * D_HEAD * N_NODES;

    bf16x8 qf0 = *(const bf16x8*)(Qh + ll * D_HEAD + lg * 8);
    bf16x8 qf1 = *(const bf16x8*)(Qh + (16 + ll) * D_HEAD + lg * 8);

    f32x4 oacc00 = {0.f,0.f,0.f,0.f}, oacc01 = {0.f,0.f,0.f,0.f};
    f32x4 oacc10 = {0.f,0.f,0.f,0.f}, oacc11 = {0.f,0.f,0.f,0.f};
    float l0[4] = {0.f,0.f,0.f,0.f}, l1[4] = {0.f,0.f,0.f,0.f};

    unsigned short* Pw = Pl + wv * (32 * P_STRIDE);
    const int k0 = wv * (N_NODES / 8);

    for (int t = 0; t < (N_NODES / 8) / 128; ++t) {
        const int kt = k0 + t * 128;

        float s0[8][4], s1[8][4];
#pragma unroll
        for (int kc = 0; kc < 8; ++kc) {
            bf16x8 kf = *(const bf16x8*)(Kh + (size_t)(kt + kc * 16 + ll) * D_HEAD + lg * 8);
            f32x4 z = {0.f, 0.f, 0.f, 0.f};
            f32x4 d0 = __builtin_amdgcn_mfma_f32_16x16x32_bf16(qf0, kf, z, 0, 0, 0);
            f32x4 d1 = __builtin_amdgcn_mfma_f32_16x16x32_bf16(qf1, kf, z, 0, 0, 0);
#pragma unroll
            for (int r = 0; r < 4; ++r) { s0[kc][r] = d0[r]; s1[kc][r] = d1[r]; }
        }

#pragma unroll
        for (int r = 0; r < 4; ++r) {
            float a = 0.f, b = 0.f;
#pragma unroll
            for (int kc = 0; kc < 8; ++kc) {
                float p0 = exp2f(s0[kc][r]); s0[kc][r] = p0; a += p0;
                float p1 = exp2f(s1[kc][r]); s1[kc][r] = p1; b += p1;
            }
#pragma unroll
            for (int off = 1; off < 16; off <<= 1) {
                a += __shfl_xor(a, off, 64);
                b += __shfl_xor(b, off, 64);
            }
            l0[r] += a;
            l1[r] += b;
        }

#pragma unroll
        for (int kc = 0; kc < 8; ++kc)
#pragma unroll
            for (int r = 0; r < 4; ++r) {
                Pw[(lg * 4 + r) * P_STRIDE + kc * 16 + ll]      = f2bf(s0[kc][r]);
                Pw[(16 + lg * 4 + r) * P_STRIDE + kc * 16 + ll] = f2bf(s1[kc][r]);
            }
        asm volatile("" ::: "memory");

#pragma unroll
        for (int kc2 = 0; kc2 < 4; ++kc2) {
            bf16x8 va = *(const bf16x8*)(Vh + (size_t)ll * N_NODES + kt + kc2 * 32 + lg * 8);
            bf16x8 vb = *(const bf16x8*)(Vh + (size_t)(16 + ll) * N_NODES + kt + kc2 * 32 + lg * 8);
            bf16x8 pf0 = *(const bf16x8*)(Pw + ll * P_STRIDE + kc2 * 32 + lg * 8);
            bf16x8 pf1 = *(const bf16x8*)(Pw + (16 + ll) * P_STRIDE + kc2 * 32 + lg * 8);
            oacc00 = __builtin_amdgcn_mfma_f32_16x16x32_bf16(pf0, va, oacc00, 0, 0, 0);
            oacc01 = __builtin_amdgcn_mfma_f32_16x16x32_bf16(pf0, vb, oacc01, 0, 0, 0);
            oacc10 = __builtin_amdgcn_mfma_f32_16x16x32_bf16(pf1, va, oacc10, 0, 0, 0);
            oacc11 = __builtin_amdgcn_mfma_f32_16x16x32_bf16(pf1, vb, oacc11, 0, 0, 0);
        }
    }

    __syncthreads();

#pragma unroll
    for (int r = 0; r < 4; ++r) {
        Ouns[wv][lg * 4 + r][ll]           = oacc00[r];
        Ouns[wv][lg * 4 + r][16 + ll]      = oacc01[r];
        Ouns[wv][16 + lg * 4 + r][ll]      = oacc10[r];
        Ouns[wv][16 + lg * 4 + r][16 + ll] = oacc11[r];
    }
    if (ll == 0) {
#pragma unroll
        for (int r = 0; r < 4; ++r) {
            Llp[wv][lg * 4 + r]      = l0[r];
            Llp[wv][16 + lg * 4 + r] = l1[r];
        }
    }
    __syncthreads();

    {
        const int row = tid >> 4, col = tid & 15;
        float L = 0.f, oa = 0.f, obv = 0.f;
#pragma unroll
        for (int w = 0; w < 8; ++w) {
            L   += Llp[w][row];
            oa  += Ouns[w][row][col];
            obv += Ouns[w][row][16 + col];
        }
        float inv = 1.f / L;
        ob[(size_t)(q0 + row) * C_DIM + h * D_HEAD + col]      = f2bf(oa * inv);
        ob[(size_t)(q0 + row) * C_DIM + h * D_HEAD + 16 + col] = f2bf(obv * inv);
    }
}

// ---------------------------------------------------------------------------
// h = bn1(g1)+bn2(a2) with BN scales computed inline from raw sums (R9-proven)
// ---------------------------------------------------------------------------
__global__ __launch_bounds__(256) void combine2(const float* __restrict__ p1,
                                                const float* __restrict__ p2,
                                                const float* __restrict__ st1,
                                                const float* __restrict__ st2,
                                                const float* __restrict__ g1v,
                                                const float* __restrict__ b1v,
                                                const float* __restrict__ g2v,
                                                const float* __restrict__ b2v,
                                                float* __restrict__ out,
                                                unsigned short* __restrict__ outb) {
    int idx = blockIdx.x * 256 + threadIdx.x;
    int c4 = (idx & 31) * 4;
    const float inv_n = 1.f / N_NODES;
    float sc1[4], sh1[4], sc2[4], sh2[4];
#pragma unroll
    for (int c = 0; c < 4; ++c) {
        int ch = c4 + c;
        float m1 = st1[ch] * inv_n;
        float v1 = st1[C_DIM + ch] * inv_n - m1 * m1;
        float r1 = rsqrtf(v1 + 1e-5f);
        sc1[c] = g1v[ch] * r1; sh1[c] = b1v[ch] - m1 * sc1[c];
        float m2 = st2[ch] * inv_n;
        float v2 = st2[C_DIM + ch] * inv_n - m2 * m2;
        float r2 = rsqrtf(v2 + 1e-5f);
        sc2[c] = g2v[ch] * r2; sh2[c] = b2v[ch] - m2 * sc2[c];
    }
    float4 v1 = ((const float4*)p1)[idx];
    float4 v2 = ((const float4*)p2)[idx];
    float4 o;
    o.x = v1.x * sc1[0] + sh1[0] + v2.x * sc2[0] + sh2[0];
    o.y = v1.y * sc1[1] + sh1[1] + v2.y * sc2[1] + sh2[1];
    o.z = v1.z * sc1[2] + sh1[2] + v2.z * sc2[2] + sh2[2];
    o.w = v1.w * sc1[3] + sh1[3] + v2.w * sc2[3] + sh2[3];
    ((float4*)out)[idx] = o;
    ushort4 ub;
    ub.x = f2bf(o.x); ub.y = f2bf(o.y); ub.z = f2bf(o.z); ub.w = f2bf(o.w);
    *(ushort4*)(outb + (size_t)idx * 4) = ub;
}

// x = bn3(m3), scales inline from raw sums (R9-proven)
__global__ __launch_bounds__(256) void bn_apply(const float* __restrict__ p,
                                                const float* __restrict__ st,
                                                const float* __restrict__ gv,
                                                const float* __restrict__ bv,
                                                float* __restrict__ out,
                                                unsigned short* __restrict__ outb) {
    int idx = blockIdx.x * 256 + threadIdx.x;
    int c4 = (idx & 31) * 4;
    const float inv_n = 1.f / N_NODES;
    float sc[4], sh[4];
#pragma unroll
    for (int c = 0; c < 4; ++c) {
        int ch = c4 + c;
        float m = st[ch] * inv_n;
        float vv = st[C_DIM + ch] * inv_n - m * m;
        float r = rsqrtf(vv + 1e-5f);
        sc[c] = gv[ch] * r; sh[c] = bv[ch] - m * sc[c];
    }
    float4 v = ((const float4*)p)[idx];
    float4 o;
    o.x = v.x * sc[0] + sh[0];
    o.y = v.y * sc[1] + sh[1];
    o.z = v.z * sc[2] + sh[2];
    o.w = v.w * sc[3] + sh[3];
    ((float4*)out)[idx] = o;
    ushort4 ub;
    ub.x = f2bf(o.x); ub.y = f2bf(o.y); ub.z = f2bf(o.z); ub.w = f2bf(o.w);
    *(ushort4*)(outb + (size_t)idx * 4) = ub;
}

// ---------------------------------------------------------------------------
// Fused head MLP
// ---------------------------------------------------------------------------
__global__ __launch_bounds__(256) void head_fused(const float* __restrict__ x,
                                                  const float* __restrict__ w1,
                                                  const float* __restrict__ b1,
                                                  const float* __restrict__ w2,
                                                  const float* __restrict__ b2,
                                                  const float* __restrict__ w3,
                                                  const float* __restrict__ b3,
                                                  float* __restrict__ out) {
    __shared__ __align__(16) float xs[8][128];
    __shared__ __align__(16) float hs[8][64];
    const int tid = threadIdx.x;
    const int n = tid >> 5;
    const int g = tid & 31;
    const int node0 = blockIdx.x * 8;

    {
        int r = tid >> 5, q = tid & 31;
        *(float4*)(&xs[r][q * 4]) = *(const float4*)(x + (size_t)(node0 + r) * 128 + q * 4);
    }
    __syncthreads();

    {
        float acc0 = b1[g], acc1 = b1[g + 32];
        const float* wa = w1 + (size_t)g * 128;
        const float* wb = w1 + (size_t)(g + 32) * 128;
#pragma unroll 8
        for (int k = 0; k < 128; k += 4) {
            float4 xv = *(const float4*)(&xs[n][k]);
            float4 va = *(const float4*)(wa + k);
            float4 vb = *(const float4*)(wb + k);
            acc0 += xv.x * va.x + xv.y * va.y + xv.z * va.z + xv.w * va.w;
            acc1 += xv.x * vb.x + xv.y * vb.y + xv.z * vb.z + xv.w * vb.w;
        }
        hs[n][g]      = fmaxf(acc0, 0.f);
        hs[n][g + 32] = fmaxf(acc1, 0.f);
    }
    __syncthreads();

    {
        float acc = b2[g];
        const float* wr = w2 + (size_t)g * 64;
#pragma unroll 8
        for (int k = 0; k < 64; k += 4) {
            float4 hv = *(const float4*)(&hs[n][k]);
            float4 wv = *(const float4*)(wr + k);
            acc += hv.x * wv.x + hv.y * wv.y + hv.z * wv.z + hv.w * wv.w;
        }
        float t = fmaxf(acc, 0.f) * w3[g];
#pragma unroll
        for (int off = 1; off < 32; off <<= 1) t += __shfl_xor(t, off, 64);
        if (g == 0) out[node0 + n] = t + b3[0];
    }
}

// ---------------------------------------------------------------------------
extern "C" void kernel_launch(void* const* d_in, const int* in_sizes, int n_in,
                              void* d_out, int out_size, void* d_ws, size_t ws_size,
                              hipStream_t stream) {
    (void)in_sizes; (void)n_in; (void)out_size; (void)ws_size;
    const float* x_in   = (const float*)d_in[0];
    const int*   ei     = (const int*)d_in[1];
    const float* gin_w1 = (const float*)d_in[2];
    const float* gin_b1 = (const float*)d_in[3];
    const float* gin_w2 = (const float*)d_in[4];
    const float* gin_b2 = (const float*)d_in[5];
    const float* ain_w  = (const float*)d_in[6];
    const float* ain_b  = (const float*)d_in[7];
    const float* aout_w = (const float*)d_in[8];
    const float* aout_b = (const float*)d_in[9];
    const float* n1_g   = (const float*)d_in[10];
    const float* n1_b   = (const float*)d_in[11];
    const float* n2_g   = (const float*)d_in[12];
    const float* n2_b   = (const float*)d_in[13];
    const float* n3_g   = (const float*)d_in[14];
    const float* n3_b   = (const float*)d_in[15];
    const float* mlp_w1 = (const float*)d_in[16];
    const float* mlp_b1 = (const float*)d_in[17];
    const float* mlp_w2 = (const float*)d_in[18];
    const float* mlp_b2 = (const float*)d_in[19];
    const float* h_w1   = (const float*)d_in[20];
    const float* h_b1   = (const float*)d_in[21];
    const float* h_w2   = (const float*)d_in[22];
    const float* h_b2   = (const float*)d_in[23];
    const float* h_w3   = (const float*)d_in[24];
    const float* h_b3   = (const float*)d_in[25];

    float* f = (float*)d_ws;
    float* g1   = f;                 // c0; m3 aliases (g1 dead after combine2)
    float* m3   = f;
    float* a2   = f + 1 * (size_t)NC;
    float* hbuf = f + 2 * (size_t)NC;
    float* xA   = f + 3 * (size_t)NC;
    float* xB   = f + 4 * (size_t)NC;
    unsigned short* R1  = (unsigned short*)(f + 5 * (size_t)NC);  // 3 NCu
    unsigned short* hsum_bf = R1;
    unsigned short* t1_bf   = R1 + (size_t)NCu;
    unsigned short* Qb      = R1;
    unsigned short* Kb      = R1 + (size_t)NCu;
    unsigned short* VT      = R1 + 2 * (size_t)NCu;
    unsigned short* t2_bf   = R1;
    unsigned short* R2      = R1 + 3 * (size_t)NCu;
    unsigned short* ao_bf   = R2;
    unsigned short* hbuf_bf = R2;
    unsigned short* xbf     = R2 + (size_t)NCu;
    unsigned short* wbf     = xbf + (size_t)NCu;
    float* ss    = (float*)(wbf + 655360);   // 768 raw sums (3 BNs)
    int* ibase    = (int*)(ss + 768);
    int* deg      = ibase;
    int* rowstart = ibase + 4096;
    int* cursor   = ibase + 4096 + 4098;
    int* csr_src  = ibase + 4096 + 4098 + 4096;

    const int OG1 = 0, OG2 = 65536, OAI = 131072, OAO = 327680, OM1 = 393216, OM2 = 524288;

    hipMemsetAsync(deg, 0, 4096 * sizeof(int), stream);
    hist_kernel<<<E_EDGES / 256, 256, 0, stream>>>(ei, deg);
    scan_kernel<<<1, 256, 0, stream>>>(deg, rowstart, cursor);
    fill_kernel<<<E_EDGES / 256, 256, 0, stream>>>(ei, cursor, csr_src);
    wcvt<<<320, 256, 0, stream>>>(gin_w1, gin_w2, ain_w, aout_w, mlp_w1, mlp_w2, wbf);
    x2bf<<<NC / 2048, 256, 0, stream>>>(x_in, xbf);

    for (int i = 0; i < L_LAYERS; ++i) {
        const float* xin = (i == 0) ? x_in : ((i & 1) ? xA : xB);
        float* xout = (i & 1) ? xB : xA;
        const float* gb1 = gin_b1 + (size_t)i * C_DIM;
        const float* gb2 = gin_b2 + (size_t)i * C_DIM;
        const float* aib = ain_b + (size_t)i * 3 * C_DIM;
        const float* aob = aout_b + (size_t)i * C_DIM;
        const float* mb1 = mlp_b1 + (size_t)i * 2 * C_DIM;
        const float* mb2 = mlp_b2 + (size_t)i * C_DIM;

        // GIN branch (gather zeroes ss for this layer's fused BN stats)
        gather_agg<<<N_NODES / 4, 256, 0, stream>>>(xbf, rowstart, csr_src,
                                                    (unsigned int*)hsum_bf, ss);
        gemm_bf<128><<<dim3(2, 256), 256, 0, stream>>>(hsum_bf, wbf + OG1 + (size_t)i * 16384,
                                                       gb1, nullptr, nullptr, t1_bf, nullptr, 128, 1);
        gemm_bf<128><<<dim3(2, 256), 256, 0, stream>>>(t1_bf, wbf + OG2 + (size_t)i * 16384,
                                                       gb2, xin, g1, nullptr, ss, 128, 0);
        // attention branch
        gemm_qkv_bf<<<dim3(6, 256), 256, 0, stream>>>(xbf, wbf + OAI + (size_t)i * 49152,
                                                      aib, Qb, Kb, VT);
        attn_kernel<<<dim3(N_NODES / 32, H_HEADS), 512, 0, stream>>>(Qb, Kb, VT, ao_bf);
        gemm_bf<128><<<dim3(2, 256), 256, 0, stream>>>(ao_bf, wbf + OAO + (size_t)i * 16384,
                                                       aob, xin, a2, nullptr, ss + 256, 128, 0);
        // combine (BN scales inline from fused stats)
        combine2<<<512, 256, 0, stream>>>(g1, a2, ss, ss + 256,
                                          n1_g + (size_t)i * C_DIM, n1_b + (size_t)i * C_DIM,
                                          n2_g + (size_t)i * C_DIM, n2_b + (size_t)i * C_DIM,
                                          hbuf, hbuf_bf);
        // MLP
        gemm_bf<128><<<dim3(4, 256), 256, 0, stream>>>(hbuf_bf, wbf + OM1 + (size_t)i * 32768,
                                                       mb1, nullptr, nullptr, t2_bf, nullptr, 256, 1);
        gemm_bf<256><<<dim3(2, 256), 256, 0, stream>>>(t2_bf, wbf + OM2 + (size_t)i * 32768,
                                                       mb2, hbuf, m3, nullptr, ss + 512, 128, 0);
        // final BN
        bn_apply<<<512, 256, 0, stream>>>(m3, ss + 512,
                                          n3_g + (size_t)i * C_DIM, n3_b + (size_t)i * C_DIM,
                                          xout, xbf);
    }

    const float* xf = xB;  // after layer 3
    head_fused<<<N_NODES / 8, 256, 0, stream>>>(xf, h_w1, h_b1, h_w2, h_b2, h_w3, h_b3,
                                                (float*)d_out);
}

// Round 13
// 453.527 us; speedup vs baseline: 1.1094x; 1.0334x over previous
//
#include <hip/hip_runtime.h>

#define N_NODES 4096
#define C_DIM   128
#define L_LAYERS 4
#define E_EDGES 131072
#define H_HEADS 4
#define D_HEAD  32
#define NC      (N_NODES * C_DIM)
#define NCu     (N_NODES * C_DIM)
#define P_STRIDE 136

typedef short bf16x8 __attribute__((ext_vector_type(8)));
typedef float f32x4  __attribute__((ext_vector_type(4)));

__device__ __forceinline__ unsigned short f2bf(float f) {
    unsigned int u = __float_as_uint(f);
    u += 0x7fffu + ((u >> 16) & 1u);
    return (unsigned short)(u >> 16);
}

__device__ __forceinline__ float bf_lo(unsigned int u) { return __uint_as_float(u << 16); }
__device__ __forceinline__ float bf_hi(unsigned int u) { return __uint_as_float(u & 0xffff0000u); }

__device__ __forceinline__ bf16x8 pack8(const float* v) {
    bf16x8 o;
#pragma unroll
    for (int i = 0; i < 8; ++i) o[i] = (short)f2bf(v[i]);
    return o;
}

// ---------------------------------------------------------------------------
// CSR build (once per launch)
// ---------------------------------------------------------------------------
__global__ __launch_bounds__(256) void hist_kernel(const int* __restrict__ ei,
                                                   int* __restrict__ deg) {
    int e = blockIdx.x * 256 + threadIdx.x;
    atomicAdd(&deg[ei[E_EDGES + e]], 1);
}

__global__ __launch_bounds__(256) void scan_kernel(const int* __restrict__ deg,
                                                   int* __restrict__ rowstart,
                                                   int* __restrict__ cursor) {
    __shared__ int ts[256];
    const int tid = threadIdx.x;
    int loc[16];
    int s = 0;
#pragma unroll
    for (int i = 0; i < 16; ++i) { loc[i] = s; s += deg[tid * 16 + i]; }
    ts[tid] = s;
    __syncthreads();
    for (int off = 1; off < 256; off <<= 1) {
        int t = (tid >= off) ? ts[tid - off] : 0;
        __syncthreads();
        if (tid >= off) ts[tid] += t;
        __syncthreads();
    }
    int off0 = ts[tid] - s;
#pragma unroll
    for (int i = 0; i < 16; ++i) {
        int v = off0 + loc[i];
        rowstart[tid * 16 + i] = v;
        cursor[tid * 16 + i] = v;
    }
    if (tid == 255) rowstart[4096] = off0 + s;
}

__global__ __launch_bounds__(256) void fill_kernel(const int* __restrict__ ei,
                                                   int* __restrict__ cursor,
                                                   int* __restrict__ csr_src) {
    int e = blockIdx.x * 256 + threadIdx.x;
    int d = ei[E_EDGES + e];
    int s = ei[e];
    int p = atomicAdd(&cursor[d], 1);
    csr_src[p] = s;
}

// ---------------------------------------------------------------------------
// weight pre-convert fp32 -> bf16
// ---------------------------------------------------------------------------
__global__ __launch_bounds__(256) void wcvt(const float* __restrict__ s0, const float* __restrict__ s1,
                                            const float* __restrict__ s2, const float* __restrict__ s3,
                                            const float* __restrict__ s4, const float* __restrict__ s5,
                                            unsigned short* __restrict__ wbf) {
    int i0 = (blockIdx.x * 256 + threadIdx.x) * 8;
    const float* src; int base;
    if      (i0 < 65536)  { src = s0; base = 0; }
    else if (i0 < 131072) { src = s1; base = 65536; }
    else if (i0 < 327680) { src = s2; base = 131072; }
    else if (i0 < 393216) { src = s3; base = 327680; }
    else if (i0 < 524288) { src = s4; base = 393216; }
    else                  { src = s5; base = 524288; }
    const float* p = src + (i0 - base);
    float t[8];
#pragma unroll
    for (int i = 0; i < 8; ++i) t[i] = p[i];
    *(bf16x8*)(wbf + i0) = pack8(t);
}

__global__ __launch_bounds__(256) void x2bf(const float* __restrict__ x,
                                            unsigned short* __restrict__ xb) {
    int i0 = (blockIdx.x * 256 + threadIdx.x) * 8;
    float t[8];
#pragma unroll
    for (int i = 0; i < 8; ++i) t[i] = x[i0 + i];
    *(bf16x8*)(xb + i0) = pack8(t);
}

// ---------------------------------------------------------------------------
// Fused QKV-GEMM + GIN-gather (independent work, both read xbf only).
// blocks 0..1535: QKV GEMM (ct = b%6, rt = b/6) -> Qb/Kb/VT epilogue.
// blocks 1536..2559: gather (node = (b-1536)*4 + tid/64); block 1536 also
// zeroes the per-layer BN stats buffer (768 floats, stream-ordered before
// all stats-producing GEMMs of this layer).
// ---------------------------------------------------------------------------
__global__ __launch_bounds__(256, 8) void qkv_gather(const unsigned short* __restrict__ xb,
                                                     const unsigned short* __restrict__ Wbf,
                                                     const float* __restrict__ bias,
                                                     unsigned short* __restrict__ Qb,
                                                     unsigned short* __restrict__ Kb,
                                                     unsigned short* __restrict__ VT,
                                                     const int* __restrict__ rowstart,
                                                     const int* __restrict__ csr_src,
                                                     unsigned int* __restrict__ hsum,
                                                     float* __restrict__ ssz) {
    const int b = blockIdx.x;
    const int tid = threadIdx.x;
    if (b < 1536) {
        const int ct = b % 6, rt = b / 6;
        const int wv = tid >> 6;
        const int lane = tid & 63, lg = lane >> 4, ll = lane & 15;
        const int rowbase = rt * 16;
        const int colbase = ct * 64 + wv * 16;

        const unsigned short* Ap = xb  + (size_t)(rowbase + ll) * 128 + lg * 8;
        const unsigned short* Wp = Wbf + (size_t)(colbase + ll) * 128 + lg * 8;

        f32x4 acc = {0.f, 0.f, 0.f, 0.f};
#pragma unroll
        for (int k = 0; k < 128; k += 32) {
            bf16x8 a = *(const bf16x8*)(Ap + k);
            bf16x8 w = *(const bf16x8*)(Wp + k);
            acc = __builtin_amdgcn_mfma_f32_16x16x32_bf16(a, w, acc, 0, 0, 0);
        }

        const float qsc = 0.25506973f;  // (1/sqrt(32)) * log2(e)
        const int col = colbase + ll;
        const float bi = bias[col];
#pragma unroll
        for (int r = 0; r < 4; ++r) {
            const int row = rowbase + lg * 4 + r;
            float v = acc[r] + bi;
            if (col < 128) {
                int hh = col >> 5, d = col & 31;
                Qb[((size_t)hh * N_NODES + row) * D_HEAD + d] = f2bf(v * qsc);
            } else if (col < 256) {
                int c2 = col - 128, hh = c2 >> 5, d = c2 & 31;
                Kb[((size_t)hh * N_NODES + row) * D_HEAD + d] = f2bf(v);
            } else {
                int c2 = col - 256, hh = c2 >> 5, d = c2 & 31;
                VT[((size_t)hh * D_HEAD + d) * N_NODES + row] = f2bf(v);
            }
        }
    } else {
        if (b == 1536) {
            ssz[tid] = 0.f; ssz[256 + tid] = 0.f; ssz[512 + tid] = 0.f;
        }
        const int node = (b - 1536) * 4 + (tid >> 6);
        const int lane = tid & 63;
        const unsigned int* xu = (const unsigned int*)xb;
        const int beg = rowstart[node], end = rowstart[node + 1];
        unsigned int su = xu[(size_t)node * 64 + lane];
        float ax = bf_lo(su), ay = bf_hi(su);
        float bx = 0.f, by = 0.f;
        int e = beg;
        for (; e + 4 <= end; e += 4) {
            int s0 = csr_src[e], s1 = csr_src[e + 1], s2 = csr_src[e + 2], s3 = csr_src[e + 3];
            unsigned int u0 = xu[(size_t)s0 * 64 + lane];
            unsigned int u1 = xu[(size_t)s1 * 64 + lane];
            unsigned int u2 = xu[(size_t)s2 * 64 + lane];
            unsigned int u3 = xu[(size_t)s3 * 64 + lane];
            ax += bf_lo(u0) + bf_lo(u1); ay += bf_hi(u0) + bf_hi(u1);
            bx += bf_lo(u2) + bf_lo(u3); by += bf_hi(u2) + bf_hi(u3);
        }
        for (; e < end; ++e) {
            unsigned int u0 = xu[(size_t)csr_src[e] * 64 + lane];
            ax += bf_lo(u0); ay += bf_hi(u0);
        }
        float ox = ax + bx, oy = ay + by;
        hsum[(size_t)node * 64 + lane] = (unsigned int)f2bf(ox) | ((unsigned int)f2bf(oy) << 16);
    }
}

// ---------------------------------------------------------------------------
// bf16 MFMA GEMM, LDS-free, 16x16 tile per wave. grid (J/64, N/16).
// Optional fused BatchNorm stats (2 wave-reduced atomics per column).
// ---------------------------------------------------------------------------
template <int K>
__global__ __launch_bounds__(256, 8) void gemm_bf(const unsigned short* __restrict__ Abf,
                                                  const unsigned short* __restrict__ Wbf,
                                                  const float* __restrict__ bias,
                                                  const float* __restrict__ resid,
                                                  float* __restrict__ outf,
                                                  unsigned short* __restrict__ outb,
                                                  float* __restrict__ stats,
                                                  const int J, const int relu) {
    const int tid = threadIdx.x;
    const int wv = tid >> 6;
    const int lane = tid & 63, lg = lane >> 4, ll = lane & 15;
    const int rowbase = blockIdx.y * 16;
    const int colbase = blockIdx.x * 64 + wv * 16;

    const unsigned short* Ap = Abf + (size_t)(rowbase + ll) * K + lg * 8;
    const unsigned short* Wp = Wbf + (size_t)(colbase + ll) * K + lg * 8;

    f32x4 acc = {0.f, 0.f, 0.f, 0.f};
#pragma unroll
    for (int k = 0; k < K; k += 32) {
        bf16x8 a = *(const bf16x8*)(Ap + k);
        bf16x8 b = *(const bf16x8*)(Wp + k);
        acc = __builtin_amdgcn_mfma_f32_16x16x32_bf16(a, b, acc, 0, 0, 0);
    }

    const int col = colbase + ll;
    const float bi = bias[col];
    float sv = 0.f, sv2 = 0.f;
#pragma unroll
    for (int r = 0; r < 4; ++r) {
        const int row = rowbase + lg * 4 + r;
        float v = acc[r] + bi;
        if (resid) v += resid[(size_t)row * J + col];
        if (relu) v = fmaxf(v, 0.f);
        if (outf) outf[(size_t)row * J + col] = v;
        if (outb) outb[(size_t)row * J + col] = f2bf(v);
        sv += v; sv2 += v * v;
    }
    if (stats) {
        sv  += __shfl_xor(sv, 16, 64);  sv  += __shfl_xor(sv, 32, 64);
        sv2 += __shfl_xor(sv2, 16, 64); sv2 += __shfl_xor(sv2, 32, 64);
        if (lg == 0) {
            atomicAdd(&stats[col], sv);
            atomicAdd(&stats[C_DIM + col], sv2);
        }
    }
}

// ---------------------------------------------------------------------------
// Flash attention v4 (R7/R11/R12 verified, byte-for-byte unchanged):
// grid (N/32, H), 512 thr = 8 waves; wave = 2 q-fragments x 512-key range.
// ---------------------------------------------------------------------------
__global__ __launch_bounds__(512, 4) void attn_kernel(const unsigned short* __restrict__ Qb,
                                                      const unsigned short* __restrict__ Kb,
                                                      const unsigned short* __restrict__ VT,
                                                      unsigned short* __restrict__ ob) {
    __shared__ __align__(16) unsigned short Pl[8 * 32 * P_STRIDE];
    float (*Ouns)[32][33] = (float (*)[32][33])(void*)Pl;
    float (*Llp)[32] = (float (*)[32])(void*)(Pl + 8 * 32 * 33 * 2);

    const int h   = blockIdx.y;
    const int q0  = blockIdx.x * 32;
    const int tid = threadIdx.x;
    const int wv  = tid >> 6;
    const int lane = tid & 63;
    const int lg  = lane >> 4;
    const int ll  = lane & 15;

    const unsigned short* Qh = Qb + ((size_t)h * N_NODES + q0) * D_HEAD;
    const unsigned short* Kh = Kb + (size_t)h * N_NODES * D_HEAD;
    const unsigned short* Vh = VT + (size_t)h * D_HEAD * N_NODES;

    bf16x8 qf0 = *(const bf16x8*)(Qh + ll * D_HEAD + lg * 8);
    bf16x8 qf1 = *(const bf16x8*)(Qh + (16 + ll) * D_HEAD + lg * 8);

    f32x4 oacc00 = {0.f,0.f,0.f,0.f}, oacc01 = {0.f,0.f,0.f,0.f};
    f32x4 oacc10 = {0.f,0.f,0.f,0.f}, oacc11 = {0.f,0.f,0.f,0.f};
    float l0[4] = {0.f,0.f,0.f,0.f}, l1[4] = {0.f,0.f,0.f,0.f};

    unsigned short* Pw = Pl + wv * (32 * P_STRIDE);
    const int k0 = wv * (N_NODES / 8);

    for (int t = 0; t < (N_NODES / 8) / 128; ++t) {
        const int kt = k0 + t * 128;

        float s0[8][4], s1[8][4];
#pragma unroll
        for (int kc = 0; kc < 8; ++kc) {
            bf16x8 kf = *(const bf16x8*)(Kh + (size_t)(kt + kc * 16 + ll) * D_HEAD + lg * 8);
            f32x4 z = {0.f, 0.f, 0.f, 0.f};
            f32x4 d0 = __builtin_amdgcn_mfma_f32_16x16x32_bf16(qf0, kf, z, 0, 0, 0);
            f32x4 d1 = __builtin_amdgcn_mfma_f32_16x16x32_bf16(qf1, kf, z, 0, 0, 0);
#pragma unroll
            for (int r = 0; r < 4; ++r) { s0[kc][r] = d0[r]; s1[kc][r] = d1[r]; }
        }

#pragma unroll
        for (int r = 0; r < 4; ++r) {
            float a = 0.f, b = 0.f;
#pragma unroll
            for (int kc = 0; kc < 8; ++kc) {
                float p0 = exp2f(s0[kc][r]); s0[kc][r] = p0; a += p0;
                float p1 = exp2f(s1[kc][r]); s1[kc][r] = p1; b += p1;
            }
#pragma unroll
            for (int off = 1; off < 16; off <<= 1) {
                a += __shfl_xor(a, off, 64);
                b += __shfl_xor(b, off, 64);
            }
            l0[r] += a;
            l1[r] += b;
        }

#pragma unroll
        for (int kc = 0; kc < 8; ++kc)
#pragma unroll
            for (int r = 0; r < 4; ++r) {
                Pw[(lg * 4 + r) * P_STRIDE + kc * 16 + ll]      = f2bf(s0[kc][r]);
                Pw[(16 + lg * 4 + r) * P_STRIDE + kc * 16 + ll] = f2bf(s1[kc][r]);
            }
        asm volatile("" ::: "memory");

#pragma unroll
        for (int kc2 = 0; kc2 < 4; ++kc2) {
            bf16x8 va = *(const bf16x8*)(Vh + (size_t)ll * N_NODES + kt + kc2 * 32 + lg * 8);
            bf16x8 vb = *(const bf16x8*)(Vh + (size_t)(16 + ll) * N_NODES + kt + kc2 * 32 + lg * 8);
            bf16x8 pf0 = *(const bf16x8*)(Pw + ll * P_STRIDE + kc2 * 32 + lg * 8);
            bf16x8 pf1 = *(const bf16x8*)(Pw + (16 + ll) * P_STRIDE + kc2 * 32 + lg * 8);
            oacc00 = __builtin_amdgcn_mfma_f32_16x16x32_bf16(pf0, va, oacc00, 0, 0, 0);
            oacc01 = __builtin_amdgcn_mfma_f32_16x16x32_bf16(pf0, vb, oacc01, 0, 0, 0);
            oacc10 = __builtin_amdgcn_mfma_f32_16x16x32_bf16(pf1, va, oacc10, 0, 0, 0);
            oacc11 = __builtin_amdgcn_mfma_f32_16x16x32_bf16(pf1, vb, oacc11, 0, 0, 0);
        }
    }

    __syncthreads();

#pragma unroll
    for (int r = 0; r < 4; ++r) {
        Ouns[wv][lg * 4 + r][ll]           = oacc00[r];
        Ouns[wv][lg * 4 + r][16 + ll]      = oacc01[r];
        Ouns[wv][16 + lg * 4 + r][ll]      = oacc10[r];
        Ouns[wv][16 + lg * 4 + r][16 + ll] = oacc11[r];
    }
    if (ll == 0) {
#pragma unroll
        for (int r = 0; r < 4; ++r) {
            Llp[wv][lg * 4 + r]      = l0[r];
            Llp[wv][16 + lg * 4 + r] = l1[r];
        }
    }
    __syncthreads();

    {
        const int row = tid >> 4, col = tid & 15;
        float L = 0.f, oa = 0.f, obv = 0.f;
#pragma unroll
        for (int w = 0; w < 8; ++w) {
            L   += Llp[w][row];
            oa  += Ouns[w][row][col];
            obv += Ouns[w][row][16 + col];
        }
        float inv = 1.f / L;
        ob[(size_t)(q0 + row) * C_DIM + h * D_HEAD + col]      = f2bf(oa * inv);
        ob[(size_t)(q0 + row) * C_DIM + h * D_HEAD + 16 + col] = f2bf(obv * inv);
    }
}

// ---------------------------------------------------------------------------
// h = bn1(g1)+bn2(a2) with BN scales computed inline from raw sums
// ---------------------------------------------------------------------------
__global__ __launch_bounds__(256) void combine2(const float* __restrict__ p1,
                                                const float* __restrict__ p2,
                                                const float* __restrict__ st1,
                                                const float* __restrict__ st2,
                                                const float* __restrict__ g1v,
                                                const float* __restrict__ b1v,
                                                const float* __restrict__ g2v,
                                                const float* __restrict__ b2v,
                                                float* __restrict__ out,
                                                unsigned short* __restrict__ outb) {
    int idx = blockIdx.x * 256 + threadIdx.x;
    int c4 = (idx & 31) * 4;
    const float inv_n = 1.f / N_NODES;
    float sc1[4], sh1[4], sc2[4], sh2[4];
#pragma unroll
    for (int c = 0; c < 4; ++c) {
        int ch = c4 + c;
        float m1 = st1[ch] * inv_n;
        float v1 = st1[C_DIM + ch] * inv_n - m1 * m1;
        float r1 = rsqrtf(v1 + 1e-5f);
        sc1[c] = g1v[ch] * r1; sh1[c] = b1v[ch] - m1 * sc1[c];
        float m2 = st2[ch] * inv_n;
        float v2 = st2[C_DIM + ch] * inv_n - m2 * m2;
        float r2 = rsqrtf(v2 + 1e-5f);
        sc2[c] = g2v[ch] * r2; sh2[c] = b2v[ch] - m2 * sc2[c];
    }
    float4 v1 = ((const float4*)p1)[idx];
    float4 v2 = ((const float4*)p2)[idx];
    float4 o;
    o.x = v1.x * sc1[0] + sh1[0] + v2.x * sc2[0] + sh2[0];
    o.y = v1.y * sc1[1] + sh1[1] + v2.y * sc2[1] + sh2[1];
    o.z = v1.z * sc1[2] + sh1[2] + v2.z * sc2[2] + sh2[2];
    o.w = v1.w * sc1[3] + sh1[3] + v2.w * sc2[3] + sh2[3];
    ((float4*)out)[idx] = o;
    ushort4 ub;
    ub.x = f2bf(o.x); ub.y = f2bf(o.y); ub.z = f2bf(o.z); ub.w = f2bf(o.w);
    *(ushort4*)(outb + (size_t)idx * 4) = ub;
}

// x = bn3(m3), scales inline from raw sums
__global__ __launch_bounds__(256) void bn_apply(const float* __restrict__ p,
                                                const float* __restrict__ st,
                                                const float* __restrict__ gv,
                                                const float* __restrict__ bv,
                                                float* __restrict__ out,
                                                unsigned short* __restrict__ outb) {
    int idx = blockIdx.x * 256 + threadIdx.x;
    int c4 = (idx & 31) * 4;
    const float inv_n = 1.f / N_NODES;
    float sc[4], sh[4];
#pragma unroll
    for (int c = 0; c < 4; ++c) {
        int ch = c4 + c;
        float m = st[ch] * inv_n;
        float vv = st[C_DIM + ch] * inv_n - m * m;
        float r = rsqrtf(vv + 1e-5f);
        sc[c] = gv[ch] * r; sh[c] = bv[ch] - m * sc[c];
    }
    float4 v = ((const float4*)p)[idx];
    float4 o;
    o.x = v.x * sc[0] + sh[0];
    o.y = v.y * sc[1] + sh[1];
    o.z = v.z * sc[2] + sh[2];
    o.w = v.w * sc[3] + sh[3];
    ((float4*)out)[idx] = o;
    ushort4 ub;
    ub.x = f2bf(o.x); ub.y = f2bf(o.y); ub.z = f2bf(o.z); ub.w = f2bf(o.w);
    *(ushort4*)(outb + (size_t)idx * 4) = ub;
}

// ---------------------------------------------------------------------------
// Fused head MLP
// ---------------------------------------------------------------------------
__global__ __launch_bounds__(256) void head_fused(const float* __restrict__ x,
                                                  const float* __restrict__ w1,
                                                  const float* __restrict__ b1,
                                                  const float* __restrict__ w2,
                                                  const float* __restrict__ b2,
                                                  const float* __restrict__ w3,
                                                  const float* __restrict__ b3,
                                                  float* __restrict__ out) {
    __shared__ __align__(16) float xs[8][128];
    __shared__ __align__(16) float hs[8][64];
    const int tid = threadIdx.x;
    const int n = tid >> 5;
    const int g = tid & 31;
    const int node0 = blockIdx.x * 8;

    {
        int r = tid >> 5, q = tid & 31;
        *(float4*)(&xs[r][q * 4]) = *(const float4*)(x + (size_t)(node0 + r) * 128 + q * 4);
    }
    __syncthreads();

    {
        float acc0 = b1[g], acc1 = b1[g + 32];
        const float* wa = w1 + (size_t)g * 128;
        const float* wb = w1 + (size_t)(g + 32) * 128;
#pragma unroll 8
        for (int k = 0; k < 128; k += 4) {
            float4 xv = *(const float4*)(&xs[n][k]);
            float4 va = *(const float4*)(wa + k);
            float4 vb = *(const float4*)(wb + k);
            acc0 += xv.x * va.x + xv.y * va.y + xv.z * va.z + xv.w * va.w;
            acc1 += xv.x * vb.x + xv.y * vb.y + xv.z * vb.z + xv.w * vb.w;
        }
        hs[n][g]      = fmaxf(acc0, 0.f);
        hs[n][g + 32] = fmaxf(acc1, 0.f);
    }
    __syncthreads();

    {
        float acc = b2[g];
        const float* wr = w2 + (size_t)g * 64;
#pragma unroll 8
        for (int k = 0; k < 64; k += 4) {
            float4 hv = *(const float4*)(&hs[n][k]);
            float4 wv = *(const float4*)(wr + k);
            acc += hv.x * wv.x + hv.y * wv.y + hv.z * wv.z + hv.w * wv.w;
        }
        float t = fmaxf(acc, 0.f) * w3[g];
#pragma unroll
        for (int off = 1; off < 32; off <<= 1) t += __shfl_xor(t, off, 64);
        if (g == 0) out[node0 + n] = t + b3[0];
    }
}

// ---------------------------------------------------------------------------
extern "C" void kernel_launch(void* const* d_in, const int* in_sizes, int n_in,
                              void* d_out, int out_size, void* d_ws, size_t ws_size,
                              hipStream_t stream) {
    (void)in_sizes; (void)n_in; (void)out_size; (void)ws_size;
    const float* x_in   = (const float*)d_in[0];
    const int*   ei     = (const int*)d_in[1];
    const float* gin_w1 = (const float*)d_in[2];
    const float* gin_b1 = (const float*)d_in[3];
    const float* gin_w2 = (const float*)d_in[4];
    const float* gin_b2 = (const float*)d_in[5];
    const float* ain_w  = (const float*)d_in[6];
    const float* ain_b  = (const float*)d_in[7];
    const float* aout_w = (const float*)d_in[8];
    const float* aout_b = (const float*)d_in[9];
    const float* n1_g   = (const float*)d_in[10];
    const float* n1_b   = (const float*)d_in[11];
    const float* n2_g   = (const float*)d_in[12];
    const float* n2_b   = (const float*)d_in[13];
    const float* n3_g   = (const float*)d_in[14];
    const float* n3_b   = (const float*)d_in[15];
    const float* mlp_w1 = (const float*)d_in[16];
    const float* mlp_b1 = (const float*)d_in[17];
    const float* mlp_w2 = (const float*)d_in[18];
    const float* mlp_b2 = (const float*)d_in[19];
    const float* h_w1   = (const float*)d_in[20];
    const float* h_b1   = (const float*)d_in[21];
    const float* h_w2   = (const float*)d_in[22];
    const float* h_b2   = (const float*)d_in[23];
    const float* h_w3   = (const float*)d_in[24];
    const float* h_b3   = (const float*)d_in[25];

    float* f = (float*)d_ws;
    float* g1   = f;                   // c0 (m3 aliases; g1 dead after combine2)
    float* m3   = f;
    float* a2   = f + 1 * (size_t)NC;  // c1
    float* hbuf = f + 2 * (size_t)NC;  // c2 (t1_bf ushort overlay during GIN)
    float* xA   = f + 3 * (size_t)NC;
    float* xB   = f + 4 * (size_t)NC;
    unsigned short* R1  = (unsigned short*)(f + 5 * (size_t)NC);  // 3 NCu
    unsigned short* Qb      = R1;
    unsigned short* Kb      = R1 + (size_t)NCu;
    unsigned short* VT      = R1 + 2 * (size_t)NCu;
    unsigned short* t2_bf   = R1;                    // MLP1 out (QKV dead by then)
    unsigned short* R2      = R1 + 3 * (size_t)NCu;  // 1 NCu
    unsigned short* hsum_bf = R2;                    // gather out (dead after gin1)
    unsigned short* ao_bf   = R2;                    // attn out (written after gin1)
    unsigned short* hbuf_bf = R2;                    // combine out (after aout)
    unsigned short* t1_bf   = (unsigned short*)hbuf; // gin1 out (dead before combine2)
    unsigned short* xbf     = R2 + (size_t)NCu;
    unsigned short* wbf     = xbf + (size_t)NCu;
    float* ss    = (float*)(wbf + 655360);   // 768 raw sums (3 BNs)
    int* ibase    = (int*)(ss + 768);
    int* deg      = ibase;
    int* rowstart = ibase + 4096;
    int* cursor   = ibase + 4096 + 4098;
    int* csr_src  = ibase + 4096 + 4098 + 4096;

    const int OG1 = 0, OG2 = 65536, OAI = 131072, OAO = 327680, OM1 = 393216, OM2 = 524288;

    hipMemsetAsync(deg, 0, 4096 * sizeof(int), stream);
    hist_kernel<<<E_EDGES / 256, 256, 0, stream>>>(ei, deg);
    scan_kernel<<<1, 256, 0, stream>>>(deg, rowstart, cursor);
    fill_kernel<<<E_EDGES / 256, 256, 0, stream>>>(ei, cursor, csr_src);
    wcvt<<<320, 256, 0, stream>>>(gin_w1, gin_w2, ain_w, aout_w, mlp_w1, mlp_w2, wbf);
    x2bf<<<NC / 2048, 256, 0, stream>>>(x_in, xbf);

    for (int i = 0; i < L_LAYERS; ++i) {
        const float* xin = (i == 0) ? x_in : ((i & 1) ? xA : xB);
        float* xout = (i & 1) ? xB : xA;
        const float* gb1 = gin_b1 + (size_t)i * C_DIM;
        const float* gb2 = gin_b2 + (size_t)i * C_DIM;
        const float* aib = ain_b + (size_t)i * 3 * C_DIM;
        const float* aob = aout_b + (size_t)i * C_DIM;
        const float* mb1 = mlp_b1 + (size_t)i * 2 * C_DIM;
        const float* mb2 = mlp_b2 + (size_t)i * C_DIM;

        // 1) fused QKV GEMM + GIN gather (both read xbf); zeroes ss
        qkv_gather<<<2560, 256, 0, stream>>>(xbf, wbf + OAI + (size_t)i * 49152, aib,
                                             Qb, Kb, VT, rowstart, csr_src,
                                             (unsigned int*)hsum_bf, ss);
        // 2-3) GIN MLP (hsum in R2 consumed before attn overwrites R2)
        gemm_bf<128><<<dim3(2, 256), 256, 0, stream>>>(hsum_bf, wbf + OG1 + (size_t)i * 16384,
                                                       gb1, nullptr, nullptr, t1_bf, nullptr, 128, 1);
        gemm_bf<128><<<dim3(2, 256), 256, 0, stream>>>(t1_bf, wbf + OG2 + (size_t)i * 16384,
                                                       gb2, xin, g1, nullptr, ss, 128, 0);
        // 4-5) attention + out-proj
        attn_kernel<<<dim3(N_NODES / 32, H_HEADS), 512, 0, stream>>>(Qb, Kb, VT, ao_bf);
        gemm_bf<128><<<dim3(2, 256), 256, 0, stream>>>(ao_bf, wbf + OAO + (size_t)i * 16384,
                                                       aob, xin, a2, nullptr, ss + 256, 128, 0);
        // 6) combine (BN scales inline from fused stats)
        combine2<<<512, 256, 0, stream>>>(g1, a2, ss, ss + 256,
                                          n1_g + (size_t)i * C_DIM, n1_b + (size_t)i * C_DIM,
                                          n2_g + (size_t)i * C_DIM, n2_b + (size_t)i * C_DIM,
                                          hbuf, hbuf_bf);
        // 7-8) MLP
        gemm_bf<128><<<dim3(4, 256), 256, 0, stream>>>(hbuf_bf, wbf + OM1 + (size_t)i * 32768,
                                                       mb1, nullptr, nullptr, t2_bf, nullptr, 256, 1);
        gemm_bf<256><<<dim3(2, 256), 256, 0, stream>>>(t2_bf, wbf + OM2 + (size_t)i * 32768,
                                                       mb2, hbuf, m3, nullptr, ss + 512, 128, 0);
        // 9) final BN
        bn_apply<<<512, 256, 0, stream>>>(m3, ss + 512,
                                          n3_g + (size_t)i * C_DIM, n3_b + (size_t)i * C_DIM,
                                          xout, xbf);
    }

    const float* xf = xB;  // after layer 3
    head_fused<<<N_NODES / 8, 256, 0, stream>>>(xf, h_w1, h_b1, h_w2, h_b2, h_w3, h_b3,
                                                (float*)d_out);
}

// Round 14
// 415.103 us; speedup vs baseline: 1.2121x; 1.0926x over previous
//
#include <hip/hip_runtime.h>

#define N_NODES 4096
#define C_DIM   128
#define L_LAYERS 4
#define E_EDGES 131072
#define H_HEADS 4
#define D_HEAD  32
#define NC      (N_NODES * C_DIM)
#define NCu     (N_NODES * C_DIM)
#define P_STRIDE 136

typedef short bf16x8 __attribute__((ext_vector_type(8)));
typedef float f32x4  __attribute__((ext_vector_type(4)));

__device__ __forceinline__ unsigned short f2bf(float f) {
    unsigned int u = __float_as_uint(f);
    u += 0x7fffu + ((u >> 16) & 1u);
    return (unsigned short)(u >> 16);
}

__device__ __forceinline__ float bf_lo(unsigned int u) { return __uint_as_float(u << 16); }
__device__ __forceinline__ float bf_hi(unsigned int u) { return __uint_as_float(u & 0xffff0000u); }

__device__ __forceinline__ bf16x8 pack8(const float* v) {
    bf16x8 o;
#pragma unroll
    for (int i = 0; i < 8; ++i) o[i] = (short)f2bf(v[i]);
    return o;
}

// ---------------------------------------------------------------------------
// CSR build (once per launch)
// ---------------------------------------------------------------------------
__global__ __launch_bounds__(256) void hist_kernel(const int* __restrict__ ei,
                                                   int* __restrict__ deg) {
    int e = blockIdx.x * 256 + threadIdx.x;
    atomicAdd(&deg[ei[E_EDGES + e]], 1);
}

__global__ __launch_bounds__(256) void scan_kernel(const int* __restrict__ deg,
                                                   int* __restrict__ rowstart,
                                                   int* __restrict__ cursor) {
    __shared__ int ts[256];
    const int tid = threadIdx.x;
    int loc[16];
    int s = 0;
#pragma unroll
    for (int i = 0; i < 16; ++i) { loc[i] = s; s += deg[tid * 16 + i]; }
    ts[tid] = s;
    __syncthreads();
    for (int off = 1; off < 256; off <<= 1) {
        int t = (tid >= off) ? ts[tid - off] : 0;
        __syncthreads();
        if (tid >= off) ts[tid] += t;
        __syncthreads();
    }
    int off0 = ts[tid] - s;
#pragma unroll
    for (int i = 0; i < 16; ++i) {
        int v = off0 + loc[i];
        rowstart[tid * 16 + i] = v;
        cursor[tid * 16 + i] = v;
    }
    if (tid == 255) rowstart[4096] = off0 + s;
}

__global__ __launch_bounds__(256) void fill_kernel(const int* __restrict__ ei,
                                                   int* __restrict__ cursor,
                                                   int* __restrict__ csr_src) {
    int e = blockIdx.x * 256 + threadIdx.x;
    int d = ei[E_EDGES + e];
    int s = ei[e];
    int p = atomicAdd(&cursor[d], 1);
    csr_src[p] = s;
}

// ---------------------------------------------------------------------------
// weight pre-convert fp32 -> bf16
// ---------------------------------------------------------------------------
__global__ __launch_bounds__(256) void wcvt(const float* __restrict__ s0, const float* __restrict__ s1,
                                            const float* __restrict__ s2, const float* __restrict__ s3,
                                            const float* __restrict__ s4, const float* __restrict__ s5,
                                            unsigned short* __restrict__ wbf) {
    int i0 = (blockIdx.x * 256 + threadIdx.x) * 8;
    const float* src; int base;
    if      (i0 < 65536)  { src = s0; base = 0; }
    else if (i0 < 131072) { src = s1; base = 65536; }
    else if (i0 < 327680) { src = s2; base = 131072; }
    else if (i0 < 393216) { src = s3; base = 327680; }
    else if (i0 < 524288) { src = s4; base = 393216; }
    else                  { src = s5; base = 524288; }
    const float* p = src + (i0 - base);
    float t[8];
#pragma unroll
    for (int i = 0; i < 8; ++i) t[i] = p[i];
    *(bf16x8*)(wbf + i0) = pack8(t);
}

__global__ __launch_bounds__(256) void x2bf(const float* __restrict__ x,
                                            unsigned short* __restrict__ xb) {
    int i0 = (blockIdx.x * 256 + threadIdx.x) * 8;
    float t[8];
#pragma unroll
    for (int i = 0; i < 8; ++i) t[i] = x[i0 + i];
    *(bf16x8*)(xb + i0) = pack8(t);
}

// ---------------------------------------------------------------------------
// Fused QKV-GEMM + GIN-gather (R13-proven). hsum now lands in the c1 overlay.
// ---------------------------------------------------------------------------
__global__ __launch_bounds__(256, 8) void qkv_gather(const unsigned short* __restrict__ xb,
                                                     const unsigned short* __restrict__ Wbf,
                                                     const float* __restrict__ bias,
                                                     unsigned short* __restrict__ Qb,
                                                     unsigned short* __restrict__ Kb,
                                                     unsigned short* __restrict__ VT,
                                                     const int* __restrict__ rowstart,
                                                     const int* __restrict__ csr_src,
                                                     unsigned int* __restrict__ hsum,
                                                     float* __restrict__ ssz) {
    const int b = blockIdx.x;
    const int tid = threadIdx.x;
    if (b < 1536) {
        const int ct = b % 6, rt = b / 6;
        const int wv = tid >> 6;
        const int lane = tid & 63, lg = lane >> 4, ll = lane & 15;
        const int rowbase = rt * 16;
        const int colbase = ct * 64 + wv * 16;

        const unsigned short* Ap = xb  + (size_t)(rowbase + ll) * 128 + lg * 8;
        const unsigned short* Wp = Wbf + (size_t)(colbase + ll) * 128 + lg * 8;

        f32x4 acc = {0.f, 0.f, 0.f, 0.f};
#pragma unroll
        for (int k = 0; k < 128; k += 32) {
            bf16x8 a = *(const bf16x8*)(Ap + k);
            bf16x8 w = *(const bf16x8*)(Wp + k);
            acc = __builtin_amdgcn_mfma_f32_16x16x32_bf16(a, w, acc, 0, 0, 0);
        }

        const float qsc = 0.25506973f;  // (1/sqrt(32)) * log2(e)
        const int col = colbase + ll;
        const float bi = bias[col];
#pragma unroll
        for (int r = 0; r < 4; ++r) {
            const int row = rowbase + lg * 4 + r;
            float v = acc[r] + bi;
            if (col < 128) {
                int hh = col >> 5, d = col & 31;
                Qb[((size_t)hh * N_NODES + row) * D_HEAD + d] = f2bf(v * qsc);
            } else if (col < 256) {
                int c2 = col - 128, hh = c2 >> 5, d = c2 & 31;
                Kb[((size_t)hh * N_NODES + row) * D_HEAD + d] = f2bf(v);
            } else {
                int c2 = col - 256, hh = c2 >> 5, d = c2 & 31;
                VT[((size_t)hh * D_HEAD + d) * N_NODES + row] = f2bf(v);
            }
        }
    } else {
        if (b == 1536) {
            ssz[tid] = 0.f; ssz[256 + tid] = 0.f; ssz[512 + tid] = 0.f;
        }
        const int node = (b - 1536) * 4 + (tid >> 6);
        const int lane = tid & 63;
        const unsigned int* xu = (const unsigned int*)xb;
        const int beg = rowstart[node], end = rowstart[node + 1];
        unsigned int su = xu[(size_t)node * 64 + lane];
        float ax = bf_lo(su), ay = bf_hi(su);
        float bx = 0.f, by = 0.f;
        int e = beg;
        for (; e + 4 <= end; e += 4) {
            int s0 = csr_src[e], s1 = csr_src[e + 1], s2 = csr_src[e + 2], s3 = csr_src[e + 3];
            unsigned int u0 = xu[(size_t)s0 * 64 + lane];
            unsigned int u1 = xu[(size_t)s1 * 64 + lane];
            unsigned int u2 = xu[(size_t)s2 * 64 + lane];
            unsigned int u3 = xu[(size_t)s3 * 64 + lane];
            ax += bf_lo(u0) + bf_lo(u1); ay += bf_hi(u0) + bf_hi(u1);
            bx += bf_lo(u2) + bf_lo(u3); by += bf_hi(u2) + bf_hi(u3);
        }
        for (; e < end; ++e) {
            unsigned int u0 = xu[(size_t)csr_src[e] * 64 + lane];
            ax += bf_lo(u0); ay += bf_hi(u0);
        }
        float ox = ax + bx, oy = ay + by;
        hsum[(size_t)node * 64 + lane] = (unsigned int)f2bf(ox) | ((unsigned int)f2bf(oy) << 16);
    }
}

// ---------------------------------------------------------------------------
// Fused attention + GIN-MLP-1. grid 768, 512 thr.
// blocks 0..511: attn v4 (byte-identical math; h = b>>7, qtile = b&127).
// blocks 512..767: gin1 GEMM (A=hsum, W=gw1, relu, bf16 out t1); 8 waves of
// 16x16 tiles, rowbase = (b-512)*16, colbase = wv*16 (J=K=128).
// Both branches depend only on qkv_gather outputs; attn writes R2 (ao),
// gin1 reads c1 (hsum) and writes c2 (t1) - disjoint.
// ---------------------------------------------------------------------------
__global__ __launch_bounds__(512, 4) void attn_gin1(const unsigned short* __restrict__ Qb,
                                                    const unsigned short* __restrict__ Kb,
                                                    const unsigned short* __restrict__ VT,
                                                    unsigned short* __restrict__ ob,
                                                    const unsigned short* __restrict__ hsum,
                                                    const unsigned short* __restrict__ W1,
                                                    const float* __restrict__ bias1,
                                                    unsigned short* __restrict__ t1out) {
    __shared__ __align__(16) unsigned short Pl[8 * 32 * P_STRIDE];
    float (*Ouns)[32][33] = (float (*)[32][33])(void*)Pl;
    float (*Llp)[32] = (float (*)[32])(void*)(Pl + 8 * 32 * 33 * 2);

    const int b   = blockIdx.x;
    const int tid = threadIdx.x;
    const int wv  = tid >> 6;
    const int lane = tid & 63;
    const int lg  = lane >> 4;
    const int ll  = lane & 15;

    if (b >= 512) {
        // ---- gin1 GEMM branch ----
        const int rowbase = (b - 512) * 16;
        const int colbase = wv * 16;
        const unsigned short* Ap = hsum + (size_t)(rowbase + ll) * 128 + lg * 8;
        const unsigned short* Wp = W1 + (size_t)(colbase + ll) * 128 + lg * 8;
        f32x4 acc = {0.f, 0.f, 0.f, 0.f};
#pragma unroll
        for (int k = 0; k < 128; k += 32) {
            bf16x8 a = *(const bf16x8*)(Ap + k);
            bf16x8 w = *(const bf16x8*)(Wp + k);
            acc = __builtin_amdgcn_mfma_f32_16x16x32_bf16(a, w, acc, 0, 0, 0);
        }
        const int col = colbase + ll;
        const float bi = bias1[col];
#pragma unroll
        for (int r = 0; r < 4; ++r) {
            const int row = rowbase + lg * 4 + r;
            float v = fmaxf(acc[r] + bi, 0.f);
            t1out[(size_t)row * 128 + col] = f2bf(v);
        }
        return;
    }

    // ---- attention branch (R7/R11/R12/R13 verified math) ----
    const int h   = b >> 7;
    const int q0  = (b & 127) * 32;

    const unsigned short* Qh = Qb + ((size_t)h * N_NODES + q0) * D_HEAD;
    const unsigned short* Kh = Kb + (size_t)h * N_NODES * D_HEAD;
    const unsigned short* Vh = VT + (size_t)h * D_HEAD * N_NODES;

    bf16x8 qf0 = *(const bf16x8*)(Qh + ll * D_HEAD + lg * 8);
    bf16x8 qf1 = *(const bf16x8*)(Qh + (16 + ll) * D_HEAD + lg * 8);

    f32x4 oacc00 = {0.f,0.f,0.f,0.f}, oacc01 = {0.f,0.f,0.f,0.f};
    f32x4 oacc10 = {0.f,0.f,0.f,0.f}, oacc11 = {0.f,0.f,0.f,0.f};
    float l0[4] = {0.f,0.f,0.f,0.f}, l1[4] = {0.f,0.f,0.f,0.f};

    unsigned short* Pw = Pl + wv * (32 * P_STRIDE);
    const int k0 = wv * (N_NODES / 8);

    for (int t = 0; t < (N_NODES / 8) / 128; ++t) {
        const int kt = k0 + t * 128;

        float s0[8][4], s1[8][4];
#pragma unroll
        for (int kc = 0; kc < 8; ++kc) {
            bf16x8 kf = *(const bf16x8*)(Kh + (size_t)(kt + kc * 16 + ll) * D_HEAD + lg * 8);
            f32x4 z = {0.f, 0.f, 0.f, 0.f};
            f32x4 d0 = __builtin_amdgcn_mfma_f32_16x16x32_bf16(qf0, kf, z, 0, 0, 0);
            f32x4 d1 = __builtin_amdgcn_mfma_f32_16x16x32_bf16(qf1, kf, z, 0, 0, 0);
#pragma unroll
            for (int r = 0; r < 4; ++r) { s0[kc][r] = d0[r]; s1[kc][r] = d1[r]; }
        }

#pragma unroll
        for (int r = 0; r < 4; ++r) {
            float a = 0.f, bb = 0.f;
#pragma unroll
            for (int kc = 0; kc < 8; ++kc) {
                float p0 = exp2f(s0[kc][r]); s0[kc][r] = p0; a += p0;
                float p1 = exp2f(s1[kc][r]); s1[kc][r] = p1; bb += p1;
            }
#pragma unroll
            for (int off = 1; off < 16; off <<= 1) {
                a += __shfl_xor(a, off, 64);
                bb += __shfl_xor(bb, off, 64);
            }
            l0[r] += a;
            l1[r] += bb;
        }

#pragma unroll
        for (int kc = 0; kc < 8; ++kc)
#pragma unroll
            for (int r = 0; r < 4; ++r) {
                Pw[(lg * 4 + r) * P_STRIDE + kc * 16 + ll]      = f2bf(s0[kc][r]);
                Pw[(16 + lg * 4 + r) * P_STRIDE + kc * 16 + ll] = f2bf(s1[kc][r]);
            }
        asm volatile("" ::: "memory");

#pragma unroll
        for (int kc2 = 0; kc2 < 4; ++kc2) {
            bf16x8 va = *(const bf16x8*)(Vh + (size_t)ll * N_NODES + kt + kc2 * 32 + lg * 8);
            bf16x8 vb = *(const bf16x8*)(Vh + (size_t)(16 + ll) * N_NODES + kt + kc2 * 32 + lg * 8);
            bf16x8 pf0 = *(const bf16x8*)(Pw + ll * P_STRIDE + kc2 * 32 + lg * 8);
            bf16x8 pf1 = *(const bf16x8*)(Pw + (16 + ll) * P_STRIDE + kc2 * 32 + lg * 8);
            oacc00 = __builtin_amdgcn_mfma_f32_16x16x32_bf16(pf0, va, oacc00, 0, 0, 0);
            oacc01 = __builtin_amdgcn_mfma_f32_16x16x32_bf16(pf0, vb, oacc01, 0, 0, 0);
            oacc10 = __builtin_amdgcn_mfma_f32_16x16x32_bf16(pf1, va, oacc10, 0, 0, 0);
            oacc11 = __builtin_amdgcn_mfma_f32_16x16x32_bf16(pf1, vb, oacc11, 0, 0, 0);
        }
    }

    __syncthreads();

#pragma unroll
    for (int r = 0; r < 4; ++r) {
        Ouns[wv][lg * 4 + r][ll]           = oacc00[r];
        Ouns[wv][lg * 4 + r][16 + ll]      = oacc01[r];
        Ouns[wv][16 + lg * 4 + r][ll]      = oacc10[r];
        Ouns[wv][16 + lg * 4 + r][16 + ll] = oacc11[r];
    }
    if (ll == 0) {
#pragma unroll
        for (int r = 0; r < 4; ++r) {
            Llp[wv][lg * 4 + r]      = l0[r];
            Llp[wv][16 + lg * 4 + r] = l1[r];
        }
    }
    __syncthreads();

    {
        const int row = tid >> 4, col = tid & 15;
        float L = 0.f, oa = 0.f, obv = 0.f;
#pragma unroll
        for (int w = 0; w < 8; ++w) {
            L   += Llp[w][row];
            oa  += Ouns[w][row][col];
            obv += Ouns[w][row][16 + col];
        }
        float inv = 1.f / L;
        ob[(size_t)(q0 + row) * C_DIM + h * D_HEAD + col]      = f2bf(oa * inv);
        ob[(size_t)(q0 + row) * C_DIM + h * D_HEAD + 16 + col] = f2bf(obv * inv);
    }
}

// ---------------------------------------------------------------------------
// bf16 MFMA GEMM, LDS-free, 16x16 tile per wave. grid (J/64, N/16).
// Optional fused BatchNorm stats (2 wave-reduced atomics per column).
// ---------------------------------------------------------------------------
template <int K>
__global__ __launch_bounds__(256, 8) void gemm_bf(const unsigned short* __restrict__ Abf,
                                                  const unsigned short* __restrict__ Wbf,
                                                  const float* __restrict__ bias,
                                                  const float* __restrict__ resid,
                                                  float* __restrict__ outf,
                                                  unsigned short* __restrict__ outb,
                                                  float* __restrict__ stats,
                                                  const int J, const int relu) {
    const int tid = threadIdx.x;
    const int wv = tid >> 6;
    const int lane = tid & 63, lg = lane >> 4, ll = lane & 15;
    const int rowbase = blockIdx.y * 16;
    const int colbase = blockIdx.x * 64 + wv * 16;

    const unsigned short* Ap = Abf + (size_t)(rowbase + ll) * K + lg * 8;
    const unsigned short* Wp = Wbf + (size_t)(colbase + ll) * K + lg * 8;

    f32x4 acc = {0.f, 0.f, 0.f, 0.f};
#pragma unroll
    for (int k = 0; k < K; k += 32) {
        bf16x8 a = *(const bf16x8*)(Ap + k);
        bf16x8 b = *(const bf16x8*)(Wp + k);
        acc = __builtin_amdgcn_mfma_f32_16x16x32_bf16(a, b, acc, 0, 0, 0);
    }

    const int col = colbase + ll;
    const float bi = bias[col];
    float sv = 0.f, sv2 = 0.f;
#pragma unroll
    for (int r = 0; r < 4; ++r) {
        const int row = rowbase + lg * 4 + r;
        float v = acc[r] + bi;
        if (resid) v += resid[(size_t)row * J + col];
        if (relu) v = fmaxf(v, 0.f);
        if (outf) outf[(size_t)row * J + col] = v;
        if (outb) outb[(size_t)row * J + col] = f2bf(v);
        sv += v; sv2 += v * v;
    }
    if (stats) {
        sv  += __shfl_xor(sv, 16, 64);  sv  += __shfl_xor(sv, 32, 64);
        sv2 += __shfl_xor(sv2, 16, 64); sv2 += __shfl_xor(sv2, 32, 64);
        if (lg == 0) {
            atomicAdd(&stats[col], sv);
            atomicAdd(&stats[C_DIM + col], sv2);
        }
    }
}

// ---------------------------------------------------------------------------
// Fused gin2 + aout: two shape-identical GEMMs (K=J=128, resid, fp32 out,
// stats), block-uniform pointer select. grid 1024, 256 thr.
// blocks 0..511: gin2 (A=t1, W=Wg2, out g1, stats ss).
// blocks 512..1023: aout (A=ao, W=Wao, out a2, stats ss+256).
// ---------------------------------------------------------------------------
__global__ __launch_bounds__(256, 8) void gemm2x(const unsigned short* __restrict__ A0,
                                                 const unsigned short* __restrict__ W0,
                                                 const float* __restrict__ bias0,
                                                 float* __restrict__ out0,
                                                 float* __restrict__ stats0,
                                                 const unsigned short* __restrict__ A1,
                                                 const unsigned short* __restrict__ W1,
                                                 const float* __restrict__ bias1,
                                                 float* __restrict__ out1,
                                                 float* __restrict__ stats1,
                                                 const float* __restrict__ resid) {
    const int b = blockIdx.x;
    const int which = b >> 9;
    const int bl = b & 511;
    const unsigned short* Abf = which ? A1 : A0;
    const unsigned short* Wbf = which ? W1 : W0;
    const float* bias = which ? bias1 : bias0;
    float* outf  = which ? out1 : out0;
    float* stats = which ? stats1 : stats0;

    const int tid = threadIdx.x;
    const int wv = tid >> 6;
    const int lane = tid & 63, lg = lane >> 4, ll = lane & 15;
    const int rowbase = (bl >> 1) * 16;
    const int colbase = (bl & 1) * 64 + wv * 16;

    const unsigned short* Ap = Abf + (size_t)(rowbase + ll) * 128 + lg * 8;
    const unsigned short* Wp = Wbf + (size_t)(colbase + ll) * 128 + lg * 8;

    f32x4 acc = {0.f, 0.f, 0.f, 0.f};
#pragma unroll
    for (int k = 0; k < 128; k += 32) {
        bf16x8 a = *(const bf16x8*)(Ap + k);
        bf16x8 w = *(const bf16x8*)(Wp + k);
        acc = __builtin_amdgcn_mfma_f32_16x16x32_bf16(a, w, acc, 0, 0, 0);
    }

    const int col = colbase + ll;
    const float bi = bias[col];
    float sv = 0.f, sv2 = 0.f;
#pragma unroll
    for (int r = 0; r < 4; ++r) {
        const int row = rowbase + lg * 4 + r;
        float v = acc[r] + bi + resid[(size_t)row * 128 + col];
        outf[(size_t)row * 128 + col] = v;
        sv += v; sv2 += v * v;
    }
    sv  += __shfl_xor(sv, 16, 64);  sv  += __shfl_xor(sv, 32, 64);
    sv2 += __shfl_xor(sv2, 16, 64); sv2 += __shfl_xor(sv2, 32, 64);
    if (lg == 0) {
        atomicAdd(&stats[col], sv);
        atomicAdd(&stats[128 + col], sv2);
    }
}

// ---------------------------------------------------------------------------
// h = bn1(g1)+bn2(a2) with BN scales computed inline from raw sums
// ---------------------------------------------------------------------------
__global__ __launch_bounds__(256) void combine2(const float* __restrict__ p1,
                                                const float* __restrict__ p2,
                                                const float* __restrict__ st1,
                                                const float* __restrict__ st2,
                                                const float* __restrict__ g1v,
                                                const float* __restrict__ b1v,
                                                const float* __restrict__ g2v,
                                                const float* __restrict__ b2v,
                                                float* __restrict__ out,
                                                unsigned short* __restrict__ outb) {
    int idx = blockIdx.x * 256 + threadIdx.x;
    int c4 = (idx & 31) * 4;
    const float inv_n = 1.f / N_NODES;
    float sc1[4], sh1[4], sc2[4], sh2[4];
#pragma unroll
    for (int c = 0; c < 4; ++c) {
        int ch = c4 + c;
        float m1 = st1[ch] * inv_n;
        float v1 = st1[C_DIM + ch] * inv_n - m1 * m1;
        float r1 = rsqrtf(v1 + 1e-5f);
        sc1[c] = g1v[ch] * r1; sh1[c] = b1v[ch] - m1 * sc1[c];
        float m2 = st2[ch] * inv_n;
        float v2 = st2[C_DIM + ch] * inv_n - m2 * m2;
        float r2 = rsqrtf(v2 + 1e-5f);
        sc2[c] = g2v[ch] * r2; sh2[c] = b2v[ch] - m2 * sc2[c];
    }
    float4 v1 = ((const float4*)p1)[idx];
    float4 v2 = ((const float4*)p2)[idx];
    float4 o;
    o.x = v1.x * sc1[0] + sh1[0] + v2.x * sc2[0] + sh2[0];
    o.y = v1.y * sc1[1] + sh1[1] + v2.y * sc2[1] + sh2[1];
    o.z = v1.z * sc1[2] + sh1[2] + v2.z * sc2[2] + sh2[2];
    o.w = v1.w * sc1[3] + sh1[3] + v2.w * sc2[3] + sh2[3];
    ((float4*)out)[idx] = o;
    ushort4 ub;
    ub.x = f2bf(o.x); ub.y = f2bf(o.y); ub.z = f2bf(o.z); ub.w = f2bf(o.w);
    *(ushort4*)(outb + (size_t)idx * 4) = ub;
}

// x = bn3(m3), scales inline from raw sums
__global__ __launch_bounds__(256) void bn_apply(const float* __restrict__ p,
                                                const float* __restrict__ st,
                                                const float* __restrict__ gv,
                                                const float* __restrict__ bv,
                                                float* __restrict__ out,
                                                unsigned short* __restrict__ outb) {
    int idx = blockIdx.x * 256 + threadIdx.x;
    int c4 = (idx & 31) * 4;
    const float inv_n = 1.f / N_NODES;
    float sc[4], sh[4];
#pragma unroll
    for (int c = 0; c < 4; ++c) {
        int ch = c4 + c;
        float m = st[ch] * inv_n;
        float vv = st[C_DIM + ch] * inv_n - m * m;
        float r = rsqrtf(vv + 1e-5f);
        sc[c] = gv[ch] * r; sh[c] = bv[ch] - m * sc[c];
    }
    float4 v = ((const float4*)p)[idx];
    float4 o;
    o.x = v.x * sc[0] + sh[0];
    o.y = v.y * sc[1] + sh[1];
    o.z = v.z * sc[2] + sh[2];
    o.w = v.w * sc[3] + sh[3];
    ((float4*)out)[idx] = o;
    ushort4 ub;
    ub.x = f2bf(o.x); ub.y = f2bf(o.y); ub.z = f2bf(o.z); ub.w = f2bf(o.w);
    *(ushort4*)(outb + (size_t)idx * 4) = ub;
}

// ---------------------------------------------------------------------------
// Fused head MLP
// ---------------------------------------------------------------------------
__global__ __launch_bounds__(256) void head_fused(const float* __restrict__ x,
                                                  const float* __restrict__ w1,
                                                  const float* __restrict__ b1,
                                                  const float* __restrict__ w2,
                                                  const float* __restrict__ b2,
                                                  const float* __restrict__ w3,
                                                  const float* __restrict__ b3,
                                                  float* __restrict__ out) {
    __shared__ __align__(16) float xs[8][128];
    __shared__ __align__(16) float hs[8][64];
    const int tid = threadIdx.x;
    const int n = tid >> 5;
    const int g = tid & 31;
    const int node0 = blockIdx.x * 8;

    {
        int r = tid >> 5, q = tid & 31;
        *(float4*)(&xs[r][q * 4]) = *(const float4*)(x + (size_t)(node0 + r) * 128 + q * 4);
    }
    __syncthreads();

    {
        float acc0 = b1[g], acc1 = b1[g + 32];
        const float* wa = w1 + (size_t)g * 128;
        const float* wb = w1 + (size_t)(g + 32) * 128;
#pragma unroll 8
        for (int k = 0; k < 128; k += 4) {
            float4 xv = *(const float4*)(&xs[n][k]);
            float4 va = *(const float4*)(wa + k);
            float4 vb = *(const float4*)(wb + k);
            acc0 += xv.x * va.x + xv.y * va.y + xv.z * va.z + xv.w * va.w;
            acc1 += xv.x * vb.x + xv.y * vb.y + xv.z * vb.z + xv.w * vb.w;
        }
        hs[n][g]      = fmaxf(acc0, 0.f);
        hs[n][g + 32] = fmaxf(acc1, 0.f);
    }
    __syncthreads();

    {
        float acc = b2[g];
        const float* wr = w2 + (size_t)g * 64;
#pragma unroll 8
        for (int k = 0; k < 64; k += 4) {
            float4 hv = *(const float4*)(&hs[n][k]);
            float4 wv = *(const float4*)(wr + k);
            acc += hv.x * wv.x + hv.y * wv.y + hv.z * wv.z + hv.w * wv.w;
        }
        float t = fmaxf(acc, 0.f) * w3[g];
#pragma unroll
        for (int off = 1; off < 32; off <<= 1) t += __shfl_xor(t, off, 64);
        if (g == 0) out[node0 + n] = t + b3[0];
    }
}

// ---------------------------------------------------------------------------
extern "C" void kernel_launch(void* const* d_in, const int* in_sizes, int n_in,
                              void* d_out, int out_size, void* d_ws, size_t ws_size,
                              hipStream_t stream) {
    (void)in_sizes; (void)n_in; (void)out_size; (void)ws_size;
    const float* x_in   = (const float*)d_in[0];
    const int*   ei     = (const int*)d_in[1];
    const float* gin_w1 = (const float*)d_in[2];
    const float* gin_b1 = (const float*)d_in[3];
    const float* gin_w2 = (const float*)d_in[4];
    const float* gin_b2 = (const float*)d_in[5];
    const float* ain_w  = (const float*)d_in[6];
    const float* ain_b  = (const float*)d_in[7];
    const float* aout_w = (const float*)d_in[8];
    const float* aout_b = (const float*)d_in[9];
    const float* n1_g   = (const float*)d_in[10];
    const float* n1_b   = (const float*)d_in[11];
    const float* n2_g   = (const float*)d_in[12];
    const float* n2_b   = (const float*)d_in[13];
    const float* n3_g   = (const float*)d_in[14];
    const float* n3_b   = (const float*)d_in[15];
    const float* mlp_w1 = (const float*)d_in[16];
    const float* mlp_b1 = (const float*)d_in[17];
    const float* mlp_w2 = (const float*)d_in[18];
    const float* mlp_b2 = (const float*)d_in[19];
    const float* h_w1   = (const float*)d_in[20];
    const float* h_b1   = (const float*)d_in[21];
    const float* h_w2   = (const float*)d_in[22];
    const float* h_b2   = (const float*)d_in[23];
    const float* h_w3   = (const float*)d_in[24];
    const float* h_b3   = (const float*)d_in[25];

    float* f = (float*)d_ws;
    float* g1   = f;                   // c0 (m3 aliases; g1 dead after combine2)
    float* m3   = f;
    float* a2   = f + 1 * (size_t)NC;  // c1 (hsum ushort overlay during steps 1-2)
    float* hbuf = f + 2 * (size_t)NC;  // c2 (t1_bf ushort overlay during GIN)
    float* xA   = f + 3 * (size_t)NC;
    float* xB   = f + 4 * (size_t)NC;
    unsigned short* R1  = (unsigned short*)(f + 5 * (size_t)NC);  // 3 NCu
    unsigned short* Qb      = R1;
    unsigned short* Kb      = R1 + (size_t)NCu;
    unsigned short* VT      = R1 + 2 * (size_t)NCu;
    unsigned short* t2_bf   = R1;                    // MLP1 out (QKV dead by then)
    unsigned short* R2      = R1 + 3 * (size_t)NCu;  // 1 NCu
    unsigned short* ao_bf   = R2;                    // attn out
    unsigned short* hbuf_bf = R2;                    // combine out (after aout)
    unsigned short* hsum_bf = (unsigned short*)a2;   // gather out (c1 overlay; dead before aout writes a2)
    unsigned short* t1_bf   = (unsigned short*)hbuf; // gin1 out (dead before combine2)
    unsigned short* xbf     = R2 + (size_t)NCu;
    unsigned short* wbf     = xbf + (size_t)NCu;
    float* ss    = (float*)(wbf + 655360);   // 768 raw sums (3 BNs)
    int* ibase    = (int*)(ss + 768);
    int* deg      = ibase;
    int* rowstart = ibase + 4096;
    int* cursor   = ibase + 4096 + 4098;
    int* csr_src  = ibase + 4096 + 4098 + 4096;

    const int OG1 = 0, OG2 = 65536, OAI = 131072, OAO = 327680, OM1 = 393216, OM2 = 524288;

    hipMemsetAsync(deg, 0, 4096 * sizeof(int), stream);
    hist_kernel<<<E_EDGES / 256, 256, 0, stream>>>(ei, deg);
    scan_kernel<<<1, 256, 0, stream>>>(deg, rowstart, cursor);
    fill_kernel<<<E_EDGES / 256, 256, 0, stream>>>(ei, cursor, csr_src);
    wcvt<<<320, 256, 0, stream>>>(gin_w1, gin_w2, ain_w, aout_w, mlp_w1, mlp_w2, wbf);
    x2bf<<<NC / 2048, 256, 0, stream>>>(x_in, xbf);

    for (int i = 0; i < L_LAYERS; ++i) {
        const float* xin = (i == 0) ? x_in : ((i & 1) ? xA : xB);
        float* xout = (i & 1) ? xB : xA;
        const float* gb1 = gin_b1 + (size_t)i * C_DIM;
        const float* gb2 = gin_b2 + (size_t)i * C_DIM;
        const float* aib = ain_b + (size_t)i * 3 * C_DIM;
        const float* aob = aout_b + (size_t)i * C_DIM;
        const float* mb1 = mlp_b1 + (size_t)i * 2 * C_DIM;
        const float* mb2 = mlp_b2 + (size_t)i * C_DIM;

        // 1) fused QKV GEMM + GIN gather (both read xbf); zeroes ss
        qkv_gather<<<2560, 256, 0, stream>>>(xbf, wbf + OAI + (size_t)i * 49152, aib,
                                             Qb, Kb, VT, rowstart, csr_src,
                                             (unsigned int*)hsum_bf, ss);
        // 2) fused attention + gin1 (both read only step-1 outputs)
        attn_gin1<<<768, 512, 0, stream>>>(Qb, Kb, VT, ao_bf,
                                           hsum_bf, wbf + OG1 + (size_t)i * 16384, gb1, t1_bf);
        // 3) fused gin2 + aout (both read step-2 outputs; stats into ss/ss+256)
        gemm2x<<<1024, 256, 0, stream>>>(t1_bf, wbf + OG2 + (size_t)i * 16384, gb2, g1, ss,
                                         ao_bf, wbf + OAO + (size_t)i * 16384, aob, a2, ss + 256,
                                         xin);
        // 4) combine (BN scales inline from fused stats)
        combine2<<<512, 256, 0, stream>>>(g1, a2, ss, ss + 256,
                                          n1_g + (size_t)i * C_DIM, n1_b + (size_t)i * C_DIM,
                                          n2_g + (size_t)i * C_DIM, n2_b + (size_t)i * C_DIM,
                                          hbuf, hbuf_bf);
        // 5-6) MLP
        gemm_bf<128><<<dim3(4, 256), 256, 0, stream>>>(hbuf_bf, wbf + OM1 + (size_t)i * 32768,
                                                       mb1, nullptr, nullptr, t2_bf, nullptr, 256, 1);
        gemm_bf<256><<<dim3(2, 256), 256, 0, stream>>>(t2_bf, wbf + OM2 + (size_t)i * 32768,
                                                       mb2, hbuf, m3, nullptr, ss + 512, 128, 0);
        // 7) final BN
        bn_apply<<<512, 256, 0, stream>>>(m3, ss + 512,
                                          n3_g + (size_t)i * C_DIM, n3_b + (size_t)i * C_DIM,
                                          xout, xbf);
    }

    const float* xf = xB;  // after layer 3
    head_fused<<<N_NODES / 8, 256, 0, stream>>>(xf, h_w1, h_b1, h_w2, h_b2, h_w3, h_b3,
                                                (float*)d_out);
}

// Round 15
// 403.637 us; speedup vs baseline: 1.2465x; 1.0284x over previous
//
#include <hip/hip_runtime.h>

#define N_NODES 4096
#define C_DIM   128
#define L_LAYERS 4
#define E_EDGES 131072
#define H_HEADS 4
#define D_HEAD  32
#define NC      (N_NODES * C_DIM)
#define NCu     (N_NODES * C_DIM)
#define P_STRIDE 136
#define HS_STRIDE 152   // ushorts; 304B row: 16B-aligned, 2-way bank spread

typedef short bf16x8 __attribute__((ext_vector_type(8)));
typedef float f32x4  __attribute__((ext_vector_type(4)));

__device__ __forceinline__ unsigned short f2bf(float f) {
    unsigned int u = __float_as_uint(f);
    u += 0x7fffu + ((u >> 16) & 1u);
    return (unsigned short)(u >> 16);
}

__device__ __forceinline__ float bf_lo(unsigned int u) { return __uint_as_float(u << 16); }
__device__ __forceinline__ float bf_hi(unsigned int u) { return __uint_as_float(u & 0xffff0000u); }

__device__ __forceinline__ bf16x8 pack8(const float* v) {
    bf16x8 o;
#pragma unroll
    for (int i = 0; i < 8; ++i) o[i] = (short)f2bf(v[i]);
    return o;
}

// ---------------------------------------------------------------------------
// CSR build (once per launch)
// ---------------------------------------------------------------------------
__global__ __launch_bounds__(256) void hist_kernel(const int* __restrict__ ei,
                                                   int* __restrict__ deg) {
    int e = blockIdx.x * 256 + threadIdx.x;
    atomicAdd(&deg[ei[E_EDGES + e]], 1);
}

__global__ __launch_bounds__(256) void scan_kernel(const int* __restrict__ deg,
                                                   int* __restrict__ rowstart,
                                                   int* __restrict__ cursor) {
    __shared__ int ts[256];
    const int tid = threadIdx.x;
    int loc[16];
    int s = 0;
#pragma unroll
    for (int i = 0; i < 16; ++i) { loc[i] = s; s += deg[tid * 16 + i]; }
    ts[tid] = s;
    __syncthreads();
    for (int off = 1; off < 256; off <<= 1) {
        int t = (tid >= off) ? ts[tid - off] : 0;
        __syncthreads();
        if (tid >= off) ts[tid] += t;
        __syncthreads();
    }
    int off0 = ts[tid] - s;
#pragma unroll
    for (int i = 0; i < 16; ++i) {
        int v = off0 + loc[i];
        rowstart[tid * 16 + i] = v;
        cursor[tid * 16 + i] = v;
    }
    if (tid == 255) rowstart[4096] = off0 + s;
}

__global__ __launch_bounds__(256) void fill_kernel(const int* __restrict__ ei,
                                                   int* __restrict__ cursor,
                                                   int* __restrict__ csr_src) {
    int e = blockIdx.x * 256 + threadIdx.x;
    int d = ei[E_EDGES + e];
    int s = ei[e];
    int p = atomicAdd(&cursor[d], 1);
    csr_src[p] = s;
}

// ---------------------------------------------------------------------------
// weight pre-convert fp32 -> bf16
// ---------------------------------------------------------------------------
__global__ __launch_bounds__(256) void wcvt(const float* __restrict__ s0, const float* __restrict__ s1,
                                            const float* __restrict__ s2, const float* __restrict__ s3,
                                            const float* __restrict__ s4, const float* __restrict__ s5,
                                            unsigned short* __restrict__ wbf) {
    int i0 = (blockIdx.x * 256 + threadIdx.x) * 8;
    const float* src; int base;
    if      (i0 < 65536)  { src = s0; base = 0; }
    else if (i0 < 131072) { src = s1; base = 65536; }
    else if (i0 < 327680) { src = s2; base = 131072; }
    else if (i0 < 393216) { src = s3; base = 327680; }
    else if (i0 < 524288) { src = s4; base = 393216; }
    else                  { src = s5; base = 524288; }
    const float* p = src + (i0 - base);
    float t[8];
#pragma unroll
    for (int i = 0; i < 8; ++i) t[i] = p[i];
    *(bf16x8*)(wbf + i0) = pack8(t);
}

__global__ __launch_bounds__(256) void x2bf(const float* __restrict__ x,
                                            unsigned short* __restrict__ xb) {
    int i0 = (blockIdx.x * 256 + threadIdx.x) * 8;
    float t[8];
#pragma unroll
    for (int i = 0; i < 8; ++i) t[i] = x[i0 + i];
    *(bf16x8*)(xb + i0) = pack8(t);
}

// ---------------------------------------------------------------------------
// Fused QKV-GEMM + GIN-gather (R13-proven). hsum lands in the c1 overlay.
// ---------------------------------------------------------------------------
__global__ __launch_bounds__(256, 8) void qkv_gather(const unsigned short* __restrict__ xb,
                                                     const unsigned short* __restrict__ Wbf,
                                                     const float* __restrict__ bias,
                                                     unsigned short* __restrict__ Qb,
                                                     unsigned short* __restrict__ Kb,
                                                     unsigned short* __restrict__ VT,
                                                     const int* __restrict__ rowstart,
                                                     const int* __restrict__ csr_src,
                                                     unsigned int* __restrict__ hsum,
                                                     float* __restrict__ ssz) {
    const int b = blockIdx.x;
    const int tid = threadIdx.x;
    if (b < 1536) {
        const int ct = b % 6, rt = b / 6;
        const int wv = tid >> 6;
        const int lane = tid & 63, lg = lane >> 4, ll = lane & 15;
        const int rowbase = rt * 16;
        const int colbase = ct * 64 + wv * 16;

        const unsigned short* Ap = xb  + (size_t)(rowbase + ll) * 128 + lg * 8;
        const unsigned short* Wp = Wbf + (size_t)(colbase + ll) * 128 + lg * 8;

        f32x4 acc = {0.f, 0.f, 0.f, 0.f};
#pragma unroll
        for (int k = 0; k < 128; k += 32) {
            bf16x8 a = *(const bf16x8*)(Ap + k);
            bf16x8 w = *(const bf16x8*)(Wp + k);
            acc = __builtin_amdgcn_mfma_f32_16x16x32_bf16(a, w, acc, 0, 0, 0);
        }

        const float qsc = 0.25506973f;  // (1/sqrt(32)) * log2(e)
        const int col = colbase + ll;
        const float bi = bias[col];
#pragma unroll
        for (int r = 0; r < 4; ++r) {
            const int row = rowbase + lg * 4 + r;
            float v = acc[r] + bi;
            if (col < 128) {
                int hh = col >> 5, d = col & 31;
                Qb[((size_t)hh * N_NODES + row) * D_HEAD + d] = f2bf(v * qsc);
            } else if (col < 256) {
                int c2 = col - 128, hh = c2 >> 5, d = c2 & 31;
                Kb[((size_t)hh * N_NODES + row) * D_HEAD + d] = f2bf(v);
            } else {
                int c2 = col - 256, hh = c2 >> 5, d = c2 & 31;
                VT[((size_t)hh * D_HEAD + d) * N_NODES + row] = f2bf(v);
            }
        }
    } else {
        if (b == 1536) {
            ssz[tid] = 0.f; ssz[256 + tid] = 0.f; ssz[512 + tid] = 0.f;
        }
        const int node = (b - 1536) * 4 + (tid >> 6);
        const int lane = tid & 63;
        const unsigned int* xu = (const unsigned int*)xb;
        const int beg = rowstart[node], end = rowstart[node + 1];
        unsigned int su = xu[(size_t)node * 64 + lane];
        float ax = bf_lo(su), ay = bf_hi(su);
        float bx = 0.f, by = 0.f;
        int e = beg;
        for (; e + 4 <= end; e += 4) {
            int s0 = csr_src[e], s1 = csr_src[e + 1], s2 = csr_src[e + 2], s3 = csr_src[e + 3];
            unsigned int u0 = xu[(size_t)s0 * 64 + lane];
            unsigned int u1 = xu[(size_t)s1 * 64 + lane];
            unsigned int u2 = xu[(size_t)s2 * 64 + lane];
            unsigned int u3 = xu[(size_t)s3 * 64 + lane];
            ax += bf_lo(u0) + bf_lo(u1); ay += bf_hi(u0) + bf_hi(u1);
            bx += bf_lo(u2) + bf_lo(u3); by += bf_hi(u2) + bf_hi(u3);
        }
        for (; e < end; ++e) {
            unsigned int u0 = xu[(size_t)csr_src[e] * 64 + lane];
            ax += bf_lo(u0); ay += bf_hi(u0);
        }
        float ox = ax + bx, oy = ay + by;
        hsum[(size_t)node * 64 + lane] = (unsigned int)f2bf(ox) | ((unsigned int)f2bf(oy) << 16);
    }
}

// ---------------------------------------------------------------------------
// Fused attention + GIN-MLP-1 (R14-proven, byte-identical).
// ---------------------------------------------------------------------------
__global__ __launch_bounds__(512, 4) void attn_gin1(const unsigned short* __restrict__ Qb,
                                                    const unsigned short* __restrict__ Kb,
                                                    const unsigned short* __restrict__ VT,
                                                    unsigned short* __restrict__ ob,
                                                    const unsigned short* __restrict__ hsum,
                                                    const unsigned short* __restrict__ W1,
                                                    const float* __restrict__ bias1,
                                                    unsigned short* __restrict__ t1out) {
    __shared__ __align__(16) unsigned short Pl[8 * 32 * P_STRIDE];
    float (*Ouns)[32][33] = (float (*)[32][33])(void*)Pl;
    float (*Llp)[32] = (float (*)[32])(void*)(Pl + 8 * 32 * 33 * 2);

    const int b   = blockIdx.x;
    const int tid = threadIdx.x;
    const int wv  = tid >> 6;
    const int lane = tid & 63;
    const int lg  = lane >> 4;
    const int ll  = lane & 15;

    if (b >= 512) {
        const int rowbase = (b - 512) * 16;
        const int colbase = wv * 16;
        const unsigned short* Ap = hsum + (size_t)(rowbase + ll) * 128 + lg * 8;
        const unsigned short* Wp = W1 + (size_t)(colbase + ll) * 128 + lg * 8;
        f32x4 acc = {0.f, 0.f, 0.f, 0.f};
#pragma unroll
        for (int k = 0; k < 128; k += 32) {
            bf16x8 a = *(const bf16x8*)(Ap + k);
            bf16x8 w = *(const bf16x8*)(Wp + k);
            acc = __builtin_amdgcn_mfma_f32_16x16x32_bf16(a, w, acc, 0, 0, 0);
        }
        const int col = colbase + ll;
        const float bi = bias1[col];
#pragma unroll
        for (int r = 0; r < 4; ++r) {
            const int row = rowbase + lg * 4 + r;
            float v = fmaxf(acc[r] + bi, 0.f);
            t1out[(size_t)row * 128 + col] = f2bf(v);
        }
        return;
    }

    const int h   = b >> 7;
    const int q0  = (b & 127) * 32;

    const unsigned short* Qh = Qb + ((size_t)h * N_NODES + q0) * D_HEAD;
    const unsigned short* Kh = Kb + (size_t)h * N_NODES * D_HEAD;
    const unsigned short* Vh = VT + (size_t)h * D_HEAD * N_NODES;

    bf16x8 qf0 = *(const bf16x8*)(Qh + ll * D_HEAD + lg * 8);
    bf16x8 qf1 = *(const bf16x8*)(Qh + (16 + ll) * D_HEAD + lg * 8);

    f32x4 oacc00 = {0.f,0.f,0.f,0.f}, oacc01 = {0.f,0.f,0.f,0.f};
    f32x4 oacc10 = {0.f,0.f,0.f,0.f}, oacc11 = {0.f,0.f,0.f,0.f};
    float l0[4] = {0.f,0.f,0.f,0.f}, l1[4] = {0.f,0.f,0.f,0.f};

    unsigned short* Pw = Pl + wv * (32 * P_STRIDE);
    const int k0 = wv * (N_NODES / 8);

    for (int t = 0; t < (N_NODES / 8) / 128; ++t) {
        const int kt = k0 + t * 128;

        float s0[8][4], s1[8][4];
#pragma unroll
        for (int kc = 0; kc < 8; ++kc) {
            bf16x8 kf = *(const bf16x8*)(Kh + (size_t)(kt + kc * 16 + ll) * D_HEAD + lg * 8);
            f32x4 z = {0.f, 0.f, 0.f, 0.f};
            f32x4 d0 = __builtin_amdgcn_mfma_f32_16x16x32_bf16(qf0, kf, z, 0, 0, 0);
            f32x4 d1 = __builtin_amdgcn_mfma_f32_16x16x32_bf16(qf1, kf, z, 0, 0, 0);
#pragma unroll
            for (int r = 0; r < 4; ++r) { s0[kc][r] = d0[r]; s1[kc][r] = d1[r]; }
        }

#pragma unroll
        for (int r = 0; r < 4; ++r) {
            float a = 0.f, bb = 0.f;
#pragma unroll
            for (int kc = 0; kc < 8; ++kc) {
                float p0 = exp2f(s0[kc][r]); s0[kc][r] = p0; a += p0;
                float p1 = exp2f(s1[kc][r]); s1[kc][r] = p1; bb += p1;
            }
#pragma unroll
            for (int off = 1; off < 16; off <<= 1) {
                a += __shfl_xor(a, off, 64);
                bb += __shfl_xor(bb, off, 64);
            }
            l0[r] += a;
            l1[r] += bb;
        }

#pragma unroll
        for (int kc = 0; kc < 8; ++kc)
#pragma unroll
            for (int r = 0; r < 4; ++r) {
                Pw[(lg * 4 + r) * P_STRIDE + kc * 16 + ll]      = f2bf(s0[kc][r]);
                Pw[(16 + lg * 4 + r) * P_STRIDE + kc * 16 + ll] = f2bf(s1[kc][r]);
            }
        asm volatile("" ::: "memory");

#pragma unroll
        for (int kc2 = 0; kc2 < 4; ++kc2) {
            bf16x8 va = *(const bf16x8*)(Vh + (size_t)ll * N_NODES + kt + kc2 * 32 + lg * 8);
            bf16x8 vb = *(const bf16x8*)(Vh + (size_t)(16 + ll) * N_NODES + kt + kc2 * 32 + lg * 8);
            bf16x8 pf0 = *(const bf16x8*)(Pw + ll * P_STRIDE + kc2 * 32 + lg * 8);
            bf16x8 pf1 = *(const bf16x8*)(Pw + (16 + ll) * P_STRIDE + kc2 * 32 + lg * 8);
            oacc00 = __builtin_amdgcn_mfma_f32_16x16x32_bf16(pf0, va, oacc00, 0, 0, 0);
            oacc01 = __builtin_amdgcn_mfma_f32_16x16x32_bf16(pf0, vb, oacc01, 0, 0, 0);
            oacc10 = __builtin_amdgcn_mfma_f32_16x16x32_bf16(pf1, va, oacc10, 0, 0, 0);
            oacc11 = __builtin_amdgcn_mfma_f32_16x16x32_bf16(pf1, vb, oacc11, 0, 0, 0);
        }
    }

    __syncthreads();

#pragma unroll
    for (int r = 0; r < 4; ++r) {
        Ouns[wv][lg * 4 + r][ll]           = oacc00[r];
        Ouns[wv][lg * 4 + r][16 + ll]      = oacc01[r];
        Ouns[wv][16 + lg * 4 + r][ll]      = oacc10[r];
        Ouns[wv][16 + lg * 4 + r][16 + ll] = oacc11[r];
    }
    if (ll == 0) {
#pragma unroll
        for (int r = 0; r < 4; ++r) {
            Llp[wv][lg * 4 + r]      = l0[r];
            Llp[wv][16 + lg * 4 + r] = l1[r];
        }
    }
    __syncthreads();

    {
        const int row = tid >> 4, col = tid & 15;
        float L = 0.f, oa = 0.f, obv = 0.f;
#pragma unroll
        for (int w = 0; w < 8; ++w) {
            L   += Llp[w][row];
            oa  += Ouns[w][row][col];
            obv += Ouns[w][row][16 + col];
        }
        float inv = 1.f / L;
        ob[(size_t)(q0 + row) * C_DIM + h * D_HEAD + col]      = f2bf(oa * inv);
        ob[(size_t)(q0 + row) * C_DIM + h * D_HEAD + 16 + col] = f2bf(obv * inv);
    }
}

// ---------------------------------------------------------------------------
// bf16 MFMA GEMM, LDS-free, 16x16 tile per wave. grid (J/64, N/16).
// Optional fused BatchNorm stats (2 wave-reduced atomics per column).
// ---------------------------------------------------------------------------
template <int K>
__global__ __launch_bounds__(256, 8) void gemm_bf(const unsigned short* __restrict__ Abf,
                                                  const unsigned short* __restrict__ Wbf,
                                                  const float* __restrict__ bias,
                                                  const float* __restrict__ resid,
                                                  float* __restrict__ outf,
                                                  unsigned short* __restrict__ outb,
                                                  float* __restrict__ stats,
                                                  const int J, const int relu) {
    const int tid = threadIdx.x;
    const int wv = tid >> 6;
    const int lane = tid & 63, lg = lane >> 4, ll = lane & 15;
    const int rowbase = blockIdx.y * 16;
    const int colbase = blockIdx.x * 64 + wv * 16;

    const unsigned short* Ap = Abf + (size_t)(rowbase + ll) * K + lg * 8;
    const unsigned short* Wp = Wbf + (size_t)(colbase + ll) * K + lg * 8;

    f32x4 acc = {0.f, 0.f, 0.f, 0.f};
#pragma unroll
    for (int k = 0; k < K; k += 32) {
        bf16x8 a = *(const bf16x8*)(Ap + k);
        bf16x8 b = *(const bf16x8*)(Wp + k);
        acc = __builtin_amdgcn_mfma_f32_16x16x32_bf16(a, b, acc, 0, 0, 0);
    }

    const int col = colbase + ll;
    const float bi = bias[col];
    float sv = 0.f, sv2 = 0.f;
#pragma unroll
    for (int r = 0; r < 4; ++r) {
        const int row = rowbase + lg * 4 + r;
        float v = acc[r] + bi;
        if (resid) v += resid[(size_t)row * J + col];
        if (relu) v = fmaxf(v, 0.f);
        if (outf) outf[(size_t)row * J + col] = v;
        if (outb) outb[(size_t)row * J + col] = f2bf(v);
        sv += v; sv2 += v * v;
    }
    if (stats) {
        sv  += __shfl_xor(sv, 16, 64);  sv  += __shfl_xor(sv, 32, 64);
        sv2 += __shfl_xor(sv2, 16, 64); sv2 += __shfl_xor(sv2, 32, 64);
        if (lg == 0) {
            atomicAdd(&stats[col], sv);
            atomicAdd(&stats[C_DIM + col], sv2);
        }
    }
}

// ---------------------------------------------------------------------------
// Fused gin2 + aout (R14-proven).
// ---------------------------------------------------------------------------
__global__ __launch_bounds__(256, 8) void gemm2x(const unsigned short* __restrict__ A0,
                                                 const unsigned short* __restrict__ W0,
                                                 const float* __restrict__ bias0,
                                                 float* __restrict__ out0,
                                                 float* __restrict__ stats0,
                                                 const unsigned short* __restrict__ A1,
                                                 const unsigned short* __restrict__ W1,
                                                 const float* __restrict__ bias1,
                                                 float* __restrict__ out1,
                                                 float* __restrict__ stats1,
                                                 const float* __restrict__ resid) {
    const int b = blockIdx.x;
    const int which = b >> 9;
    const int bl = b & 511;
    const unsigned short* Abf = which ? A1 : A0;
    const unsigned short* Wbf = which ? W1 : W0;
    const float* bias = which ? bias1 : bias0;
    float* outf  = which ? out1 : out0;
    float* stats = which ? stats1 : stats0;

    const int tid = threadIdx.x;
    const int wv = tid >> 6;
    const int lane = tid & 63, lg = lane >> 4, ll = lane & 15;
    const int rowbase = (bl >> 1) * 16;
    const int colbase = (bl & 1) * 64 + wv * 16;

    const unsigned short* Ap = Abf + (size_t)(rowbase + ll) * 128 + lg * 8;
    const unsigned short* Wp = Wbf + (size_t)(colbase + ll) * 128 + lg * 8;

    f32x4 acc = {0.f, 0.f, 0.f, 0.f};
#pragma unroll
    for (int k = 0; k < 128; k += 32) {
        bf16x8 a = *(const bf16x8*)(Ap + k);
        bf16x8 w = *(const bf16x8*)(Wp + k);
        acc = __builtin_amdgcn_mfma_f32_16x16x32_bf16(a, w, acc, 0, 0, 0);
    }

    const int col = colbase + ll;
    const float bi = bias[col];
    float sv = 0.f, sv2 = 0.f;
#pragma unroll
    for (int r = 0; r < 4; ++r) {
        const int row = rowbase + lg * 4 + r;
        float v = acc[r] + bi + resid[(size_t)row * 128 + col];
        outf[(size_t)row * 128 + col] = v;
        sv += v; sv2 += v * v;
    }
    sv  += __shfl_xor(sv, 16, 64);  sv  += __shfl_xor(sv, 32, 64);
    sv2 += __shfl_xor(sv2, 16, 64); sv2 += __shfl_xor(sv2, 32, 64);
    if (lg == 0) {
        atomicAdd(&stats[col], sv);
        atomicAdd(&stats[128 + col], sv2);
    }
}

// ---------------------------------------------------------------------------
// MLP1 with fused BN-combine (replaces combine2 + old mlp1):
// phase A: 128 thr compute per-channel (sc1,sh1,sc2,sh2) from raw sums -> LDS
// phase B: block computes its 16x128 h-tile = bn1(g1)+bn2(a2) (same math as
//          old combine2), stores bf16 tile to LDS; blockIdx.x==0 also writes
//          fp32 h to hbuf (mlp2 residual).
// phase C: J=256 GEMM, A-fragments from LDS. grid (4, 256), 256 thr.
// ---------------------------------------------------------------------------
__global__ __launch_bounds__(256, 8) void mlp1_fused(const float* __restrict__ g1p,
                                                     const float* __restrict__ a2p,
                                                     const float* __restrict__ st1,
                                                     const float* __restrict__ st2,
                                                     const float* __restrict__ g1v,
                                                     const float* __restrict__ b1v,
                                                     const float* __restrict__ g2v,
                                                     const float* __restrict__ b2v,
                                                     const unsigned short* __restrict__ Wbf,
                                                     const float* __restrict__ bias,
                                                     float* __restrict__ hbuf,
                                                     unsigned short* __restrict__ t2out) {
    __shared__ __align__(16) unsigned short hs[16 * HS_STRIDE];
    __shared__ float scl[4][128];

    const int tid = threadIdx.x;
    const int bx = blockIdx.x;
    const int rowbase = blockIdx.y * 16;
    const float inv_n = 1.f / N_NODES;

    // phase A: per-channel BN scales
    if (tid < 128) {
        const int ch = tid;
        float m1 = st1[ch] * inv_n;
        float v1 = st1[128 + ch] * inv_n - m1 * m1;
        float r1 = rsqrtf(v1 + 1e-5f);
        float sc1 = g1v[ch] * r1;
        scl[0][ch] = sc1;
        scl[1][ch] = b1v[ch] - m1 * sc1;
        float m2 = st2[ch] * inv_n;
        float v2 = st2[128 + ch] * inv_n - m2 * m2;
        float r2 = rsqrtf(v2 + 1e-5f);
        float sc2 = g2v[ch] * r2;
        scl[2][ch] = sc2;
        scl[3][ch] = b2v[ch] - m2 * sc2;
    }
    __syncthreads();

    // phase B: h tile (16 rows x 128 cols) = bn1(g1)+bn2(a2)
#pragma unroll
    for (int j = tid; j < 512; j += 256) {
        const int r = j >> 5, cq = (j & 31) * 4;
        float4 v1 = *(const float4*)(g1p + (size_t)(rowbase + r) * 128 + cq);
        float4 v2 = *(const float4*)(a2p + (size_t)(rowbase + r) * 128 + cq);
        float h0 = v1.x * scl[0][cq]     + scl[1][cq]     + v2.x * scl[2][cq]     + scl[3][cq];
        float h1 = v1.y * scl[0][cq + 1] + scl[1][cq + 1] + v2.y * scl[2][cq + 1] + scl[3][cq + 1];
        float h2 = v1.z * scl[0][cq + 2] + scl[1][cq + 2] + v2.z * scl[2][cq + 2] + scl[3][cq + 2];
        float h3 = v1.w * scl[0][cq + 3] + scl[1][cq + 3] + v2.w * scl[2][cq + 3] + scl[3][cq + 3];
        ushort4 u;
        u.x = f2bf(h0); u.y = f2bf(h1); u.z = f2bf(h2); u.w = f2bf(h3);
        *(ushort4*)(&hs[r * HS_STRIDE + cq]) = u;
        if (bx == 0) {
            float4 o = {h0, h1, h2, h3};
            *(float4*)(hbuf + (size_t)(rowbase + r) * 128 + cq) = o;
        }
    }
    __syncthreads();

    // phase C: GEMM (J=256), A from LDS
    const int wv = tid >> 6;
    const int lane = tid & 63, lg = lane >> 4, ll = lane & 15;
    const int colbase = bx * 64 + wv * 16;
    const unsigned short* Wp = Wbf + (size_t)(colbase + ll) * 128 + lg * 8;

    f32x4 acc = {0.f, 0.f, 0.f, 0.f};
#pragma unroll
    for (int k = 0; k < 128; k += 32) {
        bf16x8 a = *(const bf16x8*)(&hs[ll * HS_STRIDE + k + lg * 8]);
        bf16x8 w = *(const bf16x8*)(Wp + k);
        acc = __builtin_amdgcn_mfma_f32_16x16x32_bf16(a, w, acc, 0, 0, 0);
    }

    const int col = colbase + ll;
    const float bi = bias[col];
#pragma unroll
    for (int r = 0; r < 4; ++r) {
        const int row = rowbase + lg * 4 + r;
        float v = fmaxf(acc[r] + bi, 0.f);
        t2out[(size_t)row * 256 + col] = f2bf(v);
    }
}

// x = bn3(m3), scales inline from raw sums
__global__ __launch_bounds__(256) void bn_apply(const float* __restrict__ p,
                                                const float* __restrict__ st,
                                                const float* __restrict__ gv,
                                                const float* __restrict__ bv,
                                                float* __restrict__ out,
                                                unsigned short* __restrict__ outb) {
    int idx = blockIdx.x * 256 + threadIdx.x;
    int c4 = (idx & 31) * 4;
    const float inv_n = 1.f / N_NODES;
    float sc[4], sh[4];
#pragma unroll
    for (int c = 0; c < 4; ++c) {
        int ch = c4 + c;
        float m = st[ch] * inv_n;
        float vv = st[C_DIM + ch] * inv_n - m * m;
        float r = rsqrtf(vv + 1e-5f);
        sc[c] = gv[ch] * r; sh[c] = bv[ch] - m * sc[c];
    }
    float4 v = ((const float4*)p)[idx];
    float4 o;
    o.x = v.x * sc[0] + sh[0];
    o.y = v.y * sc[1] + sh[1];
    o.z = v.z * sc[2] + sh[2];
    o.w = v.w * sc[3] + sh[3];
    ((float4*)out)[idx] = o;
    ushort4 ub;
    ub.x = f2bf(o.x); ub.y = f2bf(o.y); ub.z = f2bf(o.z); ub.w = f2bf(o.w);
    *(ushort4*)(outb + (size_t)idx * 4) = ub;
}

// ---------------------------------------------------------------------------
// Fused head MLP
// ---------------------------------------------------------------------------
__global__ __launch_bounds__(256) void head_fused(const float* __restrict__ x,
                                                  const float* __restrict__ w1,
                                                  const float* __restrict__ b1,
                                                  const float* __restrict__ w2,
                                                  const float* __restrict__ b2,
                                                  const float* __restrict__ w3,
                                                  const float* __restrict__ b3,
                                                  float* __restrict__ out) {
    __shared__ __align__(16) float xs[8][128];
    __shared__ __align__(16) float hs2[8][64];
    const int tid = threadIdx.x;
    const int n = tid >> 5;
    const int g = tid & 31;
    const int node0 = blockIdx.x * 8;

    {
        int r = tid >> 5, q = tid & 31;
        *(float4*)(&xs[r][q * 4]) = *(const float4*)(x + (size_t)(node0 + r) * 128 + q * 4);
    }
    __syncthreads();

    {
        float acc0 = b1[g], acc1 = b1[g + 32];
        const float* wa = w1 + (size_t)g * 128;
        const float* wb = w1 + (size_t)(g + 32) * 128;
#pragma unroll 8
        for (int k = 0; k < 128; k += 4) {
            float4 xv = *(const float4*)(&xs[n][k]);
            float4 va = *(const float4*)(wa + k);
            float4 vb = *(const float4*)(wb + k);
            acc0 += xv.x * va.x + xv.y * va.y + xv.z * va.z + xv.w * va.w;
            acc1 += xv.x * vb.x + xv.y * vb.y + xv.z * vb.z + xv.w * vb.w;
        }
        hs2[n][g]      = fmaxf(acc0, 0.f);
        hs2[n][g + 32] = fmaxf(acc1, 0.f);
    }
    __syncthreads();

    {
        float acc = b2[g];
        const float* wr = w2 + (size_t)g * 64;
#pragma unroll 8
        for (int k = 0; k < 64; k += 4) {
            float4 hv = *(const float4*)(&hs2[n][k]);
            float4 wv = *(const float4*)(wr + k);
            acc += hv.x * wv.x + hv.y * wv.y + hv.z * wv.z + hv.w * wv.w;
        }
        float t = fmaxf(acc, 0.f) * w3[g];
#pragma unroll
        for (int off = 1; off < 32; off <<= 1) t += __shfl_xor(t, off, 64);
        if (g == 0) out[node0 + n] = t + b3[0];
    }
}

// ---------------------------------------------------------------------------
extern "C" void kernel_launch(void* const* d_in, const int* in_sizes, int n_in,
                              void* d_out, int out_size, void* d_ws, size_t ws_size,
                              hipStream_t stream) {
    (void)in_sizes; (void)n_in; (void)out_size; (void)ws_size;
    const float* x_in   = (const float*)d_in[0];
    const int*   ei     = (const int*)d_in[1];
    const float* gin_w1 = (const float*)d_in[2];
    const float* gin_b1 = (const float*)d_in[3];
    const float* gin_w2 = (const float*)d_in[4];
    const float* gin_b2 = (const float*)d_in[5];
    const float* ain_w  = (const float*)d_in[6];
    const float* ain_b  = (const float*)d_in[7];
    const float* aout_w = (const float*)d_in[8];
    const float* aout_b = (const float*)d_in[9];
    const float* n1_g   = (const float*)d_in[10];
    const float* n1_b   = (const float*)d_in[11];
    const float* n2_g   = (const float*)d_in[12];
    const float* n2_b   = (const float*)d_in[13];
    const float* n3_g   = (const float*)d_in[14];
    const float* n3_b   = (const float*)d_in[15];
    const float* mlp_w1 = (const float*)d_in[16];
    const float* mlp_b1 = (const float*)d_in[17];
    const float* mlp_w2 = (const float*)d_in[18];
    const float* mlp_b2 = (const float*)d_in[19];
    const float* h_w1   = (const float*)d_in[20];
    const float* h_b1   = (const float*)d_in[21];
    const float* h_w2   = (const float*)d_in[22];
    const float* h_b2   = (const float*)d_in[23];
    const float* h_w3   = (const float*)d_in[24];
    const float* h_b3   = (const float*)d_in[25];

    float* f = (float*)d_ws;
    float* g1   = f;                   // c0 (m3 aliases; g1 dead after mlp1/mlp2)
    float* m3   = f;
    float* a2   = f + 1 * (size_t)NC;  // c1 (hsum ushort overlay during steps 1-2)
    float* hbuf = f + 2 * (size_t)NC;  // c2 (t1_bf ushort overlay during GIN)
    float* xA   = f + 3 * (size_t)NC;
    float* xB   = f + 4 * (size_t)NC;
    unsigned short* R1  = (unsigned short*)(f + 5 * (size_t)NC);  // 3 NCu
    unsigned short* Qb      = R1;
    unsigned short* Kb      = R1 + (size_t)NCu;
    unsigned short* VT      = R1 + 2 * (size_t)NCu;
    unsigned short* t2_bf   = R1;                    // MLP1 out (QKV dead by then)
    unsigned short* R2      = R1 + 3 * (size_t)NCu;  // 1 NCu
    unsigned short* ao_bf   = R2;                    // attn out
    unsigned short* hsum_bf = (unsigned short*)a2;   // gather out (c1 overlay; dead before aout writes a2)
    unsigned short* t1_bf   = (unsigned short*)hbuf; // gin1 out (dead before mlp1 writes hbuf)
    unsigned short* xbf     = R2 + (size_t)NCu;
    unsigned short* wbf     = xbf + (size_t)NCu;
    float* ss    = (float*)(wbf + 655360);   // 768 raw sums (3 BNs)
    int* ibase    = (int*)(ss + 768);
    int* deg      = ibase;
    int* rowstart = ibase + 4096;
    int* cursor   = ibase + 4096 + 4098;
    int* csr_src  = ibase + 4096 + 4098 + 4096;

    const int OG1 = 0, OG2 = 65536, OAI = 131072, OAO = 327680, OM1 = 393216, OM2 = 524288;

    hipMemsetAsync(deg, 0, 4096 * sizeof(int), stream);
    hist_kernel<<<E_EDGES / 256, 256, 0, stream>>>(ei, deg);
    scan_kernel<<<1, 256, 0, stream>>>(deg, rowstart, cursor);
    fill_kernel<<<E_EDGES / 256, 256, 0, stream>>>(ei, cursor, csr_src);
    wcvt<<<320, 256, 0, stream>>>(gin_w1, gin_w2, ain_w, aout_w, mlp_w1, mlp_w2, wbf);
    x2bf<<<NC / 2048, 256, 0, stream>>>(x_in, xbf);

    for (int i = 0; i < L_LAYERS; ++i) {
        const float* xin = (i == 0) ? x_in : ((i & 1) ? xA : xB);
        float* xout = (i & 1) ? xB : xA;
        const float* gb1 = gin_b1 + (size_t)i * C_DIM;
        const float* gb2 = gin_b2 + (size_t)i * C_DIM;
        const float* aib = ain_b + (size_t)i * 3 * C_DIM;
        const float* aob = aout_b + (size_t)i * C_DIM;
        const float* mb1 = mlp_b1 + (size_t)i * 2 * C_DIM;
        const float* mb2 = mlp_b2 + (size_t)i * C_DIM;

        // 1) fused QKV GEMM + GIN gather (both read xbf); zeroes ss
        qkv_gather<<<2560, 256, 0, stream>>>(xbf, wbf + OAI + (size_t)i * 49152, aib,
                                             Qb, Kb, VT, rowstart, csr_src,
                                             (unsigned int*)hsum_bf, ss);
        // 2) fused attention + gin1
        attn_gin1<<<768, 512, 0, stream>>>(Qb, Kb, VT, ao_bf,
                                           hsum_bf, wbf + OG1 + (size_t)i * 16384, gb1, t1_bf);
        // 3) fused gin2 + aout (stats into ss/ss+256)
        gemm2x<<<1024, 256, 0, stream>>>(t1_bf, wbf + OG2 + (size_t)i * 16384, gb2, g1, ss,
                                         ao_bf, wbf + OAO + (size_t)i * 16384, aob, a2, ss + 256,
                                         xin);
        // 4) MLP1 with fused BN-combine (replaces combine2 + mlp1)
        mlp1_fused<<<dim3(4, 256), 256, 0, stream>>>(g1, a2, ss, ss + 256,
                                                     n1_g + (size_t)i * C_DIM, n1_b + (size_t)i * C_DIM,
                                                     n2_g + (size_t)i * C_DIM, n2_b + (size_t)i * C_DIM,
                                                     wbf + OM1 + (size_t)i * 32768, mb1,
                                                     hbuf, t2_bf);
        // 5) MLP2 (resid = hbuf written by mlp1_fused bx==0 blocks)
        gemm_bf<256><<<dim3(2, 256), 256, 0, stream>>>(t2_bf, wbf + OM2 + (size_t)i * 32768,
                                                       mb2, hbuf, m3, nullptr, ss + 512, 128, 0);
        // 6) final BN
        bn_apply<<<512, 256, 0, stream>>>(m3, ss + 512,
                                          n3_g + (size_t)i * C_DIM, n3_b + (size_t)i * C_DIM,
                                          xout, xbf);
    }

    const float* xf = xB;  // after layer 3
    head_fused<<<N_NODES / 8, 256, 0, stream>>>(xf, h_w1, h_b1, h_w2, h_b2, h_w3, h_b3,
                                                (float*)d_out);
}

// Round 16
// 383.533 us; speedup vs baseline: 1.3119x; 1.0524x over previous
//
#include <hip/hip_runtime.h>

#define N_NODES 4096
#define C_DIM   128
#define L_LAYERS 4
#define E_EDGES 131072
#define H_HEADS 4
#define D_HEAD  32
#define NC      (N_NODES * C_DIM)
#define NCu     (N_NODES * C_DIM)
#define P_STRIDE 136
#define HS_STRIDE 152   // bf16 h tile stride (ushorts)
#define T2S       264   // bf16 t2 tile stride (ushorts)

typedef short bf16x8 __attribute__((ext_vector_type(8)));
typedef float f32x4  __attribute__((ext_vector_type(4)));

__device__ __forceinline__ unsigned short f2bf(float f) {
    unsigned int u = __float_as_uint(f);
    u += 0x7fffu + ((u >> 16) & 1u);
    return (unsigned short)(u >> 16);
}

__device__ __forceinline__ float bf_lo(unsigned int u) { return __uint_as_float(u << 16); }
__device__ __forceinline__ float bf_hi(unsigned int u) { return __uint_as_float(u & 0xffff0000u); }

__device__ __forceinline__ bf16x8 pack8(const float* v) {
    bf16x8 o;
#pragma unroll
    for (int i = 0; i < 8; ++i) o[i] = (short)f2bf(v[i]);
    return o;
}

// ---------------------------------------------------------------------------
// CSR build (once per launch)
// ---------------------------------------------------------------------------
__global__ __launch_bounds__(256) void hist_kernel(const int* __restrict__ ei,
                                                   int* __restrict__ deg) {
    int e = blockIdx.x * 256 + threadIdx.x;
    atomicAdd(&deg[ei[E_EDGES + e]], 1);
}

__global__ __launch_bounds__(256) void scan_kernel(const int* __restrict__ deg,
                                                   int* __restrict__ rowstart,
                                                   int* __restrict__ cursor) {
    __shared__ int ts[256];
    const int tid = threadIdx.x;
    int loc[16];
    int s = 0;
#pragma unroll
    for (int i = 0; i < 16; ++i) { loc[i] = s; s += deg[tid * 16 + i]; }
    ts[tid] = s;
    __syncthreads();
    for (int off = 1; off < 256; off <<= 1) {
        int t = (tid >= off) ? ts[tid - off] : 0;
        __syncthreads();
        if (tid >= off) ts[tid] += t;
        __syncthreads();
    }
    int off0 = ts[tid] - s;
#pragma unroll
    for (int i = 0; i < 16; ++i) {
        int v = off0 + loc[i];
        rowstart[tid * 16 + i] = v;
        cursor[tid * 16 + i] = v;
    }
    if (tid == 255) rowstart[4096] = off0 + s;
}

__global__ __launch_bounds__(256) void fill_kernel(const int* __restrict__ ei,
                                                   int* __restrict__ cursor,
                                                   int* __restrict__ csr_src) {
    int e = blockIdx.x * 256 + threadIdx.x;
    int d = ei[E_EDGES + e];
    int s = ei[e];
    int p = atomicAdd(&cursor[d], 1);
    csr_src[p] = s;
}

// ---------------------------------------------------------------------------
// weight pre-convert fp32 -> bf16
// ---------------------------------------------------------------------------
__global__ __launch_bounds__(256) void wcvt(const float* __restrict__ s0, const float* __restrict__ s1,
                                            const float* __restrict__ s2, const float* __restrict__ s3,
                                            const float* __restrict__ s4, const float* __restrict__ s5,
                                            unsigned short* __restrict__ wbf) {
    int i0 = (blockIdx.x * 256 + threadIdx.x) * 8;
    const float* src; int base;
    if      (i0 < 65536)  { src = s0; base = 0; }
    else if (i0 < 131072) { src = s1; base = 65536; }
    else if (i0 < 327680) { src = s2; base = 131072; }
    else if (i0 < 393216) { src = s3; base = 327680; }
    else if (i0 < 524288) { src = s4; base = 393216; }
    else                  { src = s5; base = 524288; }
    const float* p = src + (i0 - base);
    float t[8];
#pragma unroll
    for (int i = 0; i < 8; ++i) t[i] = p[i];
    *(bf16x8*)(wbf + i0) = pack8(t);
}

__global__ __launch_bounds__(256) void x2bf(const float* __restrict__ x,
                                            unsigned short* __restrict__ xb) {
    int i0 = (blockIdx.x * 256 + threadIdx.x) * 8;
    float t[8];
#pragma unroll
    for (int i = 0; i < 8; ++i) t[i] = x[i0 + i];
    *(bf16x8*)(xb + i0) = pack8(t);
}

// ---------------------------------------------------------------------------
// Fused QKV-GEMM + GIN-gather (R13-proven). hsum lands in the c1 overlay.
// ---------------------------------------------------------------------------
__global__ __launch_bounds__(256, 8) void qkv_gather(const unsigned short* __restrict__ xb,
                                                     const unsigned short* __restrict__ Wbf,
                                                     const float* __restrict__ bias,
                                                     unsigned short* __restrict__ Qb,
                                                     unsigned short* __restrict__ Kb,
                                                     unsigned short* __restrict__ VT,
                                                     const int* __restrict__ rowstart,
                                                     const int* __restrict__ csr_src,
                                                     unsigned int* __restrict__ hsum,
                                                     float* __restrict__ ssz) {
    const int b = blockIdx.x;
    const int tid = threadIdx.x;
    if (b < 1536) {
        const int ct = b % 6, rt = b / 6;
        const int wv = tid >> 6;
        const int lane = tid & 63, lg = lane >> 4, ll = lane & 15;
        const int rowbase = rt * 16;
        const int colbase = ct * 64 + wv * 16;

        const unsigned short* Ap = xb  + (size_t)(rowbase + ll) * 128 + lg * 8;
        const unsigned short* Wp = Wbf + (size_t)(colbase + ll) * 128 + lg * 8;

        f32x4 acc = {0.f, 0.f, 0.f, 0.f};
#pragma unroll
        for (int k = 0; k < 128; k += 32) {
            bf16x8 a = *(const bf16x8*)(Ap + k);
            bf16x8 w = *(const bf16x8*)(Wp + k);
            acc = __builtin_amdgcn_mfma_f32_16x16x32_bf16(a, w, acc, 0, 0, 0);
        }

        const float qsc = 0.25506973f;  // (1/sqrt(32)) * log2(e)
        const int col = colbase + ll;
        const float bi = bias[col];
#pragma unroll
        for (int r = 0; r < 4; ++r) {
            const int row = rowbase + lg * 4 + r;
            float v = acc[r] + bi;
            if (col < 128) {
                int hh = col >> 5, d = col & 31;
                Qb[((size_t)hh * N_NODES + row) * D_HEAD + d] = f2bf(v * qsc);
            } else if (col < 256) {
                int c2 = col - 128, hh = c2 >> 5, d = c2 & 31;
                Kb[((size_t)hh * N_NODES + row) * D_HEAD + d] = f2bf(v);
            } else {
                int c2 = col - 256, hh = c2 >> 5, d = c2 & 31;
                VT[((size_t)hh * D_HEAD + d) * N_NODES + row] = f2bf(v);
            }
        }
    } else {
        if (b == 1536) {
            ssz[tid] = 0.f; ssz[256 + tid] = 0.f; ssz[512 + tid] = 0.f;
        }
        const int node = (b - 1536) * 4 + (tid >> 6);
        const int lane = tid & 63;
        const unsigned int* xu = (const unsigned int*)xb;
        const int beg = rowstart[node], end = rowstart[node + 1];
        unsigned int su = xu[(size_t)node * 64 + lane];
        float ax = bf_lo(su), ay = bf_hi(su);
        float bx = 0.f, by = 0.f;
        int e = beg;
        for (; e + 4 <= end; e += 4) {
            int s0 = csr_src[e], s1 = csr_src[e + 1], s2 = csr_src[e + 2], s3 = csr_src[e + 3];
            unsigned int u0 = xu[(size_t)s0 * 64 + lane];
            unsigned int u1 = xu[(size_t)s1 * 64 + lane];
            unsigned int u2 = xu[(size_t)s2 * 64 + lane];
            unsigned int u3 = xu[(size_t)s3 * 64 + lane];
            ax += bf_lo(u0) + bf_lo(u1); ay += bf_hi(u0) + bf_hi(u1);
            bx += bf_lo(u2) + bf_lo(u3); by += bf_hi(u2) + bf_hi(u3);
        }
        for (; e < end; ++e) {
            unsigned int u0 = xu[(size_t)csr_src[e] * 64 + lane];
            ax += bf_lo(u0); ay += bf_hi(u0);
        }
        float ox = ax + bx, oy = ay + by;
        hsum[(size_t)node * 64 + lane] = (unsigned int)f2bf(ox) | ((unsigned int)f2bf(oy) << 16);
    }
}

// ---------------------------------------------------------------------------
// Fused attention + GIN-MLP-1 (R14/R15-proven, byte-identical).
// ---------------------------------------------------------------------------
__global__ __launch_bounds__(512, 4) void attn_gin1(const unsigned short* __restrict__ Qb,
                                                    const unsigned short* __restrict__ Kb,
                                                    const unsigned short* __restrict__ VT,
                                                    unsigned short* __restrict__ ob,
                                                    const unsigned short* __restrict__ hsum,
                                                    const unsigned short* __restrict__ W1,
                                                    const float* __restrict__ bias1,
                                                    unsigned short* __restrict__ t1out) {
    __shared__ __align__(16) unsigned short Pl[8 * 32 * P_STRIDE];
    float (*Ouns)[32][33] = (float (*)[32][33])(void*)Pl;
    float (*Llp)[32] = (float (*)[32])(void*)(Pl + 8 * 32 * 33 * 2);

    const int b   = blockIdx.x;
    const int tid = threadIdx.x;
    const int wv  = tid >> 6;
    const int lane = tid & 63;
    const int lg  = lane >> 4;
    const int ll  = lane & 15;

    if (b >= 512) {
        const int rowbase = (b - 512) * 16;
        const int colbase = wv * 16;
        const unsigned short* Ap = hsum + (size_t)(rowbase + ll) * 128 + lg * 8;
        const unsigned short* Wp = W1 + (size_t)(colbase + ll) * 128 + lg * 8;
        f32x4 acc = {0.f, 0.f, 0.f, 0.f};
#pragma unroll
        for (int k = 0; k < 128; k += 32) {
            bf16x8 a = *(const bf16x8*)(Ap + k);
            bf16x8 w = *(const bf16x8*)(Wp + k);
            acc = __builtin_amdgcn_mfma_f32_16x16x32_bf16(a, w, acc, 0, 0, 0);
        }
        const int col = colbase + ll;
        const float bi = bias1[col];
#pragma unroll
        for (int r = 0; r < 4; ++r) {
            const int row = rowbase + lg * 4 + r;
            float v = fmaxf(acc[r] + bi, 0.f);
            t1out[(size_t)row * 128 + col] = f2bf(v);
        }
        return;
    }

    const int h   = b >> 7;
    const int q0  = (b & 127) * 32;

    const unsigned short* Qh = Qb + ((size_t)h * N_NODES + q0) * D_HEAD;
    const unsigned short* Kh = Kb + (size_t)h * N_NODES * D_HEAD;
    const unsigned short* Vh = VT + (size_t)h * D_HEAD * N_NODES;

    bf16x8 qf0 = *(const bf16x8*)(Qh + ll * D_HEAD + lg * 8);
    bf16x8 qf1 = *(const bf16x8*)(Qh + (16 + ll) * D_HEAD + lg * 8);

    f32x4 oacc00 = {0.f,0.f,0.f,0.f}, oacc01 = {0.f,0.f,0.f,0.f};
    f32x4 oacc10 = {0.f,0.f,0.f,0.f}, oacc11 = {0.f,0.f,0.f,0.f};
    float l0[4] = {0.f,0.f,0.f,0.f}, l1[4] = {0.f,0.f,0.f,0.f};

    unsigned short* Pw = Pl + wv * (32 * P_STRIDE);
    const int k0 = wv * (N_NODES / 8);

    for (int t = 0; t < (N_NODES / 8) / 128; ++t) {
        const int kt = k0 + t * 128;

        float s0[8][4], s1[8][4];
#pragma unroll
        for (int kc = 0; kc < 8; ++kc) {
            bf16x8 kf = *(const bf16x8*)(Kh + (size_t)(kt + kc * 16 + ll) * D_HEAD + lg * 8);
            f32x4 z = {0.f, 0.f, 0.f, 0.f};
            f32x4 d0 = __builtin_amdgcn_mfma_f32_16x16x32_bf16(qf0, kf, z, 0, 0, 0);
            f32x4 d1 = __builtin_amdgcn_mfma_f32_16x16x32_bf16(qf1, kf, z, 0, 0, 0);
#pragma unroll
            for (int r = 0; r < 4; ++r) { s0[kc][r] = d0[r]; s1[kc][r] = d1[r]; }
        }

#pragma unroll
        for (int r = 0; r < 4; ++r) {
            float a = 0.f, bb = 0.f;
#pragma unroll
            for (int kc = 0; kc < 8; ++kc) {
                float p0 = exp2f(s0[kc][r]); s0[kc][r] = p0; a += p0;
                float p1 = exp2f(s1[kc][r]); s1[kc][r] = p1; bb += p1;
            }
#pragma unroll
            for (int off = 1; off < 16; off <<= 1) {
                a += __shfl_xor(a, off, 64);
                bb += __shfl_xor(bb, off, 64);
            }
            l0[r] += a;
            l1[r] += bb;
        }

#pragma unroll
        for (int kc = 0; kc < 8; ++kc)
#pragma unroll
            for (int r = 0; r < 4; ++r) {
                Pw[(lg * 4 + r) * P_STRIDE + kc * 16 + ll]      = f2bf(s0[kc][r]);
                Pw[(16 + lg * 4 + r) * P_STRIDE + kc * 16 + ll] = f2bf(s1[kc][r]);
            }
        asm volatile("" ::: "memory");

#pragma unroll
        for (int kc2 = 0; kc2 < 4; ++kc2) {
            bf16x8 va = *(const bf16x8*)(Vh + (size_t)ll * N_NODES + kt + kc2 * 32 + lg * 8);
            bf16x8 vb = *(const bf16x8*)(Vh + (size_t)(16 + ll) * N_NODES + kt + kc2 * 32 + lg * 8);
            bf16x8 pf0 = *(const bf16x8*)(Pw + ll * P_STRIDE + kc2 * 32 + lg * 8);
            bf16x8 pf1 = *(const bf16x8*)(Pw + (16 + ll) * P_STRIDE + kc2 * 32 + lg * 8);
            oacc00 = __builtin_amdgcn_mfma_f32_16x16x32_bf16(pf0, va, oacc00, 0, 0, 0);
            oacc01 = __builtin_amdgcn_mfma_f32_16x16x32_bf16(pf0, vb, oacc01, 0, 0, 0);
            oacc10 = __builtin_amdgcn_mfma_f32_16x16x32_bf16(pf1, va, oacc10, 0, 0, 0);
            oacc11 = __builtin_amdgcn_mfma_f32_16x16x32_bf16(pf1, vb, oacc11, 0, 0, 0);
        }
    }

    __syncthreads();

#pragma unroll
    for (int r = 0; r < 4; ++r) {
        Ouns[wv][lg * 4 + r][ll]           = oacc00[r];
        Ouns[wv][lg * 4 + r][16 + ll]      = oacc01[r];
        Ouns[wv][16 + lg * 4 + r][ll]      = oacc10[r];
        Ouns[wv][16 + lg * 4 + r][16 + ll] = oacc11[r];
    }
    if (ll == 0) {
#pragma unroll
        for (int r = 0; r < 4; ++r) {
            Llp[wv][lg * 4 + r]      = l0[r];
            Llp[wv][16 + lg * 4 + r] = l1[r];
        }
    }
    __syncthreads();

    {
        const int row = tid >> 4, col = tid & 15;
        float L = 0.f, oa = 0.f, obv = 0.f;
#pragma unroll
        for (int w = 0; w < 8; ++w) {
            L   += Llp[w][row];
            oa  += Ouns[w][row][col];
            obv += Ouns[w][row][16 + col];
        }
        float inv = 1.f / L;
        ob[(size_t)(q0 + row) * C_DIM + h * D_HEAD + col]      = f2bf(oa * inv);
        ob[(size_t)(q0 + row) * C_DIM + h * D_HEAD + 16 + col] = f2bf(obv * inv);
    }
}

// ---------------------------------------------------------------------------
// Fused gin2 + aout (R14-proven).
// ---------------------------------------------------------------------------
__global__ __launch_bounds__(256, 8) void gemm2x(const unsigned short* __restrict__ A0,
                                                 const unsigned short* __restrict__ W0,
                                                 const float* __restrict__ bias0,
                                                 float* __restrict__ out0,
                                                 float* __restrict__ stats0,
                                                 const unsigned short* __restrict__ A1,
                                                 const unsigned short* __restrict__ W1,
                                                 const float* __restrict__ bias1,
                                                 float* __restrict__ out1,
                                                 float* __restrict__ stats1,
                                                 const float* __restrict__ resid) {
    const int b = blockIdx.x;
    const int which = b >> 9;
    const int bl = b & 511;
    const unsigned short* Abf = which ? A1 : A0;
    const unsigned short* Wbf = which ? W1 : W0;
    const float* bias = which ? bias1 : bias0;
    float* outf  = which ? out1 : out0;
    float* stats = which ? stats1 : stats0;

    const int tid = threadIdx.x;
    const int wv = tid >> 6;
    const int lane = tid & 63, lg = lane >> 4, ll = lane & 15;
    const int rowbase = (bl >> 1) * 16;
    const int colbase = (bl & 1) * 64 + wv * 16;

    const unsigned short* Ap = Abf + (size_t)(rowbase + ll) * 128 + lg * 8;
    const unsigned short* Wp = Wbf + (size_t)(colbase + ll) * 128 + lg * 8;

    f32x4 acc = {0.f, 0.f, 0.f, 0.f};
#pragma unroll
    for (int k = 0; k < 128; k += 32) {
        bf16x8 a = *(const bf16x8*)(Ap + k);
        bf16x8 w = *(const bf16x8*)(Wp + k);
        acc = __builtin_amdgcn_mfma_f32_16x16x32_bf16(a, w, acc, 0, 0, 0);
    }

    const int col = colbase + ll;
    const float bi = bias[col];
    float sv = 0.f, sv2 = 0.f;
#pragma unroll
    for (int r = 0; r < 4; ++r) {
        const int row = rowbase + lg * 4 + r;
        float v = acc[r] + bi + resid[(size_t)row * 128 + col];
        outf[(size_t)row * 128 + col] = v;
        sv += v; sv2 += v * v;
    }
    sv  += __shfl_xor(sv, 16, 64);  sv  += __shfl_xor(sv, 32, 64);
    sv2 += __shfl_xor(sv2, 16, 64); sv2 += __shfl_xor(sv2, 32, 64);
    if (lg == 0) {
        atomicAdd(&stats[col], sv);
        atomicAdd(&stats[128 + col], sv2);
    }
}

// ---------------------------------------------------------------------------
// Fully fused MLP: BN-combine + MLP1(relu) + MLP2 + residual + stats.
// One block owns 16 rows; all intermediate (h, t2) stays in LDS.
// grid 256, 256 thr = 4 waves.
//  A: per-channel BN scales (128 thr) -> scl
//  B: h = bn1(g1)+bn2(a2): fp32 -> hf LDS (residual) + bf16 -> hs LDS
//  C: t2 = relu(h @ W1^T + b1): 4 col-tiles/wave -> t2s LDS (bf16)
//  D: m3 = t2 @ W2^T + b2 + h: K=256 from LDS, 2 col-tiles/wave; stats atomics
// Numerics identical to R15's combine2->mlp1->mlp2 chain.
// ---------------------------------------------------------------------------
__global__ __launch_bounds__(256) void mlp_fused(const float* __restrict__ g1p,
                                                 const float* __restrict__ a2p,
                                                 const float* __restrict__ st1,
                                                 const float* __restrict__ st2,
                                                 const float* __restrict__ g1v,
                                                 const float* __restrict__ b1v,
                                                 const float* __restrict__ g2v,
                                                 const float* __restrict__ b2v,
                                                 const unsigned short* __restrict__ W1bf,
                                                 const float* __restrict__ bias1,
                                                 const unsigned short* __restrict__ W2bf,
                                                 const float* __restrict__ bias2,
                                                 float* __restrict__ m3out,
                                                 float* __restrict__ stats3) {
    __shared__ float hf[16][132];                              // fp32 h (residual)
    __shared__ __align__(16) unsigned short hs[16 * HS_STRIDE]; // bf16 h
    __shared__ __align__(16) unsigned short t2s[16 * T2S];      // bf16 t2 (16x256)
    __shared__ float scl[4][128];

    const int tid = threadIdx.x;
    const int rowbase = blockIdx.x * 16;
    const float inv_n = 1.f / N_NODES;

    // phase A: per-channel BN scales
    if (tid < 128) {
        const int ch = tid;
        float m1 = st1[ch] * inv_n;
        float v1 = st1[128 + ch] * inv_n - m1 * m1;
        float r1 = rsqrtf(v1 + 1e-5f);
        float sc1 = g1v[ch] * r1;
        scl[0][ch] = sc1;
        scl[1][ch] = b1v[ch] - m1 * sc1;
        float m2 = st2[ch] * inv_n;
        float v2 = st2[128 + ch] * inv_n - m2 * m2;
        float r2 = rsqrtf(v2 + 1e-5f);
        float sc2 = g2v[ch] * r2;
        scl[2][ch] = sc2;
        scl[3][ch] = b2v[ch] - m2 * sc2;
    }
    __syncthreads();

    // phase B: h tile (16 rows x 128 cols)
#pragma unroll
    for (int j = tid; j < 512; j += 256) {
        const int r = j >> 5, cq = (j & 31) * 4;
        float4 v1 = *(const float4*)(g1p + (size_t)(rowbase + r) * 128 + cq);
        float4 v2 = *(const float4*)(a2p + (size_t)(rowbase + r) * 128 + cq);
        float h0 = v1.x * scl[0][cq]     + scl[1][cq]     + v2.x * scl[2][cq]     + scl[3][cq];
        float h1 = v1.y * scl[0][cq + 1] + scl[1][cq + 1] + v2.y * scl[2][cq + 1] + scl[3][cq + 1];
        float h2 = v1.z * scl[0][cq + 2] + scl[1][cq + 2] + v2.z * scl[2][cq + 2] + scl[3][cq + 2];
        float h3 = v1.w * scl[0][cq + 3] + scl[1][cq + 3] + v2.w * scl[2][cq + 3] + scl[3][cq + 3];
        hf[r][cq] = h0; hf[r][cq + 1] = h1; hf[r][cq + 2] = h2; hf[r][cq + 3] = h3;
        ushort4 u;
        u.x = f2bf(h0); u.y = f2bf(h1); u.z = f2bf(h2); u.w = f2bf(h3);
        *(ushort4*)(&hs[r * HS_STRIDE + cq]) = u;
    }
    __syncthreads();

    const int wv = tid >> 6;
    const int lane = tid & 63, lg = lane >> 4, ll = lane & 15;

    // phase C: t2 = relu(h @ W1^T + b1), J=256: 4 col-tiles per wave
#pragma unroll
    for (int ct = 0; ct < 4; ++ct) {
        const int colbase = wv * 16 + ct * 64;
        const unsigned short* Wp = W1bf + (size_t)(colbase + ll) * 128 + lg * 8;
        f32x4 acc = {0.f, 0.f, 0.f, 0.f};
#pragma unroll
        for (int k = 0; k < 128; k += 32) {
            bf16x8 a = *(const bf16x8*)(&hs[ll * HS_STRIDE + k + lg * 8]);
            bf16x8 w = *(const bf16x8*)(Wp + k);
            acc = __builtin_amdgcn_mfma_f32_16x16x32_bf16(a, w, acc, 0, 0, 0);
        }
        const int col = colbase + ll;
        const float bi = bias1[col];
#pragma unroll
        for (int r = 0; r < 4; ++r) {
            float v = fmaxf(acc[r] + bi, 0.f);
            t2s[(lg * 4 + r) * T2S + col] = f2bf(v);
        }
    }
    __syncthreads();

    // phase D: m3 = t2 @ W2^T + b2 + h; K=256, 2 col-tiles per wave
#pragma unroll
    for (int p = 0; p < 2; ++p) {
        const int colbase = p * 64 + wv * 16;
        const unsigned short* Wp = W2bf + (size_t)(colbase + ll) * 256 + lg * 8;
        f32x4 acc = {0.f, 0.f, 0.f, 0.f};
#pragma unroll
        for (int k = 0; k < 256; k += 32) {
            bf16x8 a = *(const bf16x8*)(&t2s[ll * T2S + k + lg * 8]);
            bf16x8 w = *(const bf16x8*)(Wp + k);
            acc = __builtin_amdgcn_mfma_f32_16x16x32_bf16(a, w, acc, 0, 0, 0);
        }
        const int col = colbase + ll;
        const float bi = bias2[col];
        float sv = 0.f, sv2 = 0.f;
#pragma unroll
        for (int r = 0; r < 4; ++r) {
            const int row = lg * 4 + r;
            float v = acc[r] + bi + hf[row][col];
            m3out[(size_t)(rowbase + row) * 128 + col] = v;
            sv += v; sv2 += v * v;
        }
        sv  += __shfl_xor(sv, 16, 64);  sv  += __shfl_xor(sv, 32, 64);
        sv2 += __shfl_xor(sv2, 16, 64); sv2 += __shfl_xor(sv2, 32, 64);
        if (lg == 0) {
            atomicAdd(&stats3[col], sv);
            atomicAdd(&stats3[128 + col], sv2);
        }
    }
}

// x = bn3(m3), scales inline from raw sums
__global__ __launch_bounds__(256) void bn_apply(const float* __restrict__ p,
                                                const float* __restrict__ st,
                                                const float* __restrict__ gv,
                                                const float* __restrict__ bv,
                                                float* __restrict__ out,
                                                unsigned short* __restrict__ outb) {
    int idx = blockIdx.x * 256 + threadIdx.x;
    int c4 = (idx & 31) * 4;
    const float inv_n = 1.f / N_NODES;
    float sc[4], sh[4];
#pragma unroll
    for (int c = 0; c < 4; ++c) {
        int ch = c4 + c;
        float m = st[ch] * inv_n;
        float vv = st[C_DIM + ch] * inv_n - m * m;
        float r = rsqrtf(vv + 1e-5f);
        sc[c] = gv[ch] * r; sh[c] = bv[ch] - m * sc[c];
    }
    float4 v = ((const float4*)p)[idx];
    float4 o;
    o.x = v.x * sc[0] + sh[0];
    o.y = v.y * sc[1] + sh[1];
    o.z = v.z * sc[2] + sh[2];
    o.w = v.w * sc[3] + sh[3];
    ((float4*)out)[idx] = o;
    ushort4 ub;
    ub.x = f2bf(o.x); ub.y = f2bf(o.y); ub.z = f2bf(o.z); ub.w = f2bf(o.w);
    *(ushort4*)(outb + (size_t)idx * 4) = ub;
}

// ---------------------------------------------------------------------------
// Fused head MLP
// ---------------------------------------------------------------------------
__global__ __launch_bounds__(256) void head_fused(const float* __restrict__ x,
                                                  const float* __restrict__ w1,
                                                  const float* __restrict__ b1,
                                                  const float* __restrict__ w2,
                                                  const float* __restrict__ b2,
                                                  const float* __restrict__ w3,
                                                  const float* __restrict__ b3,
                                                  float* __restrict__ out) {
    __shared__ __align__(16) float xs[8][128];
    __shared__ __align__(16) float hs2[8][64];
    const int tid = threadIdx.x;
    const int n = tid >> 5;
    const int g = tid & 31;
    const int node0 = blockIdx.x * 8;

    {
        int r = tid >> 5, q = tid & 31;
        *(float4*)(&xs[r][q * 4]) = *(const float4*)(x + (size_t)(node0 + r) * 128 + q * 4);
    }
    __syncthreads();

    {
        float acc0 = b1[g], acc1 = b1[g + 32];
        const float* wa = w1 + (size_t)g * 128;
        const float* wb = w1 + (size_t)(g + 32) * 128;
#pragma unroll 8
        for (int k = 0; k < 128; k += 4) {
            float4 xv = *(const float4*)(&xs[n][k]);
            float4 va = *(const float4*)(wa + k);
            float4 vb = *(const float4*)(wb + k);
            acc0 += xv.x * va.x + xv.y * va.y + xv.z * va.z + xv.w * va.w;
            acc1 += xv.x * vb.x + xv.y * vb.y + xv.z * vb.z + xv.w * vb.w;
        }
        hs2[n][g]      = fmaxf(acc0, 0.f);
        hs2[n][g + 32] = fmaxf(acc1, 0.f);
    }
    __syncthreads();

    {
        float acc = b2[g];
        const float* wr = w2 + (size_t)g * 64;
#pragma unroll 8
        for (int k = 0; k < 64; k += 4) {
            float4 hv = *(const float4*)(&hs2[n][k]);
            float4 wv = *(const float4*)(wr + k);
            acc += hv.x * wv.x + hv.y * wv.y + hv.z * wv.z + hv.w * wv.w;
        }
        float t = fmaxf(acc, 0.f) * w3[g];
#pragma unroll
        for (int off = 1; off < 32; off <<= 1) t += __shfl_xor(t, off, 64);
        if (g == 0) out[node0 + n] = t + b3[0];
    }
}

// ---------------------------------------------------------------------------
extern "C" void kernel_launch(void* const* d_in, const int* in_sizes, int n_in,
                              void* d_out, int out_size, void* d_ws, size_t ws_size,
                              hipStream_t stream) {
    (void)in_sizes; (void)n_in; (void)out_size; (void)ws_size;
    const float* x_in   = (const float*)d_in[0];
    const int*   ei     = (const int*)d_in[1];
    const float* gin_w1 = (const float*)d_in[2];
    const float* gin_b1 = (const float*)d_in[3];
    const float* gin_w2 = (const float*)d_in[4];
    const float* gin_b2 = (const float*)d_in[5];
    const float* ain_w  = (const float*)d_in[6];
    const float* ain_b  = (const float*)d_in[7];
    const float* aout_w = (const float*)d_in[8];
    const float* aout_b = (const float*)d_in[9];
    const float* n1_g   = (const float*)d_in[10];
    const float* n1_b   = (const float*)d_in[11];
    const float* n2_g   = (const float*)d_in[12];
    const float* n2_b   = (const float*)d_in[13];
    const float* n3_g   = (const float*)d_in[14];
    const float* n3_b   = (const float*)d_in[15];
    const float* mlp_w1 = (const float*)d_in[16];
    const float* mlp_b1 = (const float*)d_in[17];
    const float* mlp_w2 = (const float*)d_in[18];
    const float* mlp_b2 = (const float*)d_in[19];
    const float* h_w1   = (const float*)d_in[20];
    const float* h_b1   = (const float*)d_in[21];
    const float* h_w2   = (const float*)d_in[22];
    const float* h_b2   = (const float*)d_in[23];
    const float* h_w3   = (const float*)d_in[24];
    const float* h_b3   = (const float*)d_in[25];

    float* f = (float*)d_ws;
    float* g1   = f;                   // c0 (m3 aliases; per-block row-local RAW is safe)
    float* m3   = f;
    float* a2   = f + 1 * (size_t)NC;  // c1 (hsum ushort overlay during steps 1-2)
    float* hbuf = f + 2 * (size_t)NC;  // c2 (t1_bf ushort overlay only)
    float* xA   = f + 3 * (size_t)NC;
    float* xB   = f + 4 * (size_t)NC;
    unsigned short* R1  = (unsigned short*)(f + 5 * (size_t)NC);  // 3 NCu
    unsigned short* Qb      = R1;
    unsigned short* Kb      = R1 + (size_t)NCu;
    unsigned short* VT      = R1 + 2 * (size_t)NCu;
    unsigned short* R2      = R1 + 3 * (size_t)NCu;  // 1 NCu
    unsigned short* ao_bf   = R2;                    // attn out
    unsigned short* hsum_bf = (unsigned short*)a2;   // gather out (c1 overlay)
    unsigned short* t1_bf   = (unsigned short*)hbuf; // gin1 out (c2 overlay)
    unsigned short* xbf     = R2 + (size_t)NCu;
    unsigned short* wbf     = xbf + (size_t)NCu;
    float* ss    = (float*)(wbf + 655360);   // 768 raw sums (3 BNs)
    int* ibase    = (int*)(ss + 768);
    int* deg      = ibase;
    int* rowstart = ibase + 4096;
    int* cursor   = ibase + 4096 + 4098;
    int* csr_src  = ibase + 4096 + 4098 + 4096;

    const int OG1 = 0, OG2 = 65536, OAI = 131072, OAO = 327680, OM1 = 393216, OM2 = 524288;

    hipMemsetAsync(deg, 0, 4096 * sizeof(int), stream);
    hist_kernel<<<E_EDGES / 256, 256, 0, stream>>>(ei, deg);
    scan_kernel<<<1, 256, 0, stream>>>(deg, rowstart, cursor);
    fill_kernel<<<E_EDGES / 256, 256, 0, stream>>>(ei, cursor, csr_src);
    wcvt<<<320, 256, 0, stream>>>(gin_w1, gin_w2, ain_w, aout_w, mlp_w1, mlp_w2, wbf);
    x2bf<<<NC / 2048, 256, 0, stream>>>(x_in, xbf);

    for (int i = 0; i < L_LAYERS; ++i) {
        const float* xin = (i == 0) ? x_in : ((i & 1) ? xA : xB);
        float* xout = (i & 1) ? xB : xA;
        const float* gb1 = gin_b1 + (size_t)i * C_DIM;
        const float* gb2 = gin_b2 + (size_t)i * C_DIM;
        const float* aib = ain_b + (size_t)i * 3 * C_DIM;
        const float* aob = aout_b + (size_t)i * C_DIM;
        const float* mb1 = mlp_b1 + (size_t)i * 2 * C_DIM;
        const float* mb2 = mlp_b2 + (size_t)i * C_DIM;

        // 1) fused QKV GEMM + GIN gather (both read xbf); zeroes ss
        qkv_gather<<<2560, 256, 0, stream>>>(xbf, wbf + OAI + (size_t)i * 49152, aib,
                                             Qb, Kb, VT, rowstart, csr_src,
                                             (unsigned int*)hsum_bf, ss);
        // 2) fused attention + gin1
        attn_gin1<<<768, 512, 0, stream>>>(Qb, Kb, VT, ao_bf,
                                           hsum_bf, wbf + OG1 + (size_t)i * 16384, gb1, t1_bf);
        // 3) fused gin2 + aout (stats into ss/ss+256)
        gemm2x<<<1024, 256, 0, stream>>>(t1_bf, wbf + OG2 + (size_t)i * 16384, gb2, g1, ss,
                                         ao_bf, wbf + OAO + (size_t)i * 16384, aob, a2, ss + 256,
                                         xin);
        // 4) fully fused MLP (BN-combine + MLP1 + MLP2 + resid + stats)
        mlp_fused<<<256, 256, 0, stream>>>(g1, a2, ss, ss + 256,
                                           n1_g + (size_t)i * C_DIM, n1_b + (size_t)i * C_DIM,
                                           n2_g + (size_t)i * C_DIM, n2_b + (size_t)i * C_DIM,
                                           wbf + OM1 + (size_t)i * 32768, mb1,
                                           wbf + OM2 + (size_t)i * 32768, mb2,
                                           m3, ss + 512);
        // 5) final BN
        bn_apply<<<512, 256, 0, stream>>>(m3, ss + 512,
                                          n3_g + (size_t)i * C_DIM, n3_b + (size_t)i * C_DIM,
                                          xout, xbf);
    }

    const float* xf = xB;  // after layer 3
    head_fused<<<N_NODES / 8, 256, 0, stream>>>(xf, h_w1, h_b1, h_w2, h_b2, h_w3, h_b3,
                                                (float*)d_out);
}

// Round 17
// 366.769 us; speedup vs baseline: 1.3719x; 1.0457x over previous
//
#include <hip/hip_runtime.h>

#define N_NODES 4096
#define C_DIM   128
#define L_LAYERS 4
#define E_EDGES 131072
#define H_HEADS 4
#define D_HEAD  32
#define NC      (N_NODES * C_DIM)
#define NCu     (N_NODES * C_DIM)
#define P_STRIDE 136
#define HS_STRIDE 152
#define T2S       264
#define AT_S      136   // qkv A-tile LDS stride (ushorts)

typedef short bf16x8 __attribute__((ext_vector_type(8)));
typedef float f32x4  __attribute__((ext_vector_type(4)));

__device__ __forceinline__ unsigned short f2bf(float f) {
    unsigned int u = __float_as_uint(f);
    u += 0x7fffu + ((u >> 16) & 1u);
    return (unsigned short)(u >> 16);
}

__device__ __forceinline__ float bf_lo(unsigned int u) { return __uint_as_float(u << 16); }
__device__ __forceinline__ float bf_hi(unsigned int u) { return __uint_as_float(u & 0xffff0000u); }

__device__ __forceinline__ bf16x8 pack8(const float* v) {
    bf16x8 o;
#pragma unroll
    for (int i = 0; i < 8; ++i) o[i] = (short)f2bf(v[i]);
    return o;
}

// ---------------------------------------------------------------------------
// CSR build (once per launch)
// ---------------------------------------------------------------------------
__global__ __launch_bounds__(256) void hist_kernel(const int* __restrict__ ei,
                                                   int* __restrict__ deg) {
    int e = blockIdx.x * 256 + threadIdx.x;
    atomicAdd(&deg[ei[E_EDGES + e]], 1);
}

__global__ __launch_bounds__(256) void scan_kernel(const int* __restrict__ deg,
                                                   int* __restrict__ rowstart,
                                                   int* __restrict__ cursor) {
    __shared__ int ts[256];
    const int tid = threadIdx.x;
    int loc[16];
    int s = 0;
#pragma unroll
    for (int i = 0; i < 16; ++i) { loc[i] = s; s += deg[tid * 16 + i]; }
    ts[tid] = s;
    __syncthreads();
    for (int off = 1; off < 256; off <<= 1) {
        int t = (tid >= off) ? ts[tid - off] : 0;
        __syncthreads();
        if (tid >= off) ts[tid] += t;
        __syncthreads();
    }
    int off0 = ts[tid] - s;
#pragma unroll
    for (int i = 0; i < 16; ++i) {
        int v = off0 + loc[i];
        rowstart[tid * 16 + i] = v;
        cursor[tid * 16 + i] = v;
    }
    if (tid == 255) rowstart[4096] = off0 + s;
}

__global__ __launch_bounds__(256) void fill_kernel(const int* __restrict__ ei,
                                                   int* __restrict__ cursor,
                                                   int* __restrict__ csr_src) {
    int e = blockIdx.x * 256 + threadIdx.x;
    int d = ei[E_EDGES + e];
    int s = ei[e];
    int p = atomicAdd(&cursor[d], 1);
    csr_src[p] = s;
}

// ---------------------------------------------------------------------------
// weight pre-convert fp32 -> bf16
// ---------------------------------------------------------------------------
__global__ __launch_bounds__(256) void wcvt(const float* __restrict__ s0, const float* __restrict__ s1,
                                            const float* __restrict__ s2, const float* __restrict__ s3,
                                            const float* __restrict__ s4, const float* __restrict__ s5,
                                            unsigned short* __restrict__ wbf) {
    int i0 = (blockIdx.x * 256 + threadIdx.x) * 8;
    const float* src; int base;
    if      (i0 < 65536)  { src = s0; base = 0; }
    else if (i0 < 131072) { src = s1; base = 65536; }
    else if (i0 < 327680) { src = s2; base = 131072; }
    else if (i0 < 393216) { src = s3; base = 327680; }
    else if (i0 < 524288) { src = s4; base = 393216; }
    else                  { src = s5; base = 524288; }
    const float* p = src + (i0 - base);
    float t[8];
#pragma unroll
    for (int i = 0; i < 8; ++i) t[i] = p[i];
    *(bf16x8*)(wbf + i0) = pack8(t);
}

// ---------------------------------------------------------------------------
// Fused QKV-GEMM + GIN-gather with DEFERRED BN3:
// xprev = m3 of prev layer (or x_in for layer 0); st3/g3p/b3p = prev layer's
// BN3 raw sums + params (nullptr => identity transform).
// GEMM half stages its bf16 A-tile (= f2bf(bn3(m3)), identical to old xbf)
// in LDS; gather half applies the affine in-register (2 ch/lane).
// Block 1536 zeroes this layer's stats buffer ss_cur (768 floats).
// ---------------------------------------------------------------------------
__global__ __launch_bounds__(256, 8) void qkv_gather(const float* __restrict__ xprev,
                                                     const float* __restrict__ st3,
                                                     const float* __restrict__ g3p,
                                                     const float* __restrict__ b3p,
                                                     const unsigned short* __restrict__ Wbf,
                                                     const float* __restrict__ bias,
                                                     unsigned short* __restrict__ Qb,
                                                     unsigned short* __restrict__ Kb,
                                                     unsigned short* __restrict__ VT,
                                                     const int* __restrict__ rowstart,
                                                     const int* __restrict__ csr_src,
                                                     float* __restrict__ ssz,
                                                     unsigned int* __restrict__ hsum) {
    __shared__ float scl2[2][128];
    __shared__ __align__(16) unsigned short at[16 * AT_S];

    const int b = blockIdx.x;
    const int tid = threadIdx.x;
    const float inv_n = 1.f / N_NODES;

    if (b < 1536) {
        const int ct = b % 6, rt = b / 6;
        const int rowbase = rt * 16;

        // phase A: per-channel BN3 scales (identity for layer 0)
        if (tid < 128) {
            float sc = 1.f, sh = 0.f;
            if (st3) {
                float m = st3[tid] * inv_n;
                float vv = st3[128 + tid] * inv_n - m * m;
                float r = rsqrtf(vv + 1e-5f);
                sc = g3p[tid] * r;
                sh = b3p[tid] - m * sc;
            }
            scl2[0][tid] = sc; scl2[1][tid] = sh;
        }
        __syncthreads();

        // phase B: stage bf16 A-tile (16 x 128) from xprev
        {
            const int e0 = tid * 8;
            const int r = e0 >> 7, c = e0 & 127;
            const float* xp = xprev + (size_t)(rowbase + r) * 128 + c;
            float t[8];
#pragma unroll
            for (int i = 0; i < 8; ++i) t[i] = xp[i] * scl2[0][c + i] + scl2[1][c + i];
            *(bf16x8*)(&at[r * AT_S + c]) = pack8(t);
        }
        __syncthreads();

        // phase C: GEMM, A from LDS
        const int wv = tid >> 6;
        const int lane = tid & 63, lg = lane >> 4, ll = lane & 15;
        const int colbase = ct * 64 + wv * 16;
        const unsigned short* Wp = Wbf + (size_t)(colbase + ll) * 128 + lg * 8;

        f32x4 acc = {0.f, 0.f, 0.f, 0.f};
#pragma unroll
        for (int k = 0; k < 128; k += 32) {
            bf16x8 a = *(const bf16x8*)(&at[ll * AT_S + k + lg * 8]);
            bf16x8 w = *(const bf16x8*)(Wp + k);
            acc = __builtin_amdgcn_mfma_f32_16x16x32_bf16(a, w, acc, 0, 0, 0);
        }

        const float qsc = 0.25506973f;  // (1/sqrt(32)) * log2(e)
        const int col = colbase + ll;
        const float bi = bias[col];
#pragma unroll
        for (int r = 0; r < 4; ++r) {
            const int row = rowbase + lg * 4 + r;
            float v = acc[r] + bi;
            if (col < 128) {
                int hh = col >> 5, d = col & 31;
                Qb[((size_t)hh * N_NODES + row) * D_HEAD + d] = f2bf(v * qsc);
            } else if (col < 256) {
                int c2 = col - 128, hh = c2 >> 5, d = c2 & 31;
                Kb[((size_t)hh * N_NODES + row) * D_HEAD + d] = f2bf(v);
            } else {
                int c2 = col - 256, hh = c2 >> 5, d = c2 & 31;
                VT[((size_t)hh * D_HEAD + d) * N_NODES + row] = f2bf(v);
            }
        }
    } else {
        if (b == 1536) {
            ssz[tid] = 0.f; ssz[256 + tid] = 0.f; ssz[512 + tid] = 0.f;
        }
        const int node = (b - 1536) * 4 + (tid >> 6);
        const int lane = tid & 63;
        const int ch0 = lane * 2, ch1 = ch0 + 1;
        float sc0 = 1.f, sh0 = 0.f, sc1 = 1.f, sh1 = 0.f;
        if (st3) {
            float m0 = st3[ch0] * inv_n;
            float v0 = st3[128 + ch0] * inv_n - m0 * m0;
            float r0 = rsqrtf(v0 + 1e-5f);
            sc0 = g3p[ch0] * r0; sh0 = b3p[ch0] - m0 * sc0;
            float m1 = st3[ch1] * inv_n;
            float v1 = st3[128 + ch1] * inv_n - m1 * m1;
            float r1 = rsqrtf(v1 + 1e-5f);
            sc1 = g3p[ch1] * r1; sh1 = b3p[ch1] - m1 * sc1;
        }
        const int beg = rowstart[node], end = rowstart[node + 1];
        float2 sv = *(const float2*)(xprev + (size_t)node * 128 + ch0);
        float ax = sv.x * sc0 + sh0, ay = sv.y * sc1 + sh1;
        float bx = 0.f, by = 0.f;
        int e = beg;
        for (; e + 4 <= end; e += 4) {
            int s0 = csr_src[e], s1 = csr_src[e + 1], s2 = csr_src[e + 2], s3 = csr_src[e + 3];
            float2 v0 = *(const float2*)(xprev + (size_t)s0 * 128 + ch0);
            float2 v1 = *(const float2*)(xprev + (size_t)s1 * 128 + ch0);
            float2 v2 = *(const float2*)(xprev + (size_t)s2 * 128 + ch0);
            float2 v3 = *(const float2*)(xprev + (size_t)s3 * 128 + ch0);
            ax += (v0.x * sc0 + sh0) + (v1.x * sc0 + sh0);
            ay += (v0.y * sc1 + sh1) + (v1.y * sc1 + sh1);
            bx += (v2.x * sc0 + sh0) + (v3.x * sc0 + sh0);
            by += (v2.y * sc1 + sh1) + (v3.y * sc1 + sh1);
        }
        for (; e < end; ++e) {
            float2 v0 = *(const float2*)(xprev + (size_t)csr_src[e] * 128 + ch0);
            ax += v0.x * sc0 + sh0; ay += v0.y * sc1 + sh1;
        }
        float ox = ax + bx, oy = ay + by;
        hsum[(size_t)node * 64 + lane] = (unsigned int)f2bf(ox) | ((unsigned int)f2bf(oy) << 16);
    }
}

// ---------------------------------------------------------------------------
// Fused attention + GIN-MLP-1 (R14/R15/R16-proven, byte-identical).
// ---------------------------------------------------------------------------
__global__ __launch_bounds__(512, 4) void attn_gin1(const unsigned short* __restrict__ Qb,
                                                    const unsigned short* __restrict__ Kb,
                                                    const unsigned short* __restrict__ VT,
                                                    unsigned short* __restrict__ ob,
                                                    const unsigned short* __restrict__ hsum,
                                                    const unsigned short* __restrict__ W1,
                                                    const float* __restrict__ bias1,
                                                    unsigned short* __restrict__ t1out) {
    __shared__ __align__(16) unsigned short Pl[8 * 32 * P_STRIDE];
    float (*Ouns)[32][33] = (float (*)[32][33])(void*)Pl;
    float (*Llp)[32] = (float (*)[32])(void*)(Pl + 8 * 32 * 33 * 2);

    const int b   = blockIdx.x;
    const int tid = threadIdx.x;
    const int wv  = tid >> 6;
    const int lane = tid & 63;
    const int lg  = lane >> 4;
    const int ll  = lane & 15;

    if (b >= 512) {
        const int rowbase = (b - 512) * 16;
        const int colbase = wv * 16;
        const unsigned short* Ap = hsum + (size_t)(rowbase + ll) * 128 + lg * 8;
        const unsigned short* Wp = W1 + (size_t)(colbase + ll) * 128 + lg * 8;
        f32x4 acc = {0.f, 0.f, 0.f, 0.f};
#pragma unroll
        for (int k = 0; k < 128; k += 32) {
            bf16x8 a = *(const bf16x8*)(Ap + k);
            bf16x8 w = *(const bf16x8*)(Wp + k);
            acc = __builtin_amdgcn_mfma_f32_16x16x32_bf16(a, w, acc, 0, 0, 0);
        }
        const int col = colbase + ll;
        const float bi = bias1[col];
#pragma unroll
        for (int r = 0; r < 4; ++r) {
            const int row = rowbase + lg * 4 + r;
            float v = fmaxf(acc[r] + bi, 0.f);
            t1out[(size_t)row * 128 + col] = f2bf(v);
        }
        return;
    }

    const int h   = b >> 7;
    const int q0  = (b & 127) * 32;

    const unsigned short* Qh = Qb + ((size_t)h * N_NODES + q0) * D_HEAD;
    const unsigned short* Kh = Kb + (size_t)h * N_NODES * D_HEAD;
    const unsigned short* Vh = VT + (size_t)h * D_HEAD * N_NODES;

    bf16x8 qf0 = *(const bf16x8*)(Qh + ll * D_HEAD + lg * 8);
    bf16x8 qf1 = *(const bf16x8*)(Qh + (16 + ll) * D_HEAD + lg * 8);

    f32x4 oacc00 = {0.f,0.f,0.f,0.f}, oacc01 = {0.f,0.f,0.f,0.f};
    f32x4 oacc10 = {0.f,0.f,0.f,0.f}, oacc11 = {0.f,0.f,0.f,0.f};
    float l0[4] = {0.f,0.f,0.f,0.f}, l1[4] = {0.f,0.f,0.f,0.f};

    unsigned short* Pw = Pl + wv * (32 * P_STRIDE);
    const int k0 = wv * (N_NODES / 8);

    for (int t = 0; t < (N_NODES / 8) / 128; ++t) {
        const int kt = k0 + t * 128;

        float s0[8][4], s1[8][4];
#pragma unroll
        for (int kc = 0; kc < 8; ++kc) {
            bf16x8 kf = *(const bf16x8*)(Kh + (size_t)(kt + kc * 16 + ll) * D_HEAD + lg * 8);
            f32x4 z = {0.f, 0.f, 0.f, 0.f};
            f32x4 d0 = __builtin_amdgcn_mfma_f32_16x16x32_bf16(qf0, kf, z, 0, 0, 0);
            f32x4 d1 = __builtin_amdgcn_mfma_f32_16x16x32_bf16(qf1, kf, z, 0, 0, 0);
#pragma unroll
            for (int r = 0; r < 4; ++r) { s0[kc][r] = d0[r]; s1[kc][r] = d1[r]; }
        }

#pragma unroll
        for (int r = 0; r < 4; ++r) {
            float a = 0.f, bb = 0.f;
#pragma unroll
            for (int kc = 0; kc < 8; ++kc) {
                float p0 = exp2f(s0[kc][r]); s0[kc][r] = p0; a += p0;
                float p1 = exp2f(s1[kc][r]); s1[kc][r] = p1; bb += p1;
            }
#pragma unroll
            for (int off = 1; off < 16; off <<= 1) {
                a += __shfl_xor(a, off, 64);
                bb += __shfl_xor(bb, off, 64);
            }
            l0[r] += a;
            l1[r] += bb;
        }

#pragma unroll
        for (int kc = 0; kc < 8; ++kc)
#pragma unroll
            for (int r = 0; r < 4; ++r) {
                Pw[(lg * 4 + r) * P_STRIDE + kc * 16 + ll]      = f2bf(s0[kc][r]);
                Pw[(16 + lg * 4 + r) * P_STRIDE + kc * 16 + ll] = f2bf(s1[kc][r]);
            }
        asm volatile("" ::: "memory");

#pragma unroll
        for (int kc2 = 0; kc2 < 4; ++kc2) {
            bf16x8 va = *(const bf16x8*)(Vh + (size_t)ll * N_NODES + kt + kc2 * 32 + lg * 8);
            bf16x8 vb = *(const bf16x8*)(Vh + (size_t)(16 + ll) * N_NODES + kt + kc2 * 32 + lg * 8);
            bf16x8 pf0 = *(const bf16x8*)(Pw + ll * P_STRIDE + kc2 * 32 + lg * 8);
            bf16x8 pf1 = *(const bf16x8*)(Pw + (16 + ll) * P_STRIDE + kc2 * 32 + lg * 8);
            oacc00 = __builtin_amdgcn_mfma_f32_16x16x32_bf16(pf0, va, oacc00, 0, 0, 0);
            oacc01 = __builtin_amdgcn_mfma_f32_16x16x32_bf16(pf0, vb, oacc01, 0, 0, 0);
            oacc10 = __builtin_amdgcn_mfma_f32_16x16x32_bf16(pf1, va, oacc10, 0, 0, 0);
            oacc11 = __builtin_amdgcn_mfma_f32_16x16x32_bf16(pf1, vb, oacc11, 0, 0, 0);
        }
    }

    __syncthreads();

#pragma unroll
    for (int r = 0; r < 4; ++r) {
        Ouns[wv][lg * 4 + r][ll]           = oacc00[r];
        Ouns[wv][lg * 4 + r][16 + ll]      = oacc01[r];
        Ouns[wv][16 + lg * 4 + r][ll]      = oacc10[r];
        Ouns[wv][16 + lg * 4 + r][16 + ll] = oacc11[r];
    }
    if (ll == 0) {
#pragma unroll
        for (int r = 0; r < 4; ++r) {
            Llp[wv][lg * 4 + r]      = l0[r];
            Llp[wv][16 + lg * 4 + r] = l1[r];
        }
    }
    __syncthreads();

    {
        const int row = tid >> 4, col = tid & 15;
        float L = 0.f, oa = 0.f, obv = 0.f;
#pragma unroll
        for (int w = 0; w < 8; ++w) {
            L   += Llp[w][row];
            oa  += Ouns[w][row][col];
            obv += Ouns[w][row][16 + col];
        }
        float inv = 1.f / L;
        ob[(size_t)(q0 + row) * C_DIM + h * D_HEAD + col]      = f2bf(oa * inv);
        ob[(size_t)(q0 + row) * C_DIM + h * D_HEAD + 16 + col] = f2bf(obv * inv);
    }
}

// ---------------------------------------------------------------------------
// Fused gin2 + aout with deferred-BN3 residual: resid = bn3(xprev) per thread.
// ---------------------------------------------------------------------------
__global__ __launch_bounds__(256, 8) void gemm2x(const unsigned short* __restrict__ A0,
                                                 const unsigned short* __restrict__ W0,
                                                 const float* __restrict__ bias0,
                                                 float* __restrict__ out0,
                                                 float* __restrict__ stats0,
                                                 const unsigned short* __restrict__ A1,
                                                 const unsigned short* __restrict__ W1,
                                                 const float* __restrict__ bias1,
                                                 float* __restrict__ out1,
                                                 float* __restrict__ stats1,
                                                 const float* __restrict__ xprev,
                                                 const float* __restrict__ st3,
                                                 const float* __restrict__ g3p,
                                                 const float* __restrict__ b3p) {
    const int b = blockIdx.x;
    const int which = b >> 9;
    const int bl = b & 511;
    const unsigned short* Abf = which ? A1 : A0;
    const unsigned short* Wbf = which ? W1 : W0;
    const float* bias = which ? bias1 : bias0;
    float* outf  = which ? out1 : out0;
    float* stats = which ? stats1 : stats0;

    const int tid = threadIdx.x;
    const int wv = tid >> 6;
    const int lane = tid & 63, lg = lane >> 4, ll = lane & 15;
    const int rowbase = (bl >> 1) * 16;
    const int colbase = (bl & 1) * 64 + wv * 16;

    const unsigned short* Ap = Abf + (size_t)(rowbase + ll) * 128 + lg * 8;
    const unsigned short* Wp = Wbf + (size_t)(colbase + ll) * 128 + lg * 8;

    f32x4 acc = {0.f, 0.f, 0.f, 0.f};
#pragma unroll
    for (int k = 0; k < 128; k += 32) {
        bf16x8 a = *(const bf16x8*)(Ap + k);
        bf16x8 w = *(const bf16x8*)(Wp + k);
        acc = __builtin_amdgcn_mfma_f32_16x16x32_bf16(a, w, acc, 0, 0, 0);
    }

    const int col = colbase + ll;
    const float bi = bias[col];
    float sc = 1.f, sh = 0.f;
    if (st3) {
        const float inv_n = 1.f / N_NODES;
        float m = st3[col] * inv_n;
        float vv = st3[128 + col] * inv_n - m * m;
        float r = rsqrtf(vv + 1e-5f);
        sc = g3p[col] * r; sh = b3p[col] - m * sc;
    }
    float sv = 0.f, sv2 = 0.f;
#pragma unroll
    for (int r = 0; r < 4; ++r) {
        const int row = rowbase + lg * 4 + r;
        float v = acc[r] + bi + (xprev[(size_t)row * 128 + col] * sc + sh);
        outf[(size_t)row * 128 + col] = v;
        sv += v; sv2 += v * v;
    }
    sv  += __shfl_xor(sv, 16, 64);  sv  += __shfl_xor(sv, 32, 64);
    sv2 += __shfl_xor(sv2, 16, 64); sv2 += __shfl_xor(sv2, 32, 64);
    if (lg == 0) {
        atomicAdd(&stats[col], sv);
        atomicAdd(&stats[128 + col], sv2);
    }
}

// ---------------------------------------------------------------------------
// Fully fused MLP (R16-proven): BN-combine + MLP1 + MLP2 + resid + stats.
// ---------------------------------------------------------------------------
__global__ __launch_bounds__(256) void mlp_fused(const float* __restrict__ g1p,
                                                 const float* __restrict__ a2p,
                                                 const float* __restrict__ st1,
                                                 const float* __restrict__ st2,
                                                 const float* __restrict__ g1v,
                                                 const float* __restrict__ b1v,
                                                 const float* __restrict__ g2v,
                                                 const float* __restrict__ b2v,
                                                 const unsigned short* __restrict__ W1bf,
                                                 const float* __restrict__ bias1,
                                                 const unsigned short* __restrict__ W2bf,
                                                 const float* __restrict__ bias2,
                                                 float* __restrict__ m3out,
                                                 float* __restrict__ stats3) {
    __shared__ float hf[16][132];
    __shared__ __align__(16) unsigned short hs[16 * HS_STRIDE];
    __shared__ __align__(16) unsigned short t2s[16 * T2S];
    __shared__ float scl[4][128];

    const int tid = threadIdx.x;
    const int rowbase = blockIdx.x * 16;
    const float inv_n = 1.f / N_NODES;

    if (tid < 128) {
        const int ch = tid;
        float m1 = st1[ch] * inv_n;
        float v1 = st1[128 + ch] * inv_n - m1 * m1;
        float r1 = rsqrtf(v1 + 1e-5f);
        float sc1 = g1v[ch] * r1;
        scl[0][ch] = sc1;
        scl[1][ch] = b1v[ch] - m1 * sc1;
        float m2 = st2[ch] * inv_n;
        float v2 = st2[128 + ch] * inv_n - m2 * m2;
        float r2 = rsqrtf(v2 + 1e-5f);
        float sc2 = g2v[ch] * r2;
        scl[2][ch] = sc2;
        scl[3][ch] = b2v[ch] - m2 * sc2;
    }
    __syncthreads();

#pragma unroll
    for (int j = tid; j < 512; j += 256) {
        const int r = j >> 5, cq = (j & 31) * 4;
        float4 v1 = *(const float4*)(g1p + (size_t)(rowbase + r) * 128 + cq);
        float4 v2 = *(const float4*)(a2p + (size_t)(rowbase + r) * 128 + cq);
        float h0 = v1.x * scl[0][cq]     + scl[1][cq]     + v2.x * scl[2][cq]     + scl[3][cq];
        float h1 = v1.y * scl[0][cq + 1] + scl[1][cq + 1] + v2.y * scl[2][cq + 1] + scl[3][cq + 1];
        float h2 = v1.z * scl[0][cq + 2] + scl[1][cq + 2] + v2.z * scl[2][cq + 2] + scl[3][cq + 2];
        float h3 = v1.w * scl[0][cq + 3] + scl[1][cq + 3] + v2.w * scl[2][cq + 3] + scl[3][cq + 3];
        hf[r][cq] = h0; hf[r][cq + 1] = h1; hf[r][cq + 2] = h2; hf[r][cq + 3] = h3;
        ushort4 u;
        u.x = f2bf(h0); u.y = f2bf(h1); u.z = f2bf(h2); u.w = f2bf(h3);
        *(ushort4*)(&hs[r * HS_STRIDE + cq]) = u;
    }
    __syncthreads();

    const int wv = tid >> 6;
    const int lane = tid & 63, lg = lane >> 4, ll = lane & 15;

#pragma unroll
    for (int ct = 0; ct < 4; ++ct) {
        const int colbase = wv * 16 + ct * 64;
        const unsigned short* Wp = W1bf + (size_t)(colbase + ll) * 128 + lg * 8;
        f32x4 acc = {0.f, 0.f, 0.f, 0.f};
#pragma unroll
        for (int k = 0; k < 128; k += 32) {
            bf16x8 a = *(const bf16x8*)(&hs[ll * HS_STRIDE + k + lg * 8]);
            bf16x8 w = *(const bf16x8*)(Wp + k);
            acc = __builtin_amdgcn_mfma_f32_16x16x32_bf16(a, w, acc, 0, 0, 0);
        }
        const int col = colbase + ll;
        const float bi = bias1[col];
#pragma unroll
        for (int r = 0; r < 4; ++r) {
            float v = fmaxf(acc[r] + bi, 0.f);
            t2s[(lg * 4 + r) * T2S + col] = f2bf(v);
        }
    }
    __syncthreads();

#pragma unroll
    for (int p = 0; p < 2; ++p) {
        const int colbase = p * 64 + wv * 16;
        const unsigned short* Wp = W2bf + (size_t)(colbase + ll) * 256 + lg * 8;
        f32x4 acc = {0.f, 0.f, 0.f, 0.f};
#pragma unroll
        for (int k = 0; k < 256; k += 32) {
            bf16x8 a = *(const bf16x8*)(&t2s[ll * T2S + k + lg * 8]);
            bf16x8 w = *(const bf16x8*)(Wp + k);
            acc = __builtin_amdgcn_mfma_f32_16x16x32_bf16(a, w, acc, 0, 0, 0);
        }
        const int col = colbase + ll;
        const float bi = bias2[col];
        float sv = 0.f, sv2 = 0.f;
#pragma unroll
        for (int r = 0; r < 4; ++r) {
            const int row = lg * 4 + r;
            float v = acc[r] + bi + hf[row][col];
            m3out[(size_t)(rowbase + row) * 128 + col] = v;
            sv += v; sv2 += v * v;
        }
        sv  += __shfl_xor(sv, 16, 64);  sv  += __shfl_xor(sv, 32, 64);
        sv2 += __shfl_xor(sv2, 16, 64); sv2 += __shfl_xor(sv2, 32, 64);
        if (lg == 0) {
            atomicAdd(&stats3[col], sv);
            atomicAdd(&stats3[128 + col], sv2);
        }
    }
}

// ---------------------------------------------------------------------------
// Fused head MLP with deferred BN3: stages x = bn3(m3) rows into LDS first.
// ---------------------------------------------------------------------------
__global__ __launch_bounds__(256) void head_fused(const float* __restrict__ m3p,
                                                  const float* __restrict__ st3,
                                                  const float* __restrict__ g3p,
                                                  const float* __restrict__ b3p,
                                                  const float* __restrict__ w1,
                                                  const float* __restrict__ b1,
                                                  const float* __restrict__ w2,
                                                  const float* __restrict__ b2,
                                                  const float* __restrict__ w3,
                                                  const float* __restrict__ b3,
                                                  float* __restrict__ out) {
    __shared__ __align__(16) float xs[8][128];
    __shared__ __align__(16) float hs2[8][64];
    __shared__ float scl2[2][128];
    const int tid = threadIdx.x;
    const int n = tid >> 5;
    const int g = tid & 31;
    const int node0 = blockIdx.x * 8;
    const float inv_n = 1.f / N_NODES;

    if (tid < 128) {
        float m = st3[tid] * inv_n;
        float vv = st3[128 + tid] * inv_n - m * m;
        float r = rsqrtf(vv + 1e-5f);
        float sc = g3p[tid] * r;
        scl2[0][tid] = sc;
        scl2[1][tid] = b3p[tid] - m * sc;
    }
    __syncthreads();

    {
        const int e0 = tid * 4;
        const int r = e0 >> 7, c = e0 & 127;
        float4 v = *(const float4*)(m3p + (size_t)(node0 + r) * 128 + c);
        xs[r][c]     = v.x * scl2[0][c]     + scl2[1][c];
        xs[r][c + 1] = v.y * scl2[0][c + 1] + scl2[1][c + 1];
        xs[r][c + 2] = v.z * scl2[0][c + 2] + scl2[1][c + 2];
        xs[r][c + 3] = v.w * scl2[0][c + 3] + scl2[1][c + 3];
    }
    __syncthreads();

    {
        float acc0 = b1[g], acc1 = b1[g + 32];
        const float* wa = w1 + (size_t)g * 128;
        const float* wb = w1 + (size_t)(g + 32) * 128;
#pragma unroll 8
        for (int k = 0; k < 128; k += 4) {
            float4 xv = *(const float4*)(&xs[n][k]);
            float4 va = *(const float4*)(wa + k);
            float4 vb = *(const float4*)(wb + k);
            acc0 += xv.x * va.x + xv.y * va.y + xv.z * va.z + xv.w * va.w;
            acc1 += xv.x * vb.x + xv.y * vb.y + xv.z * vb.z + xv.w * vb.w;
        }
        hs2[n][g]      = fmaxf(acc0, 0.f);
        hs2[n][g + 32] = fmaxf(acc1, 0.f);
    }
    __syncthreads();

    {
        float acc = b2[g];
        const float* wr = w2 + (size_t)g * 64;
#pragma unroll 8
        for (int k = 0; k < 64; k += 4) {
            float4 hv = *(const float4*)(&hs2[n][k]);
            float4 wv = *(const float4*)(wr + k);
            acc += hv.x * wv.x + hv.y * wv.y + hv.z * wv.z + hv.w * wv.w;
        }
        float t = fmaxf(acc, 0.f) * w3[g];
#pragma unroll
        for (int off = 1; off < 32; off <<= 1) t += __shfl_xor(t, off, 64);
        if (g == 0) out[node0 + n] = t + b3[0];
    }
}

// ---------------------------------------------------------------------------
extern "C" void kernel_launch(void* const* d_in, const int* in_sizes, int n_in,
                              void* d_out, int out_size, void* d_ws, size_t ws_size,
                              hipStream_t stream) {
    (void)in_sizes; (void)n_in; (void)out_size; (void)ws_size;
    const float* x_in   = (const float*)d_in[0];
    const int*   ei     = (const int*)d_in[1];
    const float* gin_w1 = (const float*)d_in[2];
    const float* gin_b1 = (const float*)d_in[3];
    const float* gin_w2 = (const float*)d_in[4];
    const float* gin_b2 = (const float*)d_in[5];
    const float* ain_w  = (const float*)d_in[6];
    const float* ain_b  = (const float*)d_in[7];
    const float* aout_w = (const float*)d_in[8];
    const float* aout_b = (const float*)d_in[9];
    const float* n1_g   = (const float*)d_in[10];
    const float* n1_b   = (const float*)d_in[11];
    const float* n2_g   = (const float*)d_in[12];
    const float* n2_b   = (const float*)d_in[13];
    const float* n3_g   = (const float*)d_in[14];
    const float* n3_b   = (const float*)d_in[15];
    const float* mlp_w1 = (const float*)d_in[16];
    const float* mlp_b1 = (const float*)d_in[17];
    const float* mlp_w2 = (const float*)d_in[18];
    const float* mlp_b2 = (const float*)d_in[19];
    const float* h_w1   = (const float*)d_in[20];
    const float* h_b1   = (const float*)d_in[21];
    const float* h_w2   = (const float*)d_in[22];
    const float* h_b2   = (const float*)d_in[23];
    const float* h_w3   = (const float*)d_in[24];
    const float* h_b3   = (const float*)d_in[25];

    float* f = (float*)d_ws;
    float* g1   = f;                   // c0
    float* a2   = f + 1 * (size_t)NC;  // c1 (hsum ushort overlay during steps 1-2)
    float* t1ch = f + 2 * (size_t)NC;  // c2 (t1_bf ushort overlay)
    float* m3   = f + 3 * (size_t)NC;  // c3 (dedicated; persists into next layer)
    unsigned short* R1  = (unsigned short*)(f + 4 * (size_t)NC);  // 3 NCu
    unsigned short* Qb      = R1;
    unsigned short* Kb      = R1 + (size_t)NCu;
    unsigned short* VT      = R1 + 2 * (size_t)NCu;
    unsigned short* R2      = R1 + 3 * (size_t)NCu;  // 1 NCu
    unsigned short* ao_bf   = R2;                    // attn out
    unsigned short* hsum_bf = (unsigned short*)a2;   // gather out (c1 overlay)
    unsigned short* t1_bf   = (unsigned short*)t1ch; // gin1 out (c2 overlay)
    unsigned short* wbf     = R2 + (size_t)NCu;
    float* ssA    = (float*)(wbf + 655360);   // 768 raw sums (parity 0)
    float* ssB    = ssA + 768;                // 768 raw sums (parity 1)
    int* ibase    = (int*)(ssB + 768);
    int* deg      = ibase;
    int* rowstart = ibase + 4096;
    int* cursor   = ibase + 4096 + 4098;
    int* csr_src  = ibase + 4096 + 4098 + 4096;

    const int OG1 = 0, OG2 = 65536, OAI = 131072, OAO = 327680, OM1 = 393216, OM2 = 524288;

    hipMemsetAsync(deg, 0, 4096 * sizeof(int), stream);
    hist_kernel<<<E_EDGES / 256, 256, 0, stream>>>(ei, deg);
    scan_kernel<<<1, 256, 0, stream>>>(deg, rowstart, cursor);
    fill_kernel<<<E_EDGES / 256, 256, 0, stream>>>(ei, cursor, csr_src);
    wcvt<<<320, 256, 0, stream>>>(gin_w1, gin_w2, ain_w, aout_w, mlp_w1, mlp_w2, wbf);

    for (int i = 0; i < L_LAYERS; ++i) {
        const float* xprev = (i == 0) ? x_in : m3;
        const float* st3p  = (i == 0) ? nullptr : ((i & 1) ? ssA : ssB) + 512;
        const float* g3p   = (i == 0) ? nullptr : n3_g + (size_t)(i - 1) * C_DIM;
        const float* b3p   = (i == 0) ? nullptr : n3_b + (size_t)(i - 1) * C_DIM;
        float* ss_cur = (i & 1) ? ssB : ssA;
        const float* gb1 = gin_b1 + (size_t)i * C_DIM;
        const float* gb2 = gin_b2 + (size_t)i * C_DIM;
        const float* aib = ain_b + (size_t)i * 3 * C_DIM;
        const float* aob = aout_b + (size_t)i * C_DIM;
        const float* mb1 = mlp_b1 + (size_t)i * 2 * C_DIM;
        const float* mb2 = mlp_b2 + (size_t)i * C_DIM;

        // 1) fused QKV GEMM + GIN gather, deferred BN3 from (xprev, st3p)
        qkv_gather<<<2560, 256, 0, stream>>>(xprev, st3p, g3p, b3p,
                                             wbf + OAI + (size_t)i * 49152, aib,
                                             Qb, Kb, VT, rowstart, csr_src,
                                             ss_cur, (unsigned int*)hsum_bf);
        // 2) fused attention + gin1
        attn_gin1<<<768, 512, 0, stream>>>(Qb, Kb, VT, ao_bf,
                                           hsum_bf, wbf + OG1 + (size_t)i * 16384, gb1, t1_bf);
        // 3) fused gin2 + aout (deferred-BN3 residual)
        gemm2x<<<1024, 256, 0, stream>>>(t1_bf, wbf + OG2 + (size_t)i * 16384, gb2, g1, ss_cur,
                                         ao_bf, wbf + OAO + (size_t)i * 16384, aob, a2, ss_cur + 256,
                                         xprev, st3p, g3p, b3p);
        // 4) fully fused MLP -> m3 (c3) + BN3 stats
        mlp_fused<<<256, 256, 0, stream>>>(g1, a2, ss_cur, ss_cur + 256,
                                           n1_g + (size_t)i * C_DIM, n1_b + (size_t)i * C_DIM,
                                           n2_g + (size_t)i * C_DIM, n2_b + (size_t)i * C_DIM,
                                           wbf + OM1 + (size_t)i * 32768, mb1,
                                           wbf + OM2 + (size_t)i * 32768, mb2,
                                           m3, ss_cur + 512);
    }

    // head: x = bn3(m3 of layer 3), scales from ssB+512 (layer-3 parity)
    head_fused<<<N_NODES / 8, 256, 0, stream>>>(m3, ssB + 512,
                                                n3_g + 3 * (size_t)C_DIM, n3_b + 3 * (size_t)C_DIM,
                                                h_w1, h_b1, h_w2, h_b2, h_w3, h_b3,
                                                (float*)d_out);
}